// Round 1
// baseline (3024.141 us; speedup 1.0000x reference)
//
#include <hip/hip_runtime.h>

#define NNODES 100000
#define EEDGES 600000
#define CDIM 128
#define HHEADS 2
#define DDIM 64
#define FIN 64
#define FOUT 8
#define NEG 0.2f

// ---- ordered-uint encoding for float atomicMax ----
__device__ __forceinline__ unsigned int enc_f32(float f) {
    unsigned int u = __float_as_uint(f);
    return (u & 0x80000000u) ? ~u : (u | 0x80000000u);
}
__device__ __forceinline__ float dec_f32(unsigned int e) {
    unsigned int u = (e & 0x80000000u) ? (e & 0x7FFFFFFFu) : ~e;
    return __uint_as_float(u);
}

// ---- projection GEMM [N,K]@[K,128]+b, fused per-head attention dots ----
// block = 128 threads (thread t = output channel), 4 rows per block.
// wave 0 (lanes 0..63) = head 0 channels, wave 1 = head 1 channels.
__global__ __launch_bounds__(128)
void proj_kernel(const float* __restrict__ X, int K,
                 const float* __restrict__ W, const float* __restrict__ bias,
                 const float* __restrict__ att_src, const float* __restrict__ att_dst,
                 float* __restrict__ Hout,
                 float* __restrict__ a_src, float* __restrict__ a_dst) {
    __shared__ float xs[4][128];
    int t = threadIdx.x;
    int row0 = blockIdx.x * 4;
    for (int r = 0; r < 4; ++r) {
        float v = 0.f;
        int row = row0 + r;
        if (row < NNODES && t < K) v = X[(long)row * K + t];
        xs[r][t] = v;
    }
    __syncthreads();
    float b = bias[t];
    float acc0 = b, acc1 = b, acc2 = b, acc3 = b;
    for (int k = 0; k < K; ++k) {
        float wv = W[k * CDIM + t];
        acc0 = fmaf(xs[0][k], wv, acc0);
        acc1 = fmaf(xs[1][k], wv, acc1);
        acc2 = fmaf(xs[2][k], wv, acc2);
        acc3 = fmaf(xs[3][k], wv, acc3);
    }
    float accs[4] = {acc0, acc1, acc2, acc3};
    for (int r = 0; r < 4; ++r) {
        int row = row0 + r;
        if (row < NNODES) Hout[(long)row * CDIM + t] = accs[r];
    }
    int head = t >> 6;
    int d = t & 63;
    // attention dot products: per row, per edge type, reduce over 64 lanes of the head
    for (int i = 0; i < 2; ++i) {
        float av_s = att_src[i * (HHEADS * DDIM) + head * DDIM + d];
        float av_d = att_dst[i * (HHEADS * DDIM) + head * DDIM + d];
        for (int r = 0; r < 4; ++r) {
            float ps = accs[r] * av_s;
            float pd = accs[r] * av_d;
            for (int m = 32; m >= 1; m >>= 1) {
                ps += __shfl_xor(ps, m, 64);
                pd += __shfl_xor(pd, m, 64);
            }
            int row = row0 + r;
            if (d == 0 && row < NNODES) {
                a_src[(long)i * NNODES * HHEADS + (long)row * HHEADS + head] = ps;
                a_dst[(long)i * NNODES * HHEADS + (long)row * HHEADS + head] = pd;
            }
        }
    }
}

__global__ void init_softmax_kernel(unsigned int* __restrict__ amax,
                                    float* __restrict__ ssum, int n) {
    int i = blockIdx.x * blockDim.x + threadIdx.x;
    if (i < n) { amax[i] = 0x007FFFFFu; /* enc(-inf) */ ssum[i] = 0.f; }
}

__device__ __forceinline__ float edge_raw(const float* __restrict__ as,
                                          const float* __restrict__ ad,
                                          int s, int dt, int hh) {
    float raw = as[s * HHEADS + hh] + ad[dt * HHEADS + hh];
    return raw >= 0.f ? raw : NEG * raw;
}

__global__ void edge_amax_kernel(const int* __restrict__ src, const int* __restrict__ dst,
                                 const float* __restrict__ as, const float* __restrict__ ad,
                                 unsigned int* __restrict__ amax) {
    int idx = blockIdx.x * blockDim.x + threadIdx.x;
    if (idx >= EEDGES * HHEADS) return;
    int e = idx >> 1, hh = idx & 1;
    int s = src[e], dt = dst[e];
    float raw = edge_raw(as, ad, s, dt, hh);
    atomicMax(&amax[dt * HHEADS + hh], enc_f32(raw));
}

__global__ void edge_expsum_kernel(const int* __restrict__ src, const int* __restrict__ dst,
                                   const float* __restrict__ as, const float* __restrict__ ad,
                                   const unsigned int* __restrict__ amax,
                                   float* __restrict__ ssum) {
    int idx = blockIdx.x * blockDim.x + threadIdx.x;
    if (idx >= EEDGES * HHEADS) return;
    int e = idx >> 1, hh = idx & 1;
    int s = src[e], dt = dst[e];
    float raw = edge_raw(as, ad, s, dt, hh);
    float m = dec_f32(amax[dt * HHEADS + hh]);
    atomicAdd(&ssum[dt * HHEADS + hh], expf(raw - m));
}

__global__ __launch_bounds__(256)
void edge_scatter_kernel(const int* __restrict__ src, const int* __restrict__ dst,
                         const float* __restrict__ as, const float* __restrict__ ad,
                         const unsigned int* __restrict__ amax, const float* __restrict__ ssum,
                         const float* __restrict__ Hfeat, float* __restrict__ Out) {
    long idx = (long)blockIdx.x * blockDim.x + threadIdx.x;
    if (idx >= (long)EEDGES * CDIM) return;
    int e = (int)(idx >> 7);
    int c = (int)(idx & 127);
    int hh = c >> 6;
    int s = src[e], dt = dst[e];
    float raw = edge_raw(as, ad, s, dt, hh);
    float m = dec_f32(amax[dt * HHEADS + hh]);
    float alpha = expf(raw - m) / (ssum[dt * HHEADS + hh] + 1e-16f);
    float val = Hfeat[(long)s * CDIM + c] * alpha;
    atomicAdd(&Out[(long)dt * CDIM + c], val);
}

// ---- semantic score: sacc += sum_n q . tanh(relu(Om[n]) @ kw + kb) ----
__global__ __launch_bounds__(128)
void score_kernel(const float* __restrict__ Om, const float* __restrict__ kw,
                  const float* __restrict__ kb, const float* __restrict__ q,
                  float* __restrict__ sacc) {
    __shared__ float vs[4][128];
    __shared__ float red[2];
    int t = threadIdx.x;
    int row0 = blockIdx.x * 4;
    for (int r = 0; r < 4; ++r) {
        int row = row0 + r;
        vs[r][t] = (row < NNODES) ? fmaxf(Om[(long)row * CDIM + t], 0.f) : 0.f;
    }
    __syncthreads();
    float b = kb[t];
    float a0 = b, a1 = b, a2 = b, a3 = b;
    for (int k = 0; k < CDIM; ++k) {
        float wv = kw[k * CDIM + t];
        a0 = fmaf(vs[0][k], wv, a0);
        a1 = fmaf(vs[1][k], wv, a1);
        a2 = fmaf(vs[2][k], wv, a2);
        a3 = fmaf(vs[3][k], wv, a3);
    }
    float qv = q[t];
    float s = 0.f;
    if (row0 + 0 < NNODES) s += qv * tanhf(a0);
    if (row0 + 1 < NNODES) s += qv * tanhf(a1);
    if (row0 + 2 < NNODES) s += qv * tanhf(a2);
    if (row0 + 3 < NNODES) s += qv * tanhf(a3);
    for (int m = 32; m >= 1; m >>= 1) s += __shfl_xor(s, m, 64);
    if ((t & 63) == 0) red[t >> 6] = s;
    __syncthreads();
    if (t == 0) atomicAdd(sacc, red[0] + red[1]);
}

__global__ void attn_finalize_kernel(const float* __restrict__ sacc, float* __restrict__ attn) {
    float s0 = sacc[0] / (float)NNODES;
    float s1 = sacc[1] / (float)NNODES;
    float m = fmaxf(s0, s1);
    float e0 = expf(s0 - m), e1 = expf(s1 - m);
    float inv = 1.f / (e0 + e1);
    attn[0] = e0 * inv;
    attn[1] = e1 * inv;
}

__global__ __launch_bounds__(256)
void combine_kernel(const float* __restrict__ O0, const float* __restrict__ O1,
                    const float* __restrict__ attn, float* __restrict__ Hn) {
    long i = (long)blockIdx.x * blockDim.x + threadIdx.x;
    long total = (long)NNODES * CDIM / 4;
    if (i >= total) return;
    float a0 = attn[0], a1 = attn[1];
    float4 v0 = ((const float4*)O0)[i];
    float4 v1 = ((const float4*)O1)[i];
    float4 o;
    o.x = a0 * fmaxf(v0.x, 0.f) + a1 * fmaxf(v1.x, 0.f);
    o.y = a0 * fmaxf(v0.y, 0.f) + a1 * fmaxf(v1.y, 0.f);
    o.z = a0 * fmaxf(v0.z, 0.f) + a1 * fmaxf(v1.z, 0.f);
    o.w = a0 * fmaxf(v0.w, 0.f) + a1 * fmaxf(v1.w, 0.f);
    ((float4*)Hn)[i] = o;
}

__global__ __launch_bounds__(256)
void final_linear_kernel(const float* __restrict__ Hn, const float* __restrict__ lw,
                         const float* __restrict__ lb, float* __restrict__ out) {
    int idx = blockIdx.x * blockDim.x + threadIdx.x;
    if (idx >= NNODES * FOUT) return;
    int n = idx >> 3, o = idx & 7;
    float acc = lb[o];
    const float* hrow = Hn + (long)n * CDIM;
    for (int k = 0; k < CDIM; ++k) acc = fmaf(hrow[k], lw[k * FOUT + o], acc);
    out[idx] = acc;
}

static void run_layer(const float* X, int K,
                      const float* pw, const float* pb,
                      const float* ats, const float* atd,
                      const float* q, const float* kw, const float* kb,
                      const int* ei0, const int* ei1,
                      float* Hbuf, float* O0, float* O1, float* OutBuf,
                      float* asrc, float* adst, unsigned int* amax, float* ssum,
                      float* sacc, float* attn, hipStream_t stream) {
    const int gproj = (NNODES + 3) / 4;
    proj_kernel<<<gproj, 128, 0, stream>>>(X, K, pw, pb, ats, atd, Hbuf, asrc, adst);

    const int* eis[2] = {ei0, ei1};
    float* Os[2] = {O0, O1};
    const int nh = NNODES * HHEADS;
    const int g_nh = (nh + 255) / 256;
    const int g_eh = (int)(((long)EEDGES * HHEADS + 255) / 256);
    const int g_ec = (int)(((long)EEDGES * CDIM + 255) / 256);

    for (int i = 0; i < 2; ++i) {
        const int* src = eis[i];
        const int* dst = eis[i] + EEDGES;
        const float* asi = asrc + (long)i * nh;
        const float* adi = adst + (long)i * nh;
        hipMemsetAsync(Os[i], 0, (size_t)NNODES * CDIM * sizeof(float), stream);
        init_softmax_kernel<<<g_nh, 256, 0, stream>>>(amax, ssum, nh);
        edge_amax_kernel<<<g_eh, 256, 0, stream>>>(src, dst, asi, adi, amax);
        edge_expsum_kernel<<<g_eh, 256, 0, stream>>>(src, dst, asi, adi, amax, ssum);
        edge_scatter_kernel<<<g_ec, 256, 0, stream>>>(src, dst, asi, adi, amax, ssum, Hbuf, Os[i]);
    }
    hipMemsetAsync(sacc, 0, 2 * sizeof(float), stream);
    score_kernel<<<gproj, 128, 0, stream>>>(O0, kw, kb, q, sacc + 0);
    score_kernel<<<gproj, 128, 0, stream>>>(O1, kw, kb, q, sacc + 1);
    attn_finalize_kernel<<<1, 1, 0, stream>>>(sacc, attn);
    const long q4 = (long)NNODES * CDIM / 4;
    combine_kernel<<<(int)((q4 + 255) / 256), 256, 0, stream>>>(O0, O1, attn, OutBuf);
}

extern "C" void kernel_launch(void* const* d_in, const int* in_sizes, int n_in,
                              void* d_out, int out_size, void* d_ws, size_t ws_size,
                              hipStream_t stream) {
    const float* x          = (const float*)d_in[0];
    const int*   ei_spatial = (const int*)d_in[1];
    const int*   ei_similar = (const int*)d_in[2];
    const float* p1_proj_w  = (const float*)d_in[3];
    const float* p1_proj_b  = (const float*)d_in[4];
    const float* p1_att_src = (const float*)d_in[5];
    const float* p1_att_dst = (const float*)d_in[6];
    const float* p1_q       = (const float*)d_in[7];
    const float* p1_kw      = (const float*)d_in[8];
    const float* p1_kb      = (const float*)d_in[9];
    const float* p2_proj_w  = (const float*)d_in[10];
    const float* p2_proj_b  = (const float*)d_in[11];
    const float* p2_att_src = (const float*)d_in[12];
    const float* p2_att_dst = (const float*)d_in[13];
    const float* p2_q       = (const float*)d_in[14];
    const float* p2_kw      = (const float*)d_in[15];
    const float* p2_kb      = (const float*)d_in[16];
    const float* lin_w      = (const float*)d_in[17];
    const float* lin_b      = (const float*)d_in[18];

    float* ws = (float*)d_ws;
    const size_t nc = (size_t)NNODES * CDIM;
    const size_t nh2 = (size_t)NNODES * HHEADS;

    float* A    = ws;
    float* B    = A + nc;
    float* Cb   = B + nc;
    float* asrc = Cb + nc;               // 2*N*H
    float* adst = asrc + 2 * nh2;        // 2*N*H
    unsigned int* amax = (unsigned int*)(adst + 2 * nh2);  // N*H
    float* ssum = (float*)(amax + nh2);  // N*H
    float* sacc = ssum + nh2;            // 2
    float* attn = sacc + 2;              // 2

    // Layer 1: h1 -> A ; per-type outs -> B, Cb ; combined -> A
    run_layer(x, FIN, p1_proj_w, p1_proj_b, p1_att_src, p1_att_dst,
              p1_q, p1_kw, p1_kb, ei_spatial, ei_similar,
              A, B, Cb, A, asrc, adst, amax, ssum, sacc, attn, stream);

    // Layer 2: X = A ; h2 -> B ; per-type outs -> Cb, A ; combined -> B
    run_layer(A, CDIM, p2_proj_w, p2_proj_b, p2_att_src, p2_att_dst,
              p2_q, p2_kw, p2_kb, ei_spatial, ei_similar,
              B, Cb, A, B, asrc, adst, amax, ssum, sacc, attn, stream);

    // Final classifier
    const int gfin = (NNODES * FOUT + 255) / 256;
    final_linear_kernel<<<gfin, 256, 0, stream>>>(B, lin_w, lin_b, (float*)d_out);
}

// Round 2
// 2267.888 us; speedup vs baseline: 1.3335x; 1.3335x over previous
//
#include <hip/hip_runtime.h>

#define NNODES 100000
#define EEDGES 600000
#define CDIM 128
#define HHEADS 2
#define DDIM 64
#define FIN 64
#define FOUT 8
#define NEG 0.2f

// ---- ordered-uint encoding for float atomicMax ----
__device__ __forceinline__ unsigned int enc_f32(float f) {
    unsigned int u = __float_as_uint(f);
    return (u & 0x80000000u) ? ~u : (u | 0x80000000u);
}
__device__ __forceinline__ float dec_f32(unsigned int e) {
    unsigned int u = (e & 0x80000000u) ? (e & 0x7FFFFFFFu) : ~e;
    return __uint_as_float(u);
}

__device__ __forceinline__ float tanh_fast(float x) {
    float e = __expf(2.f * x);
    return 1.f - 2.f / (e + 1.f);  // stable: x->+inf => 1, x->-inf => -1
}

// ============ register-tiled GEMM core: 32 rows/block, 256 threads ============
// thread tile: 4 rows x 4 channels (16 accumulators).
// Weights W[K][128] staged into LDS transposed + XOR-swizzled (16B granules):
//   element (k,c) -> kws[c*K + (((k>>2) ^ (c&7))<<2) + (k&3)]
// Rows read from global as float4 (L1 broadcast across lanes sharing a row).
template<int K, bool RELU_IN>
__device__ __forceinline__ void gemm_tile(const float* __restrict__ X,
                                          const float* __restrict__ W,
                                          const float* __restrict__ bias,
                                          int row0, float acc[4][4], float* kws) {
    int tid = threadIdx.x;
    for (int i = tid; i < K * CDIM; i += 256) {
        int c = i & 127;
        int k = i >> 7;
        kws[c * K + (((k >> 2) ^ (c & 7)) << 2) + (k & 3)] = W[k * CDIM + c];
    }
    __syncthreads();
    int rb = tid >> 5;   // 0..7 -> row group
    int cb = tid & 31;   // channel base
#pragma unroll
    for (int j = 0; j < 4; ++j) {
        float b = bias[cb + 32 * j];
#pragma unroll
        for (int r = 0; r < 4; ++r) acc[r][j] = b;
    }
    const float* xrow[4];
#pragma unroll
    for (int r = 0; r < 4; ++r) xrow[r] = X + (long)(row0 + rb * 4 + r) * K;

    for (int k0 = 0; k0 < K; k0 += 4) {
        float4 xr[4];
#pragma unroll
        for (int r = 0; r < 4; ++r) {
            xr[r] = *(const float4*)(xrow[r] + k0);
            if (RELU_IN) {
                xr[r].x = fmaxf(xr[r].x, 0.f);
                xr[r].y = fmaxf(xr[r].y, 0.f);
                xr[r].z = fmaxf(xr[r].z, 0.f);
                xr[r].w = fmaxf(xr[r].w, 0.f);
            }
        }
        float4 wv[4];
#pragma unroll
        for (int j = 0; j < 4; ++j) {
            int c = cb + 32 * j;
            wv[j] = *(const float4*)(kws + c * K + ((((k0 >> 2)) ^ (c & 7)) << 2));
        }
#pragma unroll
        for (int r = 0; r < 4; ++r) {
#pragma unroll
            for (int j = 0; j < 4; ++j) {
                acc[r][j] = fmaf(xr[r].x, wv[j].x, acc[r][j]);
                acc[r][j] = fmaf(xr[r].y, wv[j].y, acc[r][j]);
                acc[r][j] = fmaf(xr[r].z, wv[j].z, acc[r][j]);
                acc[r][j] = fmaf(xr[r].w, wv[j].w, acc[r][j]);
            }
        }
    }
}

// ---- projection: H = X@W + b, fused per-edge-type per-head attention dots ----
template<int K>
__global__ __launch_bounds__(256)
void proj_kernel2(const float* __restrict__ X, const float* __restrict__ W,
                  const float* __restrict__ bias,
                  const float* __restrict__ att_src, const float* __restrict__ att_dst,
                  float* __restrict__ Hout,
                  float* __restrict__ a_src, float* __restrict__ a_dst) {
    __shared__ float kws[K * CDIM];
    float acc[4][4];
    int row0 = blockIdx.x * 32;
    gemm_tile<K, false>(X, W, bias, row0, acc, kws);
    int tid = threadIdx.x, rb = tid >> 5, cb = tid & 31;
#pragma unroll
    for (int r = 0; r < 4; ++r) {
        int row = row0 + rb * 4 + r;
#pragma unroll
        for (int j = 0; j < 4; ++j) Hout[(long)row * CDIM + cb + 32 * j] = acc[r][j];
    }
    float asv[2][4], adv[2][4];
#pragma unroll
    for (int i = 0; i < 2; ++i)
#pragma unroll
        for (int j = 0; j < 4; ++j) {
            asv[i][j] = att_src[i * CDIM + cb + 32 * j];
            adv[i][j] = att_dst[i * CDIM + cb + 32 * j];
        }
#pragma unroll
    for (int i = 0; i < 2; ++i) {
#pragma unroll
        for (int r = 0; r < 4; ++r) {
            // head 0 = channels 0..63 (j=0,1); head 1 = channels 64..127 (j=2,3)
            float s0 = acc[r][0] * asv[i][0] + acc[r][1] * asv[i][1];
            float s1 = acc[r][2] * asv[i][2] + acc[r][3] * asv[i][3];
            float d0 = acc[r][0] * adv[i][0] + acc[r][1] * adv[i][1];
            float d1 = acc[r][2] * adv[i][2] + acc[r][3] * adv[i][3];
#pragma unroll
            for (int m = 16; m >= 1; m >>= 1) {
                s0 += __shfl_xor(s0, m, 64);
                s1 += __shfl_xor(s1, m, 64);
                d0 += __shfl_xor(d0, m, 64);
                d1 += __shfl_xor(d1, m, 64);
            }
            if (cb == 0) {
                int row = row0 + rb * 4 + r;
                long base = (long)i * NNODES * HHEADS + (long)row * HHEADS;
                a_src[base + 0] = s0;
                a_src[base + 1] = s1;
                a_dst[base + 0] = d0;
                a_dst[base + 1] = d1;
            }
        }
    }
}

// ---- semantic score: sacc += sum_n q . tanh(relu(Om[n]) @ kw + kb) ----
__global__ __launch_bounds__(256)
void score_kernel2(const float* __restrict__ Om, const float* __restrict__ kw,
                   const float* __restrict__ kb, const float* __restrict__ q,
                   float* __restrict__ sacc) {
    __shared__ float kws[CDIM * CDIM];
    float acc[4][4];
    int row0 = blockIdx.x * 32;
    gemm_tile<CDIM, true>(Om, kw, kb, row0, acc, kws);
    int tid = threadIdx.x, cb = tid & 31;
    float qv[4];
#pragma unroll
    for (int j = 0; j < 4; ++j) qv[j] = q[cb + 32 * j];
    float s = 0.f;
#pragma unroll
    for (int r = 0; r < 4; ++r)
#pragma unroll
        for (int j = 0; j < 4; ++j) s += qv[j] * tanh_fast(acc[r][j]);
#pragma unroll
    for (int m = 32; m >= 1; m >>= 1) s += __shfl_xor(s, m, 64);
    if ((tid & 63) == 0) atomicAdd(sacc, s);
}

__global__ void init_softmax_kernel(unsigned int* __restrict__ amax,
                                    float* __restrict__ ssum, int n) {
    int i = blockIdx.x * blockDim.x + threadIdx.x;
    if (i < n) { amax[i] = 0x007FFFFFu; /* enc(-inf) */ ssum[i] = 0.f; }
}

__device__ __forceinline__ float edge_raw(const float* __restrict__ as,
                                          const float* __restrict__ ad,
                                          int s, int dt, int hh) {
    float raw = as[s * HHEADS + hh] + ad[dt * HHEADS + hh];
    return raw >= 0.f ? raw : NEG * raw;
}

__global__ void edge_amax_kernel(const int* __restrict__ src, const int* __restrict__ dst,
                                 const float* __restrict__ as, const float* __restrict__ ad,
                                 unsigned int* __restrict__ amax) {
    int idx = blockIdx.x * blockDim.x + threadIdx.x;
    if (idx >= EEDGES * HHEADS) return;
    int e = idx >> 1, hh = idx & 1;
    int s = src[e], dt = dst[e];
    float raw = edge_raw(as, ad, s, dt, hh);
    atomicMax(&amax[dt * HHEADS + hh], enc_f32(raw));
}

__global__ void edge_expsum_kernel(const int* __restrict__ src, const int* __restrict__ dst,
                                   const float* __restrict__ as, const float* __restrict__ ad,
                                   const unsigned int* __restrict__ amax,
                                   float* __restrict__ ssum) {
    int idx = blockIdx.x * blockDim.x + threadIdx.x;
    if (idx >= EEDGES * HHEADS) return;
    int e = idx >> 1, hh = idx & 1;
    int s = src[e], dt = dst[e];
    float raw = edge_raw(as, ad, s, dt, hh);
    float m = dec_f32(amax[dt * HHEADS + hh]);
    atomicAdd(&ssum[dt * HHEADS + hh], expf(raw - m));
}

__global__ __launch_bounds__(256)
void edge_scatter_kernel(const int* __restrict__ src, const int* __restrict__ dst,
                         const float* __restrict__ as, const float* __restrict__ ad,
                         const unsigned int* __restrict__ amax, const float* __restrict__ ssum,
                         const float* __restrict__ Hfeat, float* __restrict__ Out) {
    long idx = (long)blockIdx.x * blockDim.x + threadIdx.x;
    if (idx >= (long)EEDGES * CDIM) return;
    int e = (int)(idx >> 7);
    int c = (int)(idx & 127);
    int hh = c >> 6;
    int s = src[e], dt = dst[e];
    float raw = edge_raw(as, ad, s, dt, hh);
    float m = dec_f32(amax[dt * HHEADS + hh]);
    float alpha = expf(raw - m) / (ssum[dt * HHEADS + hh] + 1e-16f);
    float val = Hfeat[(long)s * CDIM + c] * alpha;
    atomicAdd(&Out[(long)dt * CDIM + c], val);
}

__global__ void attn_finalize_kernel(const float* __restrict__ sacc, float* __restrict__ attn) {
    float s0 = sacc[0] / (float)NNODES;
    float s1 = sacc[1] / (float)NNODES;
    float m = fmaxf(s0, s1);
    float e0 = expf(s0 - m), e1 = expf(s1 - m);
    float inv = 1.f / (e0 + e1);
    attn[0] = e0 * inv;
    attn[1] = e1 * inv;
}

__global__ __launch_bounds__(256)
void combine_kernel(const float* __restrict__ O0, const float* __restrict__ O1,
                    const float* __restrict__ attn, float* __restrict__ Hn) {
    long i = (long)blockIdx.x * blockDim.x + threadIdx.x;
    long total = (long)NNODES * CDIM / 4;
    if (i >= total) return;
    float a0 = attn[0], a1 = attn[1];
    float4 v0 = ((const float4*)O0)[i];
    float4 v1 = ((const float4*)O1)[i];
    float4 o;
    o.x = a0 * fmaxf(v0.x, 0.f) + a1 * fmaxf(v1.x, 0.f);
    o.y = a0 * fmaxf(v0.y, 0.f) + a1 * fmaxf(v1.y, 0.f);
    o.z = a0 * fmaxf(v0.z, 0.f) + a1 * fmaxf(v1.z, 0.f);
    o.w = a0 * fmaxf(v0.w, 0.f) + a1 * fmaxf(v1.w, 0.f);
    ((float4*)Hn)[i] = o;
}

__global__ __launch_bounds__(256)
void final_linear_kernel(const float* __restrict__ Hn, const float* __restrict__ lw,
                         const float* __restrict__ lb, float* __restrict__ out) {
    __shared__ float lws[CDIM * FOUT];
    int tid = threadIdx.x;
    for (int i = tid; i < CDIM * FOUT; i += 256) lws[i] = lw[i];
    __syncthreads();
    int idx = blockIdx.x * 256 + tid;
    if (idx >= NNODES * FOUT) return;
    int n = idx >> 3, o = idx & 7;
    const float4* row = (const float4*)(Hn + (long)n * CDIM);
    float acc = lb[o];
#pragma unroll
    for (int k4 = 0; k4 < 32; ++k4) {
        float4 v = row[k4];
        acc = fmaf(v.x, lws[(k4 * 4 + 0) * FOUT + o], acc);
        acc = fmaf(v.y, lws[(k4 * 4 + 1) * FOUT + o], acc);
        acc = fmaf(v.z, lws[(k4 * 4 + 2) * FOUT + o], acc);
        acc = fmaf(v.w, lws[(k4 * 4 + 3) * FOUT + o], acc);
    }
    out[idx] = acc;
}

static void run_layer(const float* X, int K,
                      const float* pw, const float* pb,
                      const float* ats, const float* atd,
                      const float* q, const float* kw, const float* kb,
                      const int* ei0, const int* ei1,
                      float* Hbuf, float* O0, float* O1, float* OutBuf,
                      float* asrc, float* adst, unsigned int* amax, float* ssum,
                      float* sacc, float* attn, hipStream_t stream) {
    const int gtile = NNODES / 32;  // 3125 exactly
    if (K == 64)
        proj_kernel2<64><<<gtile, 256, 0, stream>>>(X, pw, pb, ats, atd, Hbuf, asrc, adst);
    else
        proj_kernel2<128><<<gtile, 256, 0, stream>>>(X, pw, pb, ats, atd, Hbuf, asrc, adst);

    const int* eis[2] = {ei0, ei1};
    float* Os[2] = {O0, O1};
    const int nh = NNODES * HHEADS;
    const int g_nh = (nh + 255) / 256;
    const int g_eh = (int)(((long)EEDGES * HHEADS + 255) / 256);
    const int g_ec = (int)(((long)EEDGES * CDIM + 255) / 256);

    for (int i = 0; i < 2; ++i) {
        const int* src = eis[i];
        const int* dst = eis[i] + EEDGES;
        const float* asi = asrc + (long)i * nh;
        const float* adi = adst + (long)i * nh;
        hipMemsetAsync(Os[i], 0, (size_t)NNODES * CDIM * sizeof(float), stream);
        init_softmax_kernel<<<g_nh, 256, 0, stream>>>(amax, ssum, nh);
        edge_amax_kernel<<<g_eh, 256, 0, stream>>>(src, dst, asi, adi, amax);
        edge_expsum_kernel<<<g_eh, 256, 0, stream>>>(src, dst, asi, adi, amax, ssum);
        edge_scatter_kernel<<<g_ec, 256, 0, stream>>>(src, dst, asi, adi, amax, ssum, Hbuf, Os[i]);
    }
    hipMemsetAsync(sacc, 0, 2 * sizeof(float), stream);
    score_kernel2<<<gtile, 256, 0, stream>>>(O0, kw, kb, q, sacc + 0);
    score_kernel2<<<gtile, 256, 0, stream>>>(O1, kw, kb, q, sacc + 1);
    attn_finalize_kernel<<<1, 1, 0, stream>>>(sacc, attn);
    const long q4 = (long)NNODES * CDIM / 4;
    combine_kernel<<<(int)((q4 + 255) / 256), 256, 0, stream>>>(O0, O1, attn, OutBuf);
}

extern "C" void kernel_launch(void* const* d_in, const int* in_sizes, int n_in,
                              void* d_out, int out_size, void* d_ws, size_t ws_size,
                              hipStream_t stream) {
    const float* x          = (const float*)d_in[0];
    const int*   ei_spatial = (const int*)d_in[1];
    const int*   ei_similar = (const int*)d_in[2];
    const float* p1_proj_w  = (const float*)d_in[3];
    const float* p1_proj_b  = (const float*)d_in[4];
    const float* p1_att_src = (const float*)d_in[5];
    const float* p1_att_dst = (const float*)d_in[6];
    const float* p1_q       = (const float*)d_in[7];
    const float* p1_kw      = (const float*)d_in[8];
    const float* p1_kb      = (const float*)d_in[9];
    const float* p2_proj_w  = (const float*)d_in[10];
    const float* p2_proj_b  = (const float*)d_in[11];
    const float* p2_att_src = (const float*)d_in[12];
    const float* p2_att_dst = (const float*)d_in[13];
    const float* p2_q       = (const float*)d_in[14];
    const float* p2_kw      = (const float*)d_in[15];
    const float* p2_kb      = (const float*)d_in[16];
    const float* lin_w      = (const float*)d_in[17];
    const float* lin_b      = (const float*)d_in[18];

    float* ws = (float*)d_ws;
    const size_t nc = (size_t)NNODES * CDIM;
    const size_t nh2 = (size_t)NNODES * HHEADS;

    float* A    = ws;
    float* B    = A + nc;
    float* Cb   = B + nc;
    float* asrc = Cb + nc;               // 2*N*H
    float* adst = asrc + 2 * nh2;        // 2*N*H
    unsigned int* amax = (unsigned int*)(adst + 2 * nh2);  // N*H
    float* ssum = (float*)(amax + nh2);  // N*H
    float* sacc = ssum + nh2;            // 2
    float* attn = sacc + 2;              // 2

    // Layer 1: h1 -> A ; per-type outs -> B, Cb ; combined -> A
    run_layer(x, FIN, p1_proj_w, p1_proj_b, p1_att_src, p1_att_dst,
              p1_q, p1_kw, p1_kb, ei_spatial, ei_similar,
              A, B, Cb, A, asrc, adst, amax, ssum, sacc, attn, stream);

    // Layer 2: X = A ; h2 -> B ; per-type outs -> Cb, A ; combined -> B
    run_layer(A, CDIM, p2_proj_w, p2_proj_b, p2_att_src, p2_att_dst,
              p2_q, p2_kw, p2_kb, ei_spatial, ei_similar,
              B, Cb, A, B, asrc, adst, amax, ssum, sacc, attn, stream);

    // Final classifier
    const int gfin = (NNODES * FOUT + 255) / 256;
    final_linear_kernel<<<gfin, 256, 0, stream>>>(B, lin_w, lin_b, (float*)d_out);
}

// Round 3
// 1774.419 us; speedup vs baseline: 1.7043x; 1.2781x over previous
//
#include <hip/hip_runtime.h>

#define NNODES 100000
#define EEDGES 600000
#define CDIM 128
#define HHEADS 2
#define DDIM 64
#define FIN 64
#define FOUT 8
#define NEG 0.2f

__device__ __forceinline__ float tanh_fast(float x) {
    float e = __expf(2.f * x);
    return 1.f - 2.f / (e + 1.f);  // stable: x->+inf => 1, x->-inf => -1
}

// ============ register-tiled GEMM core: 32 rows/block, 256 threads ============
// thread tile: 4 rows x 4 channels (16 accumulators).
// Weights W[K][128] staged into LDS transposed + XOR-swizzled (16B granules).
template<int K, bool RELU_IN>
__device__ __forceinline__ void gemm_tile(const float* __restrict__ X,
                                          const float* __restrict__ W,
                                          const float* __restrict__ bias,
                                          int row0, float acc[4][4], float* kws) {
    int tid = threadIdx.x;
    for (int i = tid; i < K * CDIM; i += 256) {
        int c = i & 127;
        int k = i >> 7;
        kws[c * K + (((k >> 2) ^ (c & 7)) << 2) + (k & 3)] = W[k * CDIM + c];
    }
    __syncthreads();
    int rb = tid >> 5;   // 0..7 -> row group
    int cb = tid & 31;   // channel base
#pragma unroll
    for (int j = 0; j < 4; ++j) {
        float b = bias[cb + 32 * j];
#pragma unroll
        for (int r = 0; r < 4; ++r) acc[r][j] = b;
    }
    const float* xrow[4];
#pragma unroll
    for (int r = 0; r < 4; ++r) xrow[r] = X + (long)(row0 + rb * 4 + r) * K;

    for (int k0 = 0; k0 < K; k0 += 4) {
        float4 xr[4];
#pragma unroll
        for (int r = 0; r < 4; ++r) {
            xr[r] = *(const float4*)(xrow[r] + k0);
            if (RELU_IN) {
                xr[r].x = fmaxf(xr[r].x, 0.f);
                xr[r].y = fmaxf(xr[r].y, 0.f);
                xr[r].z = fmaxf(xr[r].z, 0.f);
                xr[r].w = fmaxf(xr[r].w, 0.f);
            }
        }
        float4 wv[4];
#pragma unroll
        for (int j = 0; j < 4; ++j) {
            int c = cb + 32 * j;
            wv[j] = *(const float4*)(kws + c * K + ((((k0 >> 2)) ^ (c & 7)) << 2));
        }
#pragma unroll
        for (int r = 0; r < 4; ++r) {
#pragma unroll
            for (int j = 0; j < 4; ++j) {
                acc[r][j] = fmaf(xr[r].x, wv[j].x, acc[r][j]);
                acc[r][j] = fmaf(xr[r].y, wv[j].y, acc[r][j]);
                acc[r][j] = fmaf(xr[r].z, wv[j].z, acc[r][j]);
                acc[r][j] = fmaf(xr[r].w, wv[j].w, acc[r][j]);
            }
        }
    }
}

// ---- projection: H = X@W + b, fused per-edge-type per-head attention dots ----
template<int K>
__global__ __launch_bounds__(256)
void proj_kernel2(const float* __restrict__ X, const float* __restrict__ W,
                  const float* __restrict__ bias,
                  const float* __restrict__ att_src, const float* __restrict__ att_dst,
                  float* __restrict__ Hout,
                  float* __restrict__ a_src, float* __restrict__ a_dst) {
    __shared__ float kws[K * CDIM];
    float acc[4][4];
    int row0 = blockIdx.x * 32;
    gemm_tile<K, false>(X, W, bias, row0, acc, kws);
    int tid = threadIdx.x, rb = tid >> 5, cb = tid & 31;
#pragma unroll
    for (int r = 0; r < 4; ++r) {
        int row = row0 + rb * 4 + r;
#pragma unroll
        for (int j = 0; j < 4; ++j) Hout[(long)row * CDIM + cb + 32 * j] = acc[r][j];
    }
    float asv[2][4], adv[2][4];
#pragma unroll
    for (int i = 0; i < 2; ++i)
#pragma unroll
        for (int j = 0; j < 4; ++j) {
            asv[i][j] = att_src[i * CDIM + cb + 32 * j];
            adv[i][j] = att_dst[i * CDIM + cb + 32 * j];
        }
#pragma unroll
    for (int i = 0; i < 2; ++i) {
#pragma unroll
        for (int r = 0; r < 4; ++r) {
            // head 0 = channels 0..63 (j=0,1); head 1 = channels 64..127 (j=2,3)
            float s0 = acc[r][0] * asv[i][0] + acc[r][1] * asv[i][1];
            float s1 = acc[r][2] * asv[i][2] + acc[r][3] * asv[i][3];
            float d0 = acc[r][0] * adv[i][0] + acc[r][1] * adv[i][1];
            float d1 = acc[r][2] * adv[i][2] + acc[r][3] * adv[i][3];
#pragma unroll
            for (int m = 16; m >= 1; m >>= 1) {
                s0 += __shfl_xor(s0, m, 64);
                s1 += __shfl_xor(s1, m, 64);
                d0 += __shfl_xor(d0, m, 64);
                d1 += __shfl_xor(d1, m, 64);
            }
            if (cb == 0) {
                int row = row0 + rb * 4 + r;
                long base = (long)i * NNODES * HHEADS + (long)row * HHEADS;
                a_src[base + 0] = s0;
                a_src[base + 1] = s1;
                a_dst[base + 0] = d0;
                a_dst[base + 1] = d1;
            }
        }
    }
}

// ---- semantic score: sacc += sum_n q . tanh(relu(Om[n]) @ kw + kb) ----
__global__ __launch_bounds__(256)
void score_kernel2(const float* __restrict__ Om, const float* __restrict__ kw,
                   const float* __restrict__ kb, const float* __restrict__ q,
                   float* __restrict__ sacc) {
    __shared__ float kws[CDIM * CDIM];
    float acc[4][4];
    int row0 = blockIdx.x * 32;
    gemm_tile<CDIM, true>(Om, kw, kb, row0, acc, kws);
    int tid = threadIdx.x, cb = tid & 31;
    float qv[4];
#pragma unroll
    for (int j = 0; j < 4; ++j) qv[j] = q[cb + 32 * j];
    float s = 0.f;
#pragma unroll
    for (int r = 0; r < 4; ++r)
#pragma unroll
        for (int j = 0; j < 4; ++j) s += qv[j] * tanh_fast(acc[r][j]);
#pragma unroll
    for (int m = 32; m >= 1; m >>= 1) s += __shfl_xor(s, m, 64);
    if ((tid & 63) == 0) atomicAdd(sacc, s);
}

// ============ CSR build (per edge type, structure shared by both layers) ============
__global__ void hist_kernel(const int* __restrict__ dst, int* __restrict__ deg) {
    int e = blockIdx.x * blockDim.x + threadIdx.x;
    if (e < EEDGES) atomicAdd(&deg[dst[e]], 1);
}

__global__ __launch_bounds__(1024)
void scan_kernel(const int* __restrict__ deg, int* __restrict__ rowptr) {
    __shared__ int tot[1024];
    const int CH = (NNODES + 1023) / 1024;  // 98
    int t = threadIdx.x;
    int beg = t * CH;
    int end = beg + CH < NNODES ? beg + CH : NNODES;
    int s = 0;
    for (int i = beg; i < end; ++i) s += deg[i];
    tot[t] = s;
    __syncthreads();
    if (t == 0) {
        int run = 0;
        for (int i = 0; i < 1024; ++i) { int v = tot[i]; tot[i] = run; run += v; }
    }
    __syncthreads();
    int run = tot[t];
    for (int i = beg; i < end; ++i) { rowptr[i] = run; run += deg[i]; }
    if (beg <= NNODES && end == NNODES) rowptr[NNODES] = run;
}

__global__ void fill_kernel(const int* __restrict__ src, const int* __restrict__ dst,
                            int* __restrict__ cursor, int* __restrict__ csr_src) {
    int e = blockIdx.x * blockDim.x + threadIdx.x;
    if (e < EEDGES) {
        int pos = atomicAdd(&cursor[dst[e]], 1);
        csr_src[pos] = src[e];
    }
}

// ============ fused edge softmax + aggregation: one wave per destination node ============
// lane c handles channels c (head 0) and c+64 (head 1).
__global__ __launch_bounds__(256)
void seg_aggregate_kernel(const int* __restrict__ rowptr, const int* __restrict__ csr_src,
                          const float* __restrict__ asv, const float* __restrict__ adv,
                          const float* __restrict__ Hfeat, float* __restrict__ Out) {
    int node = blockIdx.x * 4 + (threadIdx.x >> 6);
    if (node >= NNODES) return;
    int lane = threadIdx.x & 63;
    int start = rowptr[node], end = rowptr[node + 1];
    int deg = end - start;
    float ad0 = adv[node * 2 + 0], ad1 = adv[node * 2 + 1];

    // pass 1: segment max per head
    float m0 = -1e30f, m1 = -1e30f;
    for (int i = lane; i < deg; i += 64) {
        int s = csr_src[start + i];
        float r0 = asv[s * 2 + 0] + ad0; r0 = r0 >= 0.f ? r0 : NEG * r0;
        float r1 = asv[s * 2 + 1] + ad1; r1 = r1 >= 0.f ? r1 : NEG * r1;
        m0 = fmaxf(m0, r0); m1 = fmaxf(m1, r1);
    }
#pragma unroll
    for (int t = 32; t >= 1; t >>= 1) {
        m0 = fmaxf(m0, __shfl_xor(m0, t, 64));
        m1 = fmaxf(m1, __shfl_xor(m1, t, 64));
    }
    // pass 2: sum of exp
    float s0 = 0.f, s1 = 0.f;
    for (int i = lane; i < deg; i += 64) {
        int s = csr_src[start + i];
        float r0 = asv[s * 2 + 0] + ad0; r0 = r0 >= 0.f ? r0 : NEG * r0;
        float r1 = asv[s * 2 + 1] + ad1; r1 = r1 >= 0.f ? r1 : NEG * r1;
        s0 += __expf(r0 - m0); s1 += __expf(r1 - m1);
    }
#pragma unroll
    for (int t = 32; t >= 1; t >>= 1) {
        s0 += __shfl_xor(s0, t, 64);
        s1 += __shfl_xor(s1, t, 64);
    }
    float inv0 = 1.f / (s0 + 1e-16f);
    float inv1 = 1.f / (s1 + 1e-16f);

    // pass 3: weighted gather-accumulate (all 64 lanes per edge; 512B/edge coalesced)
    float acc0 = 0.f, acc1 = 0.f;
    for (int i = 0; i < deg; ++i) {
        int s = csr_src[start + i];
        float r0 = asv[s * 2 + 0] + ad0; r0 = r0 >= 0.f ? r0 : NEG * r0;
        float r1 = asv[s * 2 + 1] + ad1; r1 = r1 >= 0.f ? r1 : NEG * r1;
        float a0 = __expf(r0 - m0) * inv0;
        float a1 = __expf(r1 - m1) * inv1;
        const float* hrow = Hfeat + (long)s * CDIM;
        acc0 = fmaf(hrow[lane], a0, acc0);
        acc1 = fmaf(hrow[64 + lane], a1, acc1);
    }
    Out[(long)node * CDIM + lane] = acc0;
    Out[(long)node * CDIM + 64 + lane] = acc1;
}

__global__ void attn_finalize_kernel(const float* __restrict__ sacc, float* __restrict__ attn) {
    float s0 = sacc[0] / (float)NNODES;
    float s1 = sacc[1] / (float)NNODES;
    float m = fmaxf(s0, s1);
    float e0 = expf(s0 - m), e1 = expf(s1 - m);
    float inv = 1.f / (e0 + e1);
    attn[0] = e0 * inv;
    attn[1] = e1 * inv;
}

__global__ __launch_bounds__(256)
void combine_kernel(const float* __restrict__ O0, const float* __restrict__ O1,
                    const float* __restrict__ attn, float* __restrict__ Hn) {
    long i = (long)blockIdx.x * blockDim.x + threadIdx.x;
    long total = (long)NNODES * CDIM / 4;
    if (i >= total) return;
    float a0 = attn[0], a1 = attn[1];
    float4 v0 = ((const float4*)O0)[i];
    float4 v1 = ((const float4*)O1)[i];
    float4 o;
    o.x = a0 * fmaxf(v0.x, 0.f) + a1 * fmaxf(v1.x, 0.f);
    o.y = a0 * fmaxf(v0.y, 0.f) + a1 * fmaxf(v1.y, 0.f);
    o.z = a0 * fmaxf(v0.z, 0.f) + a1 * fmaxf(v1.z, 0.f);
    o.w = a0 * fmaxf(v0.w, 0.f) + a1 * fmaxf(v1.w, 0.f);
    ((float4*)Hn)[i] = o;
}

__global__ __launch_bounds__(256)
void final_linear_kernel(const float* __restrict__ Hn, const float* __restrict__ lw,
                         const float* __restrict__ lb, float* __restrict__ out) {
    __shared__ float lws[CDIM * FOUT];
    int tid = threadIdx.x;
    for (int i = tid; i < CDIM * FOUT; i += 256) lws[i] = lw[i];
    __syncthreads();
    int idx = blockIdx.x * 256 + tid;
    if (idx >= NNODES * FOUT) return;
    int n = idx >> 3, o = idx & 7;
    const float4* row = (const float4*)(Hn + (long)n * CDIM);
    float acc = lb[o];
#pragma unroll
    for (int k4 = 0; k4 < 32; ++k4) {
        float4 v = row[k4];
        acc = fmaf(v.x, lws[(k4 * 4 + 0) * FOUT + o], acc);
        acc = fmaf(v.y, lws[(k4 * 4 + 1) * FOUT + o], acc);
        acc = fmaf(v.z, lws[(k4 * 4 + 2) * FOUT + o], acc);
        acc = fmaf(v.w, lws[(k4 * 4 + 3) * FOUT + o], acc);
    }
    out[idx] = acc;
}

static void run_layer(const float* X, int K,
                      const float* pw, const float* pb,
                      const float* ats, const float* atd,
                      const float* q, const float* kw, const float* kb,
                      const int* rowptr0, const int* csr0,
                      const int* rowptr1, const int* csr1,
                      float* Hbuf, float* O0, float* O1, float* OutBuf,
                      float* asrc, float* adst,
                      float* sacc, float* attn, hipStream_t stream) {
    const int gtile = NNODES / 32;  // 3125 exactly
    if (K == 64)
        proj_kernel2<64><<<gtile, 256, 0, stream>>>(X, pw, pb, ats, atd, Hbuf, asrc, adst);
    else
        proj_kernel2<128><<<gtile, 256, 0, stream>>>(X, pw, pb, ats, atd, Hbuf, asrc, adst);

    const int nh = NNODES * HHEADS;
    const int gseg = (NNODES + 3) / 4;
    seg_aggregate_kernel<<<gseg, 256, 0, stream>>>(rowptr0, csr0, asrc, adst, Hbuf, O0);
    seg_aggregate_kernel<<<gseg, 256, 0, stream>>>(rowptr1, csr1, asrc + nh, adst + nh, Hbuf, O1);

    hipMemsetAsync(sacc, 0, 2 * sizeof(float), stream);
    score_kernel2<<<gtile, 256, 0, stream>>>(O0, kw, kb, q, sacc + 0);
    score_kernel2<<<gtile, 256, 0, stream>>>(O1, kw, kb, q, sacc + 1);
    attn_finalize_kernel<<<1, 1, 0, stream>>>(sacc, attn);
    const long q4 = (long)NNODES * CDIM / 4;
    combine_kernel<<<(int)((q4 + 255) / 256), 256, 0, stream>>>(O0, O1, attn, OutBuf);
}

extern "C" void kernel_launch(void* const* d_in, const int* in_sizes, int n_in,
                              void* d_out, int out_size, void* d_ws, size_t ws_size,
                              hipStream_t stream) {
    const float* x          = (const float*)d_in[0];
    const int*   ei_spatial = (const int*)d_in[1];
    const int*   ei_similar = (const int*)d_in[2];
    const float* p1_proj_w  = (const float*)d_in[3];
    const float* p1_proj_b  = (const float*)d_in[4];
    const float* p1_att_src = (const float*)d_in[5];
    const float* p1_att_dst = (const float*)d_in[6];
    const float* p1_q       = (const float*)d_in[7];
    const float* p1_kw      = (const float*)d_in[8];
    const float* p1_kb      = (const float*)d_in[9];
    const float* p2_proj_w  = (const float*)d_in[10];
    const float* p2_proj_b  = (const float*)d_in[11];
    const float* p2_att_src = (const float*)d_in[12];
    const float* p2_att_dst = (const float*)d_in[13];
    const float* p2_q       = (const float*)d_in[14];
    const float* p2_kw      = (const float*)d_in[15];
    const float* p2_kb      = (const float*)d_in[16];
    const float* lin_w      = (const float*)d_in[17];
    const float* lin_b      = (const float*)d_in[18];

    float* ws = (float*)d_ws;
    const size_t nc = (size_t)NNODES * CDIM;
    const size_t nh2 = (size_t)NNODES * HHEADS;

    float* A    = ws;
    float* B    = A + nc;
    float* Cb   = B + nc;
    float* asrc = Cb + nc;               // 2*N*H
    float* adst = asrc + 2 * nh2;        // 2*N*H
    float* sacc = adst + 2 * nh2;        // 2
    float* attn = sacc + 2;              // 2
    int* rowptr0 = (int*)(attn + 2);
    int* rowptr1 = rowptr0 + (NNODES + 1);
    int* csr0    = rowptr1 + (NNODES + 1);
    int* csr1    = csr0 + EEDGES;
    int* scratch = csr1 + EEDGES;        // deg/cursor, NNODES ints

    // ---- build CSR for both edge types (structure reused across layers) ----
    const int g_e = (EEDGES + 255) / 256;
    const int* eis[2] = {ei_spatial, ei_similar};
    int* rps[2] = {rowptr0, rowptr1};
    int* csrs[2] = {csr0, csr1};
    for (int i = 0; i < 2; ++i) {
        const int* src = eis[i];
        const int* dst = eis[i] + EEDGES;
        hipMemsetAsync(scratch, 0, NNODES * sizeof(int), stream);
        hist_kernel<<<g_e, 256, 0, stream>>>(dst, scratch);
        scan_kernel<<<1, 1024, 0, stream>>>(scratch, rps[i]);
        hipMemcpyAsync(scratch, rps[i], NNODES * sizeof(int),
                       hipMemcpyDeviceToDevice, stream);
        fill_kernel<<<g_e, 256, 0, stream>>>(src, dst, scratch, csrs[i]);
    }

    // Layer 1: h1 -> A ; per-type outs -> B, Cb ; combined -> A
    run_layer(x, FIN, p1_proj_w, p1_proj_b, p1_att_src, p1_att_dst,
              p1_q, p1_kw, p1_kb, rowptr0, csr0, rowptr1, csr1,
              A, B, Cb, A, asrc, adst, sacc, attn, stream);

    // Layer 2: X = A ; h2 -> B ; per-type outs -> Cb, A ; combined -> B
    run_layer(A, CDIM, p2_proj_w, p2_proj_b, p2_att_src, p2_att_dst,
              p2_q, p2_kw, p2_kb, rowptr0, csr0, rowptr1, csr1,
              B, Cb, A, B, asrc, adst, sacc, attn, stream);

    // Final classifier
    const int gfin = (NNODES * FOUT + 255) / 256;
    final_linear_kernel<<<gfin, 256, 0, stream>>>(B, lin_w, lin_b, (float*)d_out);
}

// Round 4
// 1756.790 us; speedup vs baseline: 1.7214x; 1.0100x over previous
//
#include <hip/hip_runtime.h>

#define NNODES 100000
#define EEDGES 600000
#define CDIM 128
#define HHEADS 2
#define DDIM 64
#define FIN 64
#define FOUT 8
#define NEG 0.2f

__device__ __forceinline__ float tanh_fast(float x) {
    float e = __expf(2.f * x);
    return 1.f - 2.f / (e + 1.f);  // stable: x->+inf => 1, x->-inf => -1
}

// ============ register-tiled GEMM core v3: 32 rows/block, 256 threads ============
// thread (rb=tid>>5, cb=tid&31) owns rows rb*4..+3 and CONTIGUOUS channels 4cb..4cb+3.
// W[K][128] staged in 32-row K-chunks into LDS in NATIVE layout (16 KB): flat float4
// copy -> conflict-free writes; reads wch[k][4cb..] = 32 lanes x contiguous 16B ->
// conflict-free. X read from global float4 (row-group broadcast, L1-resident).
template<int K, bool RELU_IN>
__device__ __forceinline__ void gemm_tile3(const float* __restrict__ X,
                                           const float* __restrict__ W,
                                           const float* __restrict__ bias,
                                           int row0, float acc[4][4], float* wch) {
    int tid = threadIdx.x;
    int rb = tid >> 5, cb = tid & 31;
    int c0 = cb * 4;
#pragma unroll
    for (int j = 0; j < 4; ++j) {
        float b = bias[c0 + j];
#pragma unroll
        for (int r = 0; r < 4; ++r) acc[r][j] = b;
    }
    const float* xbase = X + (long)(row0 + rb * 4) * K;

    for (int kc = 0; kc < K; kc += 32) {
        __syncthreads();
        // stage W rows kc..kc+31: 32*128 floats = 1024 float4, 4 per thread, flat copy
#pragma unroll
        for (int i = 0; i < 4; ++i) {
            int idx = tid + i * 256;
            ((float4*)wch)[idx] = ((const float4*)(W + kc * CDIM))[idx];
        }
        __syncthreads();
#pragma unroll
        for (int k0 = 0; k0 < 32; k0 += 4) {
            float4 xr[4];
#pragma unroll
            for (int r = 0; r < 4; ++r) {
                xr[r] = *(const float4*)(xbase + r * K + kc + k0);
                if (RELU_IN) {
                    xr[r].x = fmaxf(xr[r].x, 0.f);
                    xr[r].y = fmaxf(xr[r].y, 0.f);
                    xr[r].z = fmaxf(xr[r].z, 0.f);
                    xr[r].w = fmaxf(xr[r].w, 0.f);
                }
            }
            float4 wv[4];
#pragma unroll
            for (int kk = 0; kk < 4; ++kk)
                wv[kk] = *(const float4*)(wch + (k0 + kk) * CDIM + c0);
#pragma unroll
            for (int r = 0; r < 4; ++r) {
                const float* xf = (const float*)&xr[r];
#pragma unroll
                for (int kk = 0; kk < 4; ++kk) {
                    const float* wf = (const float*)&wv[kk];
#pragma unroll
                    for (int j = 0; j < 4; ++j)
                        acc[r][j] = fmaf(xf[kk], wf[j], acc[r][j]);
                }
            }
        }
    }
}

// ---- projection: H = X@W + b, fused per-edge-type per-head attention dots ----
template<int K>
__global__ __launch_bounds__(256, 4)
void proj_kernel3(const float* __restrict__ X, const float* __restrict__ W,
                  const float* __restrict__ bias,
                  const float* __restrict__ att_src, const float* __restrict__ att_dst,
                  float* __restrict__ Hout,
                  float* __restrict__ a_src, float* __restrict__ a_dst) {
    __shared__ float wch[32 * CDIM];
    float acc[4][4];
    int row0 = blockIdx.x * 32;
    gemm_tile3<K, false>(X, W, bias, row0, acc, wch);
    int tid = threadIdx.x, rb = tid >> 5, cb = tid & 31;
    int c0 = cb * 4;
#pragma unroll
    for (int r = 0; r < 4; ++r) {
        int row = row0 + rb * 4 + r;
        float4 o = make_float4(acc[r][0], acc[r][1], acc[r][2], acc[r][3]);
        *(float4*)(Hout + (long)row * CDIM + c0) = o;
    }
#pragma unroll
    for (int i = 0; i < 2; ++i) {
        float as4[4], ad4[4];
#pragma unroll
        for (int j = 0; j < 4; ++j) {
            as4[j] = att_src[i * CDIM + c0 + j];
            ad4[j] = att_dst[i * CDIM + c0 + j];
        }
#pragma unroll
        for (int r = 0; r < 4; ++r) {
            float s = acc[r][0] * as4[0] + acc[r][1] * as4[1]
                    + acc[r][2] * as4[2] + acc[r][3] * as4[3];
            float d = acc[r][0] * ad4[0] + acc[r][1] * ad4[1]
                    + acc[r][2] * ad4[2] + acc[r][3] * ad4[3];
            // reduce within 16-lane head groups (head0: cb 0-15, head1: cb 16-31)
#pragma unroll
            for (int m = 8; m >= 1; m >>= 1) {
                s += __shfl_xor(s, m, 64);
                d += __shfl_xor(d, m, 64);
            }
            if ((cb & 15) == 0) {
                int hh = cb >> 4;
                int row = row0 + rb * 4 + r;
                long base = (long)i * NNODES * HHEADS + (long)row * HHEADS + hh;
                a_src[base] = s;
                a_dst[base] = d;
            }
        }
    }
}

// ---- semantic score: sacc += sum_n q . tanh(relu(Om[n]) @ kw + kb) ----
__global__ __launch_bounds__(256, 4)
void score_kernel3(const float* __restrict__ Om, const float* __restrict__ kw,
                   const float* __restrict__ kb, const float* __restrict__ q,
                   float* __restrict__ sacc) {
    __shared__ float wch[32 * CDIM];
    float acc[4][4];
    int row0 = blockIdx.x * 32;
    gemm_tile3<CDIM, true>(Om, kw, kb, row0, acc, wch);
    int tid = threadIdx.x, cb = tid & 31;
    int c0 = cb * 4;
    float qv[4];
#pragma unroll
    for (int j = 0; j < 4; ++j) qv[j] = q[c0 + j];
    float s = 0.f;
#pragma unroll
    for (int r = 0; r < 4; ++r)
#pragma unroll
        for (int j = 0; j < 4; ++j) s += qv[j] * tanh_fast(acc[r][j]);
#pragma unroll
    for (int m = 32; m >= 1; m >>= 1) s += __shfl_xor(s, m, 64);
    if ((tid & 63) == 0) atomicAdd(sacc, s);
}

// ============ CSR build (per edge type, structure shared by both layers) ============
__global__ void hist_kernel(const int* __restrict__ dst, int* __restrict__ deg) {
    int e = blockIdx.x * blockDim.x + threadIdx.x;
    if (e < EEDGES) atomicAdd(&deg[dst[e]], 1);
}

__global__ __launch_bounds__(1024)
void scan_kernel(const int* __restrict__ deg, int* __restrict__ rowptr) {
    __shared__ int tot[1024];
    const int CH = (NNODES + 1023) / 1024;  // 98
    int t = threadIdx.x;
    int beg = t * CH;
    int end = beg + CH < NNODES ? beg + CH : NNODES;
    int s = 0;
    for (int i = beg; i < end; ++i) s += deg[i];
    tot[t] = s;
    __syncthreads();
    if (t == 0) {
        int run = 0;
        for (int i = 0; i < 1024; ++i) { int v = tot[i]; tot[i] = run; run += v; }
    }
    __syncthreads();
    int run = tot[t];
    for (int i = beg; i < end; ++i) { rowptr[i] = run; run += deg[i]; }
    if (beg <= NNODES && end == NNODES) rowptr[NNODES] = run;
}

__global__ void fill_kernel(const int* __restrict__ src, const int* __restrict__ dst,
                            int* __restrict__ cursor, int* __restrict__ csr_src) {
    int e = blockIdx.x * blockDim.x + threadIdx.x;
    if (e < EEDGES) {
        int pos = atomicAdd(&cursor[dst[e]], 1);
        csr_src[pos] = src[e];
    }
}

// ============ fused edge softmax + aggregation: one wave per destination node ============
__global__ __launch_bounds__(256)
void seg_aggregate_kernel(const int* __restrict__ rowptr, const int* __restrict__ csr_src,
                          const float* __restrict__ asv, const float* __restrict__ adv,
                          const float* __restrict__ Hfeat, float* __restrict__ Out) {
    int node = blockIdx.x * 4 + (threadIdx.x >> 6);
    if (node >= NNODES) return;
    int lane = threadIdx.x & 63;
    int start = rowptr[node], end = rowptr[node + 1];
    int deg = end - start;
    float ad0 = adv[node * 2 + 0], ad1 = adv[node * 2 + 1];

    // pass 1: segment max per head
    float m0 = -1e30f, m1 = -1e30f;
    for (int i = lane; i < deg; i += 64) {
        int s = csr_src[start + i];
        float r0 = asv[s * 2 + 0] + ad0; r0 = r0 >= 0.f ? r0 : NEG * r0;
        float r1 = asv[s * 2 + 1] + ad1; r1 = r1 >= 0.f ? r1 : NEG * r1;
        m0 = fmaxf(m0, r0); m1 = fmaxf(m1, r1);
    }
#pragma unroll
    for (int t = 32; t >= 1; t >>= 1) {
        m0 = fmaxf(m0, __shfl_xor(m0, t, 64));
        m1 = fmaxf(m1, __shfl_xor(m1, t, 64));
    }
    // pass 2: sum of exp
    float s0 = 0.f, s1 = 0.f;
    for (int i = lane; i < deg; i += 64) {
        int s = csr_src[start + i];
        float r0 = asv[s * 2 + 0] + ad0; r0 = r0 >= 0.f ? r0 : NEG * r0;
        float r1 = asv[s * 2 + 1] + ad1; r1 = r1 >= 0.f ? r1 : NEG * r1;
        s0 += __expf(r0 - m0); s1 += __expf(r1 - m1);
    }
#pragma unroll
    for (int t = 32; t >= 1; t >>= 1) {
        s0 += __shfl_xor(s0, t, 64);
        s1 += __shfl_xor(s1, t, 64);
    }
    float inv0 = 1.f / (s0 + 1e-16f);
    float inv1 = 1.f / (s1 + 1e-16f);

    // pass 3: weighted gather-accumulate (all 64 lanes per edge; 512B/edge coalesced)
    float acc0 = 0.f, acc1 = 0.f;
    for (int i = 0; i < deg; ++i) {
        int s = csr_src[start + i];
        float r0 = asv[s * 2 + 0] + ad0; r0 = r0 >= 0.f ? r0 : NEG * r0;
        float r1 = asv[s * 2 + 1] + ad1; r1 = r1 >= 0.f ? r1 : NEG * r1;
        float a0 = __expf(r0 - m0) * inv0;
        float a1 = __expf(r1 - m1) * inv1;
        const float* hrow = Hfeat + (long)s * CDIM;
        acc0 = fmaf(hrow[lane], a0, acc0);
        acc1 = fmaf(hrow[64 + lane], a1, acc1);
    }
    Out[(long)node * CDIM + lane] = acc0;
    Out[(long)node * CDIM + 64 + lane] = acc1;
}

__global__ void attn_finalize_kernel(const float* __restrict__ sacc, float* __restrict__ attn) {
    float s0 = sacc[0] / (float)NNODES;
    float s1 = sacc[1] / (float)NNODES;
    float m = fmaxf(s0, s1);
    float e0 = expf(s0 - m), e1 = expf(s1 - m);
    float inv = 1.f / (e0 + e1);
    attn[0] = e0 * inv;
    attn[1] = e1 * inv;
}

__global__ __launch_bounds__(256)
void combine_kernel(const float* __restrict__ O0, const float* __restrict__ O1,
                    const float* __restrict__ attn, float* __restrict__ Hn) {
    long i = (long)blockIdx.x * blockDim.x + threadIdx.x;
    long total = (long)NNODES * CDIM / 4;
    if (i >= total) return;
    float a0 = attn[0], a1 = attn[1];
    float4 v0 = ((const float4*)O0)[i];
    float4 v1 = ((const float4*)O1)[i];
    float4 o;
    o.x = a0 * fmaxf(v0.x, 0.f) + a1 * fmaxf(v1.x, 0.f);
    o.y = a0 * fmaxf(v0.y, 0.f) + a1 * fmaxf(v1.y, 0.f);
    o.z = a0 * fmaxf(v0.z, 0.f) + a1 * fmaxf(v1.z, 0.f);
    o.w = a0 * fmaxf(v0.w, 0.f) + a1 * fmaxf(v1.w, 0.f);
    ((float4*)Hn)[i] = o;
}

__global__ __launch_bounds__(256)
void final_linear_kernel(const float* __restrict__ Hn, const float* __restrict__ lw,
                         const float* __restrict__ lb, float* __restrict__ out) {
    __shared__ float lws[CDIM * FOUT];
    int tid = threadIdx.x;
    for (int i = tid; i < CDIM * FOUT; i += 256) lws[i] = lw[i];
    __syncthreads();
    int idx = blockIdx.x * 256 + tid;
    if (idx >= NNODES * FOUT) return;
    int n = idx >> 3, o = idx & 7;
    const float4* row = (const float4*)(Hn + (long)n * CDIM);
    float acc = lb[o];
#pragma unroll
    for (int k4 = 0; k4 < 32; ++k4) {
        float4 v = row[k4];
        acc = fmaf(v.x, lws[(k4 * 4 + 0) * FOUT + o], acc);
        acc = fmaf(v.y, lws[(k4 * 4 + 1) * FOUT + o], acc);
        acc = fmaf(v.z, lws[(k4 * 4 + 2) * FOUT + o], acc);
        acc = fmaf(v.w, lws[(k4 * 4 + 3) * FOUT + o], acc);
    }
    out[idx] = acc;
}

static void run_layer(const float* X, int K,
                      const float* pw, const float* pb,
                      const float* ats, const float* atd,
                      const float* q, const float* kw, const float* kb,
                      const int* rowptr0, const int* csr0,
                      const int* rowptr1, const int* csr1,
                      float* Hbuf, float* O0, float* O1, float* OutBuf,
                      float* asrc, float* adst,
                      float* sacc, float* attn, hipStream_t stream) {
    const int gtile = NNODES / 32;  // 3125 exactly
    if (K == 64)
        proj_kernel3<64><<<gtile, 256, 0, stream>>>(X, pw, pb, ats, atd, Hbuf, asrc, adst);
    else
        proj_kernel3<128><<<gtile, 256, 0, stream>>>(X, pw, pb, ats, atd, Hbuf, asrc, adst);

    const int nh = NNODES * HHEADS;
    const int gseg = (NNODES + 3) / 4;
    seg_aggregate_kernel<<<gseg, 256, 0, stream>>>(rowptr0, csr0, asrc, adst, Hbuf, O0);
    seg_aggregate_kernel<<<gseg, 256, 0, stream>>>(rowptr1, csr1, asrc + nh, adst + nh, Hbuf, O1);

    hipMemsetAsync(sacc, 0, 2 * sizeof(float), stream);
    score_kernel3<<<gtile, 256, 0, stream>>>(O0, kw, kb, q, sacc + 0);
    score_kernel3<<<gtile, 256, 0, stream>>>(O1, kw, kb, q, sacc + 1);
    attn_finalize_kernel<<<1, 1, 0, stream>>>(sacc, attn);
    const long q4 = (long)NNODES * CDIM / 4;
    combine_kernel<<<(int)((q4 + 255) / 256), 256, 0, stream>>>(O0, O1, attn, OutBuf);
}

extern "C" void kernel_launch(void* const* d_in, const int* in_sizes, int n_in,
                              void* d_out, int out_size, void* d_ws, size_t ws_size,
                              hipStream_t stream) {
    const float* x          = (const float*)d_in[0];
    const int*   ei_spatial = (const int*)d_in[1];
    const int*   ei_similar = (const int*)d_in[2];
    const float* p1_proj_w  = (const float*)d_in[3];
    const float* p1_proj_b  = (const float*)d_in[4];
    const float* p1_att_src = (const float*)d_in[5];
    const float* p1_att_dst = (const float*)d_in[6];
    const float* p1_q       = (const float*)d_in[7];
    const float* p1_kw      = (const float*)d_in[8];
    const float* p1_kb      = (const float*)d_in[9];
    const float* p2_proj_w  = (const float*)d_in[10];
    const float* p2_proj_b  = (const float*)d_in[11];
    const float* p2_att_src = (const float*)d_in[12];
    const float* p2_att_dst = (const float*)d_in[13];
    const float* p2_q       = (const float*)d_in[14];
    const float* p2_kw      = (const float*)d_in[15];
    const float* p2_kb      = (const float*)d_in[16];
    const float* lin_w      = (const float*)d_in[17];
    const float* lin_b      = (const float*)d_in[18];

    float* ws = (float*)d_ws;
    const size_t nc = (size_t)NNODES * CDIM;
    const size_t nh2 = (size_t)NNODES * HHEADS;

    float* A    = ws;
    float* B    = A + nc;
    float* Cb   = B + nc;
    float* asrc = Cb + nc;               // 2*N*H
    float* adst = asrc + 2 * nh2;        // 2*N*H
    float* sacc = adst + 2 * nh2;        // 2
    float* attn = sacc + 2;              // 2
    int* rowptr0 = (int*)(attn + 2);
    int* rowptr1 = rowptr0 + (NNODES + 1);
    int* csr0    = rowptr1 + (NNODES + 1);
    int* csr1    = csr0 + EEDGES;
    int* scratch = csr1 + EEDGES;        // deg/cursor, NNODES ints

    // ---- build CSR for both edge types (structure reused across layers) ----
    const int g_e = (EEDGES + 255) / 256;
    const int* eis[2] = {ei_spatial, ei_similar};
    int* rps[2] = {rowptr0, rowptr1};
    int* csrs[2] = {csr0, csr1};
    for (int i = 0; i < 2; ++i) {
        const int* src = eis[i];
        const int* dst = eis[i] + EEDGES;
        hipMemsetAsync(scratch, 0, NNODES * sizeof(int), stream);
        hist_kernel<<<g_e, 256, 0, stream>>>(dst, scratch);
        scan_kernel<<<1, 1024, 0, stream>>>(scratch, rps[i]);
        hipMemcpyAsync(scratch, rps[i], NNODES * sizeof(int),
                       hipMemcpyDeviceToDevice, stream);
        fill_kernel<<<g_e, 256, 0, stream>>>(src, dst, scratch, csrs[i]);
    }

    // Layer 1: h1 -> A ; per-type outs -> B, Cb ; combined -> A
    run_layer(x, FIN, p1_proj_w, p1_proj_b, p1_att_src, p1_att_dst,
              p1_q, p1_kw, p1_kb, rowptr0, csr0, rowptr1, csr1,
              A, B, Cb, A, asrc, adst, sacc, attn, stream);

    // Layer 2: X = A ; h2 -> B ; per-type outs -> Cb, A ; combined -> B
    run_layer(A, CDIM, p2_proj_w, p2_proj_b, p2_att_src, p2_att_dst,
              p2_q, p2_kw, p2_kb, rowptr0, csr0, rowptr1, csr1,
              B, Cb, A, B, asrc, adst, sacc, attn, stream);

    // Final classifier
    const int gfin = (NNODES * FOUT + 255) / 256;
    final_linear_kernel<<<gfin, 256, 0, stream>>>(B, lin_w, lin_b, (float*)d_out);
}

// Round 5
// 1400.021 us; speedup vs baseline: 2.1601x; 1.2548x over previous
//
#include <hip/hip_runtime.h>

#define NNODES 100000
#define EEDGES 600000
#define CDIM 128
#define HHEADS 2
#define DDIM 64
#define FIN 64
#define FOUT 8
#define NEG 0.2f

typedef short bf16x8 __attribute__((ext_vector_type(8)));
typedef unsigned short ushort8 __attribute__((ext_vector_type(8)));
typedef float f32x4 __attribute__((ext_vector_type(4)));

__device__ __forceinline__ float tanh_fast(float x) {
    float e = __expf(2.f * x);
    return 1.f - 2.f / (e + 1.f);  // stable: x->+inf => 1, x->-inf => -1
}

__device__ __forceinline__ unsigned short f2bf(float x) {
    unsigned int u = __float_as_uint(x);
    unsigned int r = (u + 0x7FFFu + ((u >> 16) & 1u)) >> 16;  // RNE
    return (unsigned short)r;
}

// ============ register-tiled GEMM core v3 (f32): for projection ============
template<int K, bool RELU_IN>
__device__ __forceinline__ void gemm_tile3(const float* __restrict__ X,
                                           const float* __restrict__ W,
                                           const float* __restrict__ bias,
                                           int row0, float acc[4][4], float* wch) {
    int tid = threadIdx.x;
    int rb = tid >> 5, cb = tid & 31;
    int c0 = cb * 4;
#pragma unroll
    for (int j = 0; j < 4; ++j) {
        float b = bias[c0 + j];
#pragma unroll
        for (int r = 0; r < 4; ++r) acc[r][j] = b;
    }
    const float* xbase = X + (long)(row0 + rb * 4) * K;

    for (int kc = 0; kc < K; kc += 32) {
        __syncthreads();
#pragma unroll
        for (int i = 0; i < 4; ++i) {
            int idx = tid + i * 256;
            ((float4*)wch)[idx] = ((const float4*)(W + kc * CDIM))[idx];
        }
        __syncthreads();
#pragma unroll
        for (int k0 = 0; k0 < 32; k0 += 4) {
            float4 xr[4];
#pragma unroll
            for (int r = 0; r < 4; ++r) {
                xr[r] = *(const float4*)(xbase + r * K + kc + k0);
                if (RELU_IN) {
                    xr[r].x = fmaxf(xr[r].x, 0.f);
                    xr[r].y = fmaxf(xr[r].y, 0.f);
                    xr[r].z = fmaxf(xr[r].z, 0.f);
                    xr[r].w = fmaxf(xr[r].w, 0.f);
                }
            }
            float4 wv[4];
#pragma unroll
            for (int kk = 0; kk < 4; ++kk)
                wv[kk] = *(const float4*)(wch + (k0 + kk) * CDIM + c0);
#pragma unroll
            for (int r = 0; r < 4; ++r) {
                const float* xf = (const float*)&xr[r];
#pragma unroll
                for (int kk = 0; kk < 4; ++kk) {
                    const float* wf = (const float*)&wv[kk];
#pragma unroll
                    for (int j = 0; j < 4; ++j)
                        acc[r][j] = fmaf(xf[kk], wf[j], acc[r][j]);
                }
            }
        }
    }
}

// ---- projection: H = X@W + b, fused per-edge-type per-head attention dots ----
template<int K>
__global__ __launch_bounds__(256, 4)
void proj_kernel3(const float* __restrict__ X, const float* __restrict__ W,
                  const float* __restrict__ bias,
                  const float* __restrict__ att_src, const float* __restrict__ att_dst,
                  float* __restrict__ Hout,
                  float* __restrict__ a_src, float* __restrict__ a_dst) {
    __shared__ float wch[32 * CDIM];
    float acc[4][4];
    int row0 = blockIdx.x * 32;
    gemm_tile3<K, false>(X, W, bias, row0, acc, wch);
    int tid = threadIdx.x, rb = tid >> 5, cb = tid & 31;
    int c0 = cb * 4;
#pragma unroll
    for (int r = 0; r < 4; ++r) {
        int row = row0 + rb * 4 + r;
        float4 o = make_float4(acc[r][0], acc[r][1], acc[r][2], acc[r][3]);
        *(float4*)(Hout + (long)row * CDIM + c0) = o;
    }
#pragma unroll
    for (int i = 0; i < 2; ++i) {
        float as4[4], ad4[4];
#pragma unroll
        for (int j = 0; j < 4; ++j) {
            as4[j] = att_src[i * CDIM + c0 + j];
            ad4[j] = att_dst[i * CDIM + c0 + j];
        }
#pragma unroll
        for (int r = 0; r < 4; ++r) {
            float s = acc[r][0] * as4[0] + acc[r][1] * as4[1]
                    + acc[r][2] * as4[2] + acc[r][3] * as4[3];
            float d = acc[r][0] * ad4[0] + acc[r][1] * ad4[1]
                    + acc[r][2] * ad4[2] + acc[r][3] * ad4[3];
#pragma unroll
            for (int m = 8; m >= 1; m >>= 1) {
                s += __shfl_xor(s, m, 64);
                d += __shfl_xor(d, m, 64);
            }
            if ((cb & 15) == 0) {
                int hh = cb >> 4;
                int row = row0 + rb * 4 + r;
                long base = (long)i * NNODES * HHEADS + (long)row * HHEADS + hh;
                a_src[base] = s;
                a_dst[base] = d;
            }
        }
    }
}

// ---- kw -> transposed bf16 (once per layer): kwT_b[c][k] = bf16(kw[k][c]) ----
__global__ __launch_bounds__(256)
void cvt_kwT_kernel(const float* __restrict__ kw, unsigned short* __restrict__ kwT_b) {
    int idx = blockIdx.x * 256 + threadIdx.x;  // 64 blocks x 256 = 16384
    int c = idx >> 7, k = idx & 127;
    kwT_b[idx] = f2bf(kw[k * CDIM + c]);
}

// ---- semantic score via MFMA: sacc += sum_n q . tanh(relu(Om[n]) @ kw + kb) ----
// 64 rows/block, 4 waves; wave w: rows w*16..+15, all 128 cols (8 16x16 tiles).
// A = relu(Om) bf16, B = kwT_b; both LDS-staged with XOR swizzle on 16B units.
__global__ __launch_bounds__(256, 3)
void score_mfma(const float* __restrict__ Om, const unsigned short* __restrict__ kwT_b,
                const float* __restrict__ kb, const float* __restrict__ q,
                float* __restrict__ sacc) {
    __shared__ ushort8 As8[64 * 16];    // 16 KB: [row][u] swizzled
    __shared__ ushort8 Bs8[128 * 16];   // 32 KB: [c][u] swizzled
    int tid = threadIdx.x;
    int row0 = blockIdx.x * 64;

    // stage A: 1024 units (row, u), u = k/8; relu + f32->bf16
#pragma unroll
    for (int i = 0; i < 4; ++i) {
        int idx = tid + i * 256;
        int row = idx >> 4, u = idx & 15;
        int grow = row0 + row;
        ushort8 v;
        if (grow < NNODES) {
            const float* p = Om + (long)grow * CDIM + u * 8;
            float4 a = *(const float4*)p;
            float4 b = *(const float4*)(p + 4);
            v[0] = f2bf(fmaxf(a.x, 0.f)); v[1] = f2bf(fmaxf(a.y, 0.f));
            v[2] = f2bf(fmaxf(a.z, 0.f)); v[3] = f2bf(fmaxf(a.w, 0.f));
            v[4] = f2bf(fmaxf(b.x, 0.f)); v[5] = f2bf(fmaxf(b.y, 0.f));
            v[6] = f2bf(fmaxf(b.z, 0.f)); v[7] = f2bf(fmaxf(b.w, 0.f));
        } else {
            v = (ushort8)0;
        }
        As8[row * 16 + (u ^ (row & 7))] = v;
    }
    // stage B: 2048 units (c, u)
#pragma unroll
    for (int i = 0; i < 8; ++i) {
        int idx = tid + i * 256;
        int c = idx >> 4, u = idx & 15;
        Bs8[c * 16 + (u ^ (c & 7))] = ((const ushort8*)kwT_b)[idx];
    }
    __syncthreads();

    int l = tid & 63, w = tid >> 6;
    int lrow = w * 16 + (l & 15);       // A row within block (for this lane)
    int ug = l >> 4;                    // k-subgroup 0..3
    f32x4 acc[8];
#pragma unroll
    for (int ct = 0; ct < 8; ++ct) acc[ct] = (f32x4)0.f;

#pragma unroll
    for (int kc = 0; kc < 4; ++kc) {    // K chunks of 32
        int u = kc * 4 + ug;
        bf16x8 af = *(const bf16x8*)&As8[lrow * 16 + (u ^ (lrow & 7))];
#pragma unroll
        for (int ct = 0; ct < 8; ++ct) {
            int c = ct * 16 + (l & 15);
            bf16x8 bf = *(const bf16x8*)&Bs8[c * 16 + (u ^ (c & 7))];
            acc[ct] = __builtin_amdgcn_mfma_f32_16x16x32_bf16(af, bf, acc[ct], 0, 0, 0);
        }
    }

    // epilogue: C/D layout col = l&15, row = (l>>4)*4 + reg
    float s = 0.f;
#pragma unroll
    for (int ct = 0; ct < 8; ++ct) {
        int c = ct * 16 + (l & 15);
        float qc = q[c], kbc = kb[c];
#pragma unroll
        for (int v = 0; v < 4; ++v) {
            int grow = row0 + w * 16 + (l >> 4) * 4 + v;
            if (grow < NNODES) s += qc * tanh_fast(acc[ct][v] + kbc);
        }
    }
#pragma unroll
    for (int m = 32; m >= 1; m >>= 1) s += __shfl_xor(s, m, 64);
    if (l == 0) atomicAdd(sacc, s);
}

// ============ CSR build (per edge type, structure shared by both layers) ============
__global__ void hist_kernel(const int* __restrict__ dst, int* __restrict__ deg) {
    int e = blockIdx.x * blockDim.x + threadIdx.x;
    if (e < EEDGES) atomicAdd(&deg[dst[e]], 1);
}

__global__ __launch_bounds__(1024)
void scan_kernel(const int* __restrict__ deg, int* __restrict__ rowptr) {
    __shared__ int tot[1024];
    const int CH = (NNODES + 1023) / 1024;  // 98
    int t = threadIdx.x;
    int beg = t * CH;
    int end = beg + CH < NNODES ? beg + CH : NNODES;
    int s = 0;
    for (int i = beg; i < end; ++i) s += deg[i];
    tot[t] = s;
    __syncthreads();
    if (t == 0) {
        int run = 0;
        for (int i = 0; i < 1024; ++i) { int v = tot[i]; tot[i] = run; run += v; }
    }
    __syncthreads();
    int run = tot[t];
    for (int i = beg; i < end; ++i) { rowptr[i] = run; run += deg[i]; }
    if (beg <= NNODES && end == NNODES) rowptr[NNODES] = run;
}

__global__ void fill_kernel(const int* __restrict__ src, const int* __restrict__ dst,
                            int* __restrict__ cursor, int* __restrict__ csr_src) {
    int e = blockIdx.x * blockDim.x + threadIdx.x;
    if (e < EEDGES) {
        int pos = atomicAdd(&cursor[dst[e]], 1);
        csr_src[pos] = src[e];
    }
}

// ============ fused edge softmax + aggregation: one wave per destination node ============
__global__ __launch_bounds__(256)
void seg_aggregate_kernel(const int* __restrict__ rowptr, const int* __restrict__ csr_src,
                          const float* __restrict__ asv, const float* __restrict__ adv,
                          const float* __restrict__ Hfeat, float* __restrict__ Out) {
    int node = blockIdx.x * 4 + (threadIdx.x >> 6);
    if (node >= NNODES) return;
    int lane = threadIdx.x & 63;
    int start = rowptr[node], end = rowptr[node + 1];
    int deg = end - start;
    float ad0 = adv[node * 2 + 0], ad1 = adv[node * 2 + 1];

    float m0 = -1e30f, m1 = -1e30f;
    for (int i = lane; i < deg; i += 64) {
        int s = csr_src[start + i];
        float r0 = asv[s * 2 + 0] + ad0; r0 = r0 >= 0.f ? r0 : NEG * r0;
        float r1 = asv[s * 2 + 1] + ad1; r1 = r1 >= 0.f ? r1 : NEG * r1;
        m0 = fmaxf(m0, r0); m1 = fmaxf(m1, r1);
    }
#pragma unroll
    for (int t = 32; t >= 1; t >>= 1) {
        m0 = fmaxf(m0, __shfl_xor(m0, t, 64));
        m1 = fmaxf(m1, __shfl_xor(m1, t, 64));
    }
    float s0 = 0.f, s1 = 0.f;
    for (int i = lane; i < deg; i += 64) {
        int s = csr_src[start + i];
        float r0 = asv[s * 2 + 0] + ad0; r0 = r0 >= 0.f ? r0 : NEG * r0;
        float r1 = asv[s * 2 + 1] + ad1; r1 = r1 >= 0.f ? r1 : NEG * r1;
        s0 += __expf(r0 - m0); s1 += __expf(r1 - m1);
    }
#pragma unroll
    for (int t = 32; t >= 1; t >>= 1) {
        s0 += __shfl_xor(s0, t, 64);
        s1 += __shfl_xor(s1, t, 64);
    }
    float inv0 = 1.f / (s0 + 1e-16f);
    float inv1 = 1.f / (s1 + 1e-16f);

    float acc0 = 0.f, acc1 = 0.f;
    for (int i = 0; i < deg; ++i) {
        int s = csr_src[start + i];
        float r0 = asv[s * 2 + 0] + ad0; r0 = r0 >= 0.f ? r0 : NEG * r0;
        float r1 = asv[s * 2 + 1] + ad1; r1 = r1 >= 0.f ? r1 : NEG * r1;
        float a0 = __expf(r0 - m0) * inv0;
        float a1 = __expf(r1 - m1) * inv1;
        const float* hrow = Hfeat + (long)s * CDIM;
        acc0 = fmaf(hrow[lane], a0, acc0);
        acc1 = fmaf(hrow[64 + lane], a1, acc1);
    }
    Out[(long)node * CDIM + lane] = acc0;
    Out[(long)node * CDIM + 64 + lane] = acc1;
}

__global__ void attn_finalize_kernel(const float* __restrict__ sacc, float* __restrict__ attn) {
    float s0 = sacc[0] / (float)NNODES;
    float s1 = sacc[1] / (float)NNODES;
    float m = fmaxf(s0, s1);
    float e0 = expf(s0 - m), e1 = expf(s1 - m);
    float inv = 1.f / (e0 + e1);
    attn[0] = e0 * inv;
    attn[1] = e1 * inv;
}

__global__ __launch_bounds__(256)
void combine_kernel(const float* __restrict__ O0, const float* __restrict__ O1,
                    const float* __restrict__ attn, float* __restrict__ Hn) {
    long i = (long)blockIdx.x * blockDim.x + threadIdx.x;
    long total = (long)NNODES * CDIM / 4;
    if (i >= total) return;
    float a0 = attn[0], a1 = attn[1];
    float4 v0 = ((const float4*)O0)[i];
    float4 v1 = ((const float4*)O1)[i];
    float4 o;
    o.x = a0 * fmaxf(v0.x, 0.f) + a1 * fmaxf(v1.x, 0.f);
    o.y = a0 * fmaxf(v0.y, 0.f) + a1 * fmaxf(v1.y, 0.f);
    o.z = a0 * fmaxf(v0.z, 0.f) + a1 * fmaxf(v1.z, 0.f);
    o.w = a0 * fmaxf(v0.w, 0.f) + a1 * fmaxf(v1.w, 0.f);
    ((float4*)Hn)[i] = o;
}

__global__ __launch_bounds__(256)
void final_linear_kernel(const float* __restrict__ Hn, const float* __restrict__ lw,
                         const float* __restrict__ lb, float* __restrict__ out) {
    __shared__ float lws[CDIM * FOUT];
    int tid = threadIdx.x;
    for (int i = tid; i < CDIM * FOUT; i += 256) lws[i] = lw[i];
    __syncthreads();
    int idx = blockIdx.x * 256 + tid;
    if (idx >= NNODES * FOUT) return;
    int n = idx >> 3, o = idx & 7;
    const float4* row = (const float4*)(Hn + (long)n * CDIM);
    float acc = lb[o];
#pragma unroll
    for (int k4 = 0; k4 < 32; ++k4) {
        float4 v = row[k4];
        acc = fmaf(v.x, lws[(k4 * 4 + 0) * FOUT + o], acc);
        acc = fmaf(v.y, lws[(k4 * 4 + 1) * FOUT + o], acc);
        acc = fmaf(v.z, lws[(k4 * 4 + 2) * FOUT + o], acc);
        acc = fmaf(v.w, lws[(k4 * 4 + 3) * FOUT + o], acc);
    }
    out[idx] = acc;
}

static void run_layer(const float* X, int K,
                      const float* pw, const float* pb,
                      const float* ats, const float* atd,
                      const float* q, const float* kw, const float* kb,
                      const int* rowptr0, const int* csr0,
                      const int* rowptr1, const int* csr1,
                      float* Hbuf, float* O0, float* O1, float* OutBuf,
                      float* asrc, float* adst,
                      float* sacc, float* attn, unsigned short* kwT_b,
                      hipStream_t stream) {
    const int gtile = NNODES / 32;  // 3125 exactly
    if (K == 64)
        proj_kernel3<64><<<gtile, 256, 0, stream>>>(X, pw, pb, ats, atd, Hbuf, asrc, adst);
    else
        proj_kernel3<128><<<gtile, 256, 0, stream>>>(X, pw, pb, ats, atd, Hbuf, asrc, adst);

    cvt_kwT_kernel<<<64, 256, 0, stream>>>(kw, kwT_b);

    const int nh = NNODES * HHEADS;
    const int gseg = (NNODES + 3) / 4;
    seg_aggregate_kernel<<<gseg, 256, 0, stream>>>(rowptr0, csr0, asrc, adst, Hbuf, O0);
    seg_aggregate_kernel<<<gseg, 256, 0, stream>>>(rowptr1, csr1, asrc + nh, adst + nh, Hbuf, O1);

    hipMemsetAsync(sacc, 0, 2 * sizeof(float), stream);
    const int gsc = (NNODES + 63) / 64;  // 1563
    score_mfma<<<gsc, 256, 0, stream>>>(O0, kwT_b, kb, q, sacc + 0);
    score_mfma<<<gsc, 256, 0, stream>>>(O1, kwT_b, kb, q, sacc + 1);
    attn_finalize_kernel<<<1, 1, 0, stream>>>(sacc, attn);
    const long q4 = (long)NNODES * CDIM / 4;
    combine_kernel<<<(int)((q4 + 255) / 256), 256, 0, stream>>>(O0, O1, attn, OutBuf);
}

extern "C" void kernel_launch(void* const* d_in, const int* in_sizes, int n_in,
                              void* d_out, int out_size, void* d_ws, size_t ws_size,
                              hipStream_t stream) {
    const float* x          = (const float*)d_in[0];
    const int*   ei_spatial = (const int*)d_in[1];
    const int*   ei_similar = (const int*)d_in[2];
    const float* p1_proj_w  = (const float*)d_in[3];
    const float* p1_proj_b  = (const float*)d_in[4];
    const float* p1_att_src = (const float*)d_in[5];
    const float* p1_att_dst = (const float*)d_in[6];
    const float* p1_q       = (const float*)d_in[7];
    const float* p1_kw      = (const float*)d_in[8];
    const float* p1_kb      = (const float*)d_in[9];
    const float* p2_proj_w  = (const float*)d_in[10];
    const float* p2_proj_b  = (const float*)d_in[11];
    const float* p2_att_src = (const float*)d_in[12];
    const float* p2_att_dst = (const float*)d_in[13];
    const float* p2_q       = (const float*)d_in[14];
    const float* p2_kw      = (const float*)d_in[15];
    const float* p2_kb      = (const float*)d_in[16];
    const float* lin_w      = (const float*)d_in[17];
    const float* lin_b      = (const float*)d_in[18];

    float* ws = (float*)d_ws;
    const size_t nc = (size_t)NNODES * CDIM;
    const size_t nh2 = (size_t)NNODES * HHEADS;

    float* A    = ws;
    float* B    = A + nc;
    float* Cb   = B + nc;
    float* asrc = Cb + nc;               // 2*N*H
    float* adst = asrc + 2 * nh2;        // 2*N*H
    float* sacc = adst + 2 * nh2;        // 2
    float* attn = sacc + 2;              // 2
    int* rowptr0 = (int*)(attn + 2);
    int* rowptr1 = rowptr0 + (NNODES + 1);
    int* csr0    = rowptr1 + (NNODES + 1);
    int* csr1    = csr0 + EEDGES;
    int* scratch = csr1 + EEDGES;        // deg/cursor, NNODES ints
    uintptr_t kp = (uintptr_t)(scratch + NNODES);
    kp = (kp + 15) & ~(uintptr_t)15;
    unsigned short* kwT_b = (unsigned short*)kp;  // 128*128 bf16

    // ---- build CSR for both edge types (structure reused across layers) ----
    const int g_e = (EEDGES + 255) / 256;
    const int* eis[2] = {ei_spatial, ei_similar};
    int* rps[2] = {rowptr0, rowptr1};
    int* csrs[2] = {csr0, csr1};
    for (int i = 0; i < 2; ++i) {
        const int* src = eis[i];
        const int* dst = eis[i] + EEDGES;
        hipMemsetAsync(scratch, 0, NNODES * sizeof(int), stream);
        hist_kernel<<<g_e, 256, 0, stream>>>(dst, scratch);
        scan_kernel<<<1, 1024, 0, stream>>>(scratch, rps[i]);
        hipMemcpyAsync(scratch, rps[i], NNODES * sizeof(int),
                       hipMemcpyDeviceToDevice, stream);
        fill_kernel<<<g_e, 256, 0, stream>>>(src, dst, scratch, csrs[i]);
    }

    // Layer 1: h1 -> A ; per-type outs -> B, Cb ; combined -> A
    run_layer(x, FIN, p1_proj_w, p1_proj_b, p1_att_src, p1_att_dst,
              p1_q, p1_kw, p1_kb, rowptr0, csr0, rowptr1, csr1,
              A, B, Cb, A, asrc, adst, sacc, attn, kwT_b, stream);

    // Layer 2: X = A ; h2 -> B ; per-type outs -> Cb, A ; combined -> B
    run_layer(A, CDIM, p2_proj_w, p2_proj_b, p2_att_src, p2_att_dst,
              p2_q, p2_kw, p2_kb, rowptr0, csr0, rowptr1, csr1,
              B, Cb, A, B, asrc, adst, sacc, attn, kwT_b, stream);

    // Final classifier
    const int gfin = (NNODES * FOUT + 255) / 256;
    final_linear_kernel<<<gfin, 256, 0, stream>>>(B, lin_w, lin_b, (float*)d_out);
}

// Round 6
// 1070.243 us; speedup vs baseline: 2.8257x; 1.3081x over previous
//
#include <hip/hip_runtime.h>

#define NNODES 100000
#define EEDGES 600000
#define CDIM 128
#define HHEADS 2
#define DDIM 64
#define FIN 64
#define FOUT 8
#define NEG 0.2f

#define SB 200    // scan blocks
#define SCH 500   // nodes per scan block (200*500 = 100000 exactly)

typedef short bf16x8 __attribute__((ext_vector_type(8)));
typedef unsigned short ushort8 __attribute__((ext_vector_type(8)));
typedef float f32x4 __attribute__((ext_vector_type(4)));

__device__ __forceinline__ float tanh_fast(float x) {
    float e = __expf(2.f * x);
    return 1.f - 2.f / (e + 1.f);  // stable: x->+inf => 1, x->-inf => -1
}

__device__ __forceinline__ unsigned short f2bf(float x) {
    unsigned int u = __float_as_uint(x);
    unsigned int r = (u + 0x7FFFu + ((u >> 16) & 1u)) >> 16;  // RNE
    return (unsigned short)r;
}

// ============ register-tiled GEMM core v3 (f32): for projection ============
template<int K, bool RELU_IN>
__device__ __forceinline__ void gemm_tile3(const float* __restrict__ X,
                                           const float* __restrict__ W,
                                           const float* __restrict__ bias,
                                           int row0, float acc[4][4], float* wch) {
    int tid = threadIdx.x;
    int rb = tid >> 5, cb = tid & 31;
    int c0 = cb * 4;
#pragma unroll
    for (int j = 0; j < 4; ++j) {
        float b = bias[c0 + j];
#pragma unroll
        for (int r = 0; r < 4; ++r) acc[r][j] = b;
    }
    const float* xbase = X + (long)(row0 + rb * 4) * K;

    for (int kc = 0; kc < K; kc += 32) {
        __syncthreads();
#pragma unroll
        for (int i = 0; i < 4; ++i) {
            int idx = tid + i * 256;
            ((float4*)wch)[idx] = ((const float4*)(W + kc * CDIM))[idx];
        }
        __syncthreads();
#pragma unroll
        for (int k0 = 0; k0 < 32; k0 += 4) {
            float4 xr[4];
#pragma unroll
            for (int r = 0; r < 4; ++r) {
                xr[r] = *(const float4*)(xbase + r * K + kc + k0);
                if (RELU_IN) {
                    xr[r].x = fmaxf(xr[r].x, 0.f);
                    xr[r].y = fmaxf(xr[r].y, 0.f);
                    xr[r].z = fmaxf(xr[r].z, 0.f);
                    xr[r].w = fmaxf(xr[r].w, 0.f);
                }
            }
            float4 wv[4];
#pragma unroll
            for (int kk = 0; kk < 4; ++kk)
                wv[kk] = *(const float4*)(wch + (k0 + kk) * CDIM + c0);
#pragma unroll
            for (int r = 0; r < 4; ++r) {
                const float* xf = (const float*)&xr[r];
#pragma unroll
                for (int kk = 0; kk < 4; ++kk) {
                    const float* wf = (const float*)&wv[kk];
#pragma unroll
                    for (int j = 0; j < 4; ++j)
                        acc[r][j] = fmaf(xf[kk], wf[j], acc[r][j]);
                }
            }
        }
    }
}

// ---- projection: H = X@W + b, fused per-edge-type per-head attention dots ----
template<int K>
__global__ __launch_bounds__(256, 4)
void proj_kernel3(const float* __restrict__ X, const float* __restrict__ W,
                  const float* __restrict__ bias,
                  const float* __restrict__ att_src, const float* __restrict__ att_dst,
                  float* __restrict__ Hout,
                  float* __restrict__ a_src, float* __restrict__ a_dst) {
    __shared__ float wch[32 * CDIM];
    float acc[4][4];
    int row0 = blockIdx.x * 32;
    gemm_tile3<K, false>(X, W, bias, row0, acc, wch);
    int tid = threadIdx.x, rb = tid >> 5, cb = tid & 31;
    int c0 = cb * 4;
#pragma unroll
    for (int r = 0; r < 4; ++r) {
        int row = row0 + rb * 4 + r;
        float4 o = make_float4(acc[r][0], acc[r][1], acc[r][2], acc[r][3]);
        *(float4*)(Hout + (long)row * CDIM + c0) = o;
    }
#pragma unroll
    for (int i = 0; i < 2; ++i) {
        float as4[4], ad4[4];
#pragma unroll
        for (int j = 0; j < 4; ++j) {
            as4[j] = att_src[i * CDIM + c0 + j];
            ad4[j] = att_dst[i * CDIM + c0 + j];
        }
#pragma unroll
        for (int r = 0; r < 4; ++r) {
            float s = acc[r][0] * as4[0] + acc[r][1] * as4[1]
                    + acc[r][2] * as4[2] + acc[r][3] * as4[3];
            float d = acc[r][0] * ad4[0] + acc[r][1] * ad4[1]
                    + acc[r][2] * ad4[2] + acc[r][3] * ad4[3];
#pragma unroll
            for (int m = 8; m >= 1; m >>= 1) {
                s += __shfl_xor(s, m, 64);
                d += __shfl_xor(d, m, 64);
            }
            if ((cb & 15) == 0) {
                int hh = cb >> 4;
                int row = row0 + rb * 4 + r;
                long base = (long)i * NNODES * HHEADS + (long)row * HHEADS + hh;
                a_src[base] = s;
                a_dst[base] = d;
            }
        }
    }
}

// ---- kw -> transposed bf16 (once per layer): kwT_b[c][k] = bf16(kw[k][c]) ----
__global__ __launch_bounds__(256)
void cvt_kwT_kernel(const float* __restrict__ kw, unsigned short* __restrict__ kwT_b) {
    int idx = blockIdx.x * 256 + threadIdx.x;  // 64 blocks x 256 = 16384
    int c = idx >> 7, k = idx & 127;
    kwT_b[idx] = f2bf(kw[k * CDIM + c]);
}

// ---- semantic score via MFMA ----
__global__ __launch_bounds__(256, 3)
void score_mfma(const float* __restrict__ Om, const unsigned short* __restrict__ kwT_b,
                const float* __restrict__ kb, const float* __restrict__ q,
                float* __restrict__ sacc) {
    __shared__ ushort8 As8[64 * 16];    // 16 KB: [row][u] swizzled
    __shared__ ushort8 Bs8[128 * 16];   // 32 KB: [c][u] swizzled
    int tid = threadIdx.x;
    int row0 = blockIdx.x * 64;

#pragma unroll
    for (int i = 0; i < 4; ++i) {
        int idx = tid + i * 256;
        int row = idx >> 4, u = idx & 15;
        int grow = row0 + row;
        ushort8 v;
        if (grow < NNODES) {
            const float* p = Om + (long)grow * CDIM + u * 8;
            float4 a = *(const float4*)p;
            float4 b = *(const float4*)(p + 4);
            v[0] = f2bf(fmaxf(a.x, 0.f)); v[1] = f2bf(fmaxf(a.y, 0.f));
            v[2] = f2bf(fmaxf(a.z, 0.f)); v[3] = f2bf(fmaxf(a.w, 0.f));
            v[4] = f2bf(fmaxf(b.x, 0.f)); v[5] = f2bf(fmaxf(b.y, 0.f));
            v[6] = f2bf(fmaxf(b.z, 0.f)); v[7] = f2bf(fmaxf(b.w, 0.f));
        } else {
            v = (ushort8)0;
        }
        As8[row * 16 + (u ^ (row & 7))] = v;
    }
#pragma unroll
    for (int i = 0; i < 8; ++i) {
        int idx = tid + i * 256;
        int c = idx >> 4, u = idx & 15;
        Bs8[c * 16 + (u ^ (c & 7))] = ((const ushort8*)kwT_b)[idx];
    }
    __syncthreads();

    int l = tid & 63, w = tid >> 6;
    int lrow = w * 16 + (l & 15);
    int ug = l >> 4;
    f32x4 acc[8];
#pragma unroll
    for (int ct = 0; ct < 8; ++ct) acc[ct] = (f32x4)0.f;

#pragma unroll
    for (int kc = 0; kc < 4; ++kc) {
        int u = kc * 4 + ug;
        bf16x8 af = *(const bf16x8*)&As8[lrow * 16 + (u ^ (lrow & 7))];
#pragma unroll
        for (int ct = 0; ct < 8; ++ct) {
            int c = ct * 16 + (l & 15);
            bf16x8 bf = *(const bf16x8*)&Bs8[c * 16 + (u ^ (c & 7))];
            acc[ct] = __builtin_amdgcn_mfma_f32_16x16x32_bf16(af, bf, acc[ct], 0, 0, 0);
        }
    }

    float s = 0.f;
#pragma unroll
    for (int ct = 0; ct < 8; ++ct) {
        int c = ct * 16 + (l & 15);
        float qc = q[c], kbc = kb[c];
#pragma unroll
        for (int v = 0; v < 4; ++v) {
            int grow = row0 + w * 16 + (l >> 4) * 4 + v;
            if (grow < NNODES) s += qc * tanh_fast(acc[ct][v] + kbc);
        }
    }
#pragma unroll
    for (int m = 32; m >= 1; m >>= 1) s += __shfl_xor(s, m, 64);
    if (l == 0) atomicAdd(sacc, s);
}

// ============ CSR build ============
__global__ void hist_kernel(const int* __restrict__ dst, int* __restrict__ deg) {
    int e = blockIdx.x * blockDim.x + threadIdx.x;
    if (e < EEDGES) atomicAdd(&deg[dst[e]], 1);
}

// 3-phase decoupled scan over deg[NNODES] -> exclusive rowptr
__global__ __launch_bounds__(256)
void scan_partial(const int* __restrict__ deg, int* __restrict__ bsum) {
    __shared__ int red[256];
    int b = blockIdx.x, t = threadIdx.x;
    int s = 0;
    if (t < 250) {
        int base = b * SCH + t * 2;
        s = deg[base] + deg[base + 1];
    }
    red[t] = s;
    __syncthreads();
#pragma unroll
    for (int off = 128; off >= 1; off >>= 1) {
        if (t < off) red[t] += red[t + off];
        __syncthreads();
    }
    if (t == 0) bsum[b] = red[0];
}

__global__ void scan_bsum(int* __restrict__ bsum) {
    if (threadIdx.x == 0) {
        int run = 0;
        for (int i = 0; i < SB; ++i) { int v = bsum[i]; bsum[i] = run; run += v; }
    }
}

__global__ __launch_bounds__(256)
void scan_final(const int* __restrict__ deg, const int* __restrict__ bsum,
                int* __restrict__ rowptr) {
    __shared__ int ts[256];
    int b = blockIdx.x, t = threadIdx.x;
    int d0 = 0, d1 = 0;
    int base = b * SCH + t * 2;
    if (t < 250) { d0 = deg[base]; d1 = deg[base + 1]; }
    ts[t] = d0 + d1;
    __syncthreads();
    // Hillis-Steele inclusive scan over 256 thread sums
#pragma unroll
    for (int off = 1; off < 256; off <<= 1) {
        int v = (t >= off) ? ts[t - off] : 0;
        __syncthreads();
        ts[t] += v;
        __syncthreads();
    }
    if (t < 250) {
        int excl = bsum[b] + (t > 0 ? ts[t - 1] : 0);
        rowptr[base] = excl;
        rowptr[base + 1] = excl + d0;
    }
    if (b == 0 && t == 0) rowptr[NNODES] = EEDGES;  // total degree is E by construction
}

__global__ void fill_kernel(const int* __restrict__ src, const int* __restrict__ dst,
                            int* __restrict__ cursor, int* __restrict__ csr_src) {
    int e = blockIdx.x * blockDim.x + threadIdx.x;
    if (e < EEDGES) {
        int pos = atomicAdd(&cursor[dst[e]], 1);
        csr_src[pos] = src[e];
    }
}

// ============ fused edge softmax + aggregation, BOTH edge types in one launch ======
// blocks [0, gseg) -> type 0, [gseg, 2*gseg) -> type 1; one wave per dest node.
__global__ __launch_bounds__(256)
void seg_aggregate_dual(const int* __restrict__ rowptr0, const int* __restrict__ csr0,
                        const float* __restrict__ as0, const float* __restrict__ ad0,
                        float* __restrict__ O0,
                        const int* __restrict__ rowptr1, const int* __restrict__ csr1,
                        const float* __restrict__ as1, const float* __restrict__ ad1,
                        float* __restrict__ O1,
                        const float* __restrict__ Hfeat, int gseg) {
    int bid = blockIdx.x;
    int type = bid >= gseg;
    const int* rowptr = type ? rowptr1 : rowptr0;
    const int* csr_src = type ? csr1 : csr0;
    const float* asv = type ? as1 : as0;
    const float* adv = type ? ad1 : ad0;
    float* Out = type ? O1 : O0;
    int node = (bid - (type ? gseg : 0)) * 4 + (threadIdx.x >> 6);
    if (node >= NNODES) return;
    int lane = threadIdx.x & 63;
    int start = rowptr[node], end = rowptr[node + 1];
    int deg = end - start;
    float ad0v = adv[node * 2 + 0], ad1v = adv[node * 2 + 1];

    float m0 = -1e30f, m1 = -1e30f;
    for (int i = lane; i < deg; i += 64) {
        int s = csr_src[start + i];
        float r0 = asv[s * 2 + 0] + ad0v; r0 = r0 >= 0.f ? r0 : NEG * r0;
        float r1 = asv[s * 2 + 1] + ad1v; r1 = r1 >= 0.f ? r1 : NEG * r1;
        m0 = fmaxf(m0, r0); m1 = fmaxf(m1, r1);
    }
#pragma unroll
    for (int t = 32; t >= 1; t >>= 1) {
        m0 = fmaxf(m0, __shfl_xor(m0, t, 64));
        m1 = fmaxf(m1, __shfl_xor(m1, t, 64));
    }
    float s0 = 0.f, s1 = 0.f;
    for (int i = lane; i < deg; i += 64) {
        int s = csr_src[start + i];
        float r0 = asv[s * 2 + 0] + ad0v; r0 = r0 >= 0.f ? r0 : NEG * r0;
        float r1 = asv[s * 2 + 1] + ad1v; r1 = r1 >= 0.f ? r1 : NEG * r1;
        s0 += __expf(r0 - m0); s1 += __expf(r1 - m1);
    }
#pragma unroll
    for (int t = 32; t >= 1; t >>= 1) {
        s0 += __shfl_xor(s0, t, 64);
        s1 += __shfl_xor(s1, t, 64);
    }
    float inv0 = 1.f / (s0 + 1e-16f);
    float inv1 = 1.f / (s1 + 1e-16f);

    float acc0 = 0.f, acc1 = 0.f;
    for (int i = 0; i < deg; ++i) {
        int s = csr_src[start + i];
        float r0 = asv[s * 2 + 0] + ad0v; r0 = r0 >= 0.f ? r0 : NEG * r0;
        float r1 = asv[s * 2 + 1] + ad1v; r1 = r1 >= 0.f ? r1 : NEG * r1;
        float a0 = __expf(r0 - m0) * inv0;
        float a1 = __expf(r1 - m1) * inv1;
        const float* hrow = Hfeat + (long)s * CDIM;
        acc0 = fmaf(hrow[lane], a0, acc0);
        acc1 = fmaf(hrow[64 + lane], a1, acc1);
    }
    Out[(long)node * CDIM + lane] = acc0;
    Out[(long)node * CDIM + 64 + lane] = acc1;
}

__global__ void attn_finalize_kernel(const float* __restrict__ sacc, float* __restrict__ attn) {
    float s0 = sacc[0] / (float)NNODES;
    float s1 = sacc[1] / (float)NNODES;
    float m = fmaxf(s0, s1);
    float e0 = expf(s0 - m), e1 = expf(s1 - m);
    float inv = 1.f / (e0 + e1);
    attn[0] = e0 * inv;
    attn[1] = e1 * inv;
}

__global__ __launch_bounds__(256)
void combine_kernel(const float* __restrict__ O0, const float* __restrict__ O1,
                    const float* __restrict__ attn, float* __restrict__ Hn) {
    long i = (long)blockIdx.x * blockDim.x + threadIdx.x;
    long total = (long)NNODES * CDIM / 4;
    if (i >= total) return;
    float a0 = attn[0], a1 = attn[1];
    float4 v0 = ((const float4*)O0)[i];
    float4 v1 = ((const float4*)O1)[i];
    float4 o;
    o.x = a0 * fmaxf(v0.x, 0.f) + a1 * fmaxf(v1.x, 0.f);
    o.y = a0 * fmaxf(v0.y, 0.f) + a1 * fmaxf(v1.y, 0.f);
    o.z = a0 * fmaxf(v0.z, 0.f) + a1 * fmaxf(v1.z, 0.f);
    o.w = a0 * fmaxf(v0.w, 0.f) + a1 * fmaxf(v1.w, 0.f);
    ((float4*)Hn)[i] = o;
}

__global__ __launch_bounds__(256)
void final_linear_kernel(const float* __restrict__ Hn, const float* __restrict__ lw,
                         const float* __restrict__ lb, float* __restrict__ out) {
    __shared__ float lws[CDIM * FOUT];
    int tid = threadIdx.x;
    for (int i = tid; i < CDIM * FOUT; i += 256) lws[i] = lw[i];
    __syncthreads();
    int idx = blockIdx.x * 256 + tid;
    if (idx >= NNODES * FOUT) return;
    int n = idx >> 3, o = idx & 7;
    const float4* row = (const float4*)(Hn + (long)n * CDIM);
    float acc = lb[o];
#pragma unroll
    for (int k4 = 0; k4 < 32; ++k4) {
        float4 v = row[k4];
        acc = fmaf(v.x, lws[(k4 * 4 + 0) * FOUT + o], acc);
        acc = fmaf(v.y, lws[(k4 * 4 + 1) * FOUT + o], acc);
        acc = fmaf(v.z, lws[(k4 * 4 + 2) * FOUT + o], acc);
        acc = fmaf(v.w, lws[(k4 * 4 + 3) * FOUT + o], acc);
    }
    out[idx] = acc;
}

static void run_layer(const float* X, int K,
                      const float* pw, const float* pb,
                      const float* ats, const float* atd,
                      const float* q, const float* kw, const float* kb,
                      const int* rowptr0, const int* csr0,
                      const int* rowptr1, const int* csr1,
                      float* Hbuf, float* O0, float* O1, float* OutBuf,
                      float* asrc, float* adst,
                      float* sacc, float* attn, unsigned short* kwT_b,
                      hipStream_t stream) {
    const int gtile = NNODES / 32;  // 3125 exactly
    if (K == 64)
        proj_kernel3<64><<<gtile, 256, 0, stream>>>(X, pw, pb, ats, atd, Hbuf, asrc, adst);
    else
        proj_kernel3<128><<<gtile, 256, 0, stream>>>(X, pw, pb, ats, atd, Hbuf, asrc, adst);

    cvt_kwT_kernel<<<64, 256, 0, stream>>>(kw, kwT_b);

    const int nh = NNODES * HHEADS;
    const int gseg = (NNODES + 3) / 4;
    seg_aggregate_dual<<<2 * gseg, 256, 0, stream>>>(
        rowptr0, csr0, asrc, adst, O0,
        rowptr1, csr1, asrc + nh, adst + nh, O1, Hbuf, gseg);

    hipMemsetAsync(sacc, 0, 2 * sizeof(float), stream);
    const int gsc = (NNODES + 63) / 64;  // 1563
    score_mfma<<<gsc, 256, 0, stream>>>(O0, kwT_b, kb, q, sacc + 0);
    score_mfma<<<gsc, 256, 0, stream>>>(O1, kwT_b, kb, q, sacc + 1);
    attn_finalize_kernel<<<1, 1, 0, stream>>>(sacc, attn);
    const long q4 = (long)NNODES * CDIM / 4;
    combine_kernel<<<(int)((q4 + 255) / 256), 256, 0, stream>>>(O0, O1, attn, OutBuf);
}

extern "C" void kernel_launch(void* const* d_in, const int* in_sizes, int n_in,
                              void* d_out, int out_size, void* d_ws, size_t ws_size,
                              hipStream_t stream) {
    const float* x          = (const float*)d_in[0];
    const int*   ei_spatial = (const int*)d_in[1];
    const int*   ei_similar = (const int*)d_in[2];
    const float* p1_proj_w  = (const float*)d_in[3];
    const float* p1_proj_b  = (const float*)d_in[4];
    const float* p1_att_src = (const float*)d_in[5];
    const float* p1_att_dst = (const float*)d_in[6];
    const float* p1_q       = (const float*)d_in[7];
    const float* p1_kw      = (const float*)d_in[8];
    const float* p1_kb      = (const float*)d_in[9];
    const float* p2_proj_w  = (const float*)d_in[10];
    const float* p2_proj_b  = (const float*)d_in[11];
    const float* p2_att_src = (const float*)d_in[12];
    const float* p2_att_dst = (const float*)d_in[13];
    const float* p2_q       = (const float*)d_in[14];
    const float* p2_kw      = (const float*)d_in[15];
    const float* p2_kb      = (const float*)d_in[16];
    const float* lin_w      = (const float*)d_in[17];
    const float* lin_b      = (const float*)d_in[18];

    float* ws = (float*)d_ws;
    const size_t nc = (size_t)NNODES * CDIM;
    const size_t nh2 = (size_t)NNODES * HHEADS;

    float* A    = ws;
    float* B    = A + nc;
    float* Cb   = B + nc;
    float* asrc = Cb + nc;               // 2*N*H
    float* adst = asrc + 2 * nh2;        // 2*N*H
    float* sacc = adst + 2 * nh2;        // 2
    float* attn = sacc + 2;              // 2
    int* rowptr0 = (int*)(attn + 2);
    int* rowptr1 = rowptr0 + (NNODES + 1);
    int* csr0    = rowptr1 + (NNODES + 1);
    int* csr1    = csr0 + EEDGES;
    int* scratch = csr1 + EEDGES;        // deg/cursor, NNODES ints
    int* bsum    = scratch + NNODES;     // SB ints
    uintptr_t kp = (uintptr_t)(bsum + SB);
    kp = (kp + 15) & ~(uintptr_t)15;
    unsigned short* kwT_b = (unsigned short*)kp;  // 128*128 bf16

    // ---- build CSR for both edge types (structure reused across layers) ----
    const int g_e = (EEDGES + 255) / 256;
    const int* eis[2] = {ei_spatial, ei_similar};
    int* rps[2] = {rowptr0, rowptr1};
    int* csrs[2] = {csr0, csr1};
    for (int i = 0; i < 2; ++i) {
        const int* src = eis[i];
        const int* dst = eis[i] + EEDGES;
        hipMemsetAsync(scratch, 0, NNODES * sizeof(int), stream);
        hist_kernel<<<g_e, 256, 0, stream>>>(dst, scratch);
        scan_partial<<<SB, 256, 0, stream>>>(scratch, bsum);
        scan_bsum<<<1, 64, 0, stream>>>(bsum);
        scan_final<<<SB, 256, 0, stream>>>(scratch, bsum, rps[i]);
        hipMemcpyAsync(scratch, rps[i], NNODES * sizeof(int),
                       hipMemcpyDeviceToDevice, stream);
        fill_kernel<<<g_e, 256, 0, stream>>>(src, dst, scratch, csrs[i]);
    }

    // Layer 1: h1 -> A ; per-type outs -> B, Cb ; combined -> A
    run_layer(x, FIN, p1_proj_w, p1_proj_b, p1_att_src, p1_att_dst,
              p1_q, p1_kw, p1_kb, rowptr0, csr0, rowptr1, csr1,
              A, B, Cb, A, asrc, adst, sacc, attn, kwT_b, stream);

    // Layer 2: X = A ; h2 -> B ; per-type outs -> Cb, A ; combined -> B
    run_layer(A, CDIM, p2_proj_w, p2_proj_b, p2_att_src, p2_att_dst,
              p2_q, p2_kw, p2_kb, rowptr0, csr0, rowptr1, csr1,
              B, Cb, A, B, asrc, adst, sacc, attn, kwT_b, stream);

    // Final classifier
    const int gfin = (NNODES * FOUT + 255) / 256;
    final_linear_kernel<<<gfin, 256, 0, stream>>>(B, lin_w, lin_b, (float*)d_out);
}

// Round 7
// 918.638 us; speedup vs baseline: 3.2920x; 1.1650x over previous
//
#include <hip/hip_runtime.h>

#define NNODES 100000
#define EEDGES 600000
#define CDIM 128
#define HHEADS 2
#define DDIM 64
#define FIN 64
#define FOUT 8
#define NEG 0.2f

#define SB 200    // scan blocks
#define SCH 500   // nodes per scan block (200*500 = 100000 exactly)

typedef short bf16x8 __attribute__((ext_vector_type(8)));
typedef unsigned short ushort8 __attribute__((ext_vector_type(8)));
typedef float f32x4 __attribute__((ext_vector_type(4)));

__device__ __forceinline__ float tanh_fast(float x) {
    float e = __expf(2.f * x);
    return 1.f - 2.f / (e + 1.f);  // stable: x->+inf => 1, x->-inf => -1
}

__device__ __forceinline__ unsigned short f2bf(float x) {
    unsigned int u = __float_as_uint(x);
    unsigned int r = (u + 0x7FFFu + ((u >> 16) & 1u)) >> 16;  // RNE
    return (unsigned short)r;
}

// ============ register-tiled GEMM core v3 (f32): for projection ============
template<int K, bool RELU_IN>
__device__ __forceinline__ void gemm_tile3(const float* __restrict__ X,
                                           const float* __restrict__ W,
                                           const float* __restrict__ bias,
                                           int row0, float acc[4][4], float* wch) {
    int tid = threadIdx.x;
    int rb = tid >> 5, cb = tid & 31;
    int c0 = cb * 4;
#pragma unroll
    for (int j = 0; j < 4; ++j) {
        float b = bias[c0 + j];
#pragma unroll
        for (int r = 0; r < 4; ++r) acc[r][j] = b;
    }
    const float* xbase = X + (long)(row0 + rb * 4) * K;

    for (int kc = 0; kc < K; kc += 32) {
        __syncthreads();
#pragma unroll
        for (int i = 0; i < 4; ++i) {
            int idx = tid + i * 256;
            ((float4*)wch)[idx] = ((const float4*)(W + kc * CDIM))[idx];
        }
        __syncthreads();
#pragma unroll
        for (int k0 = 0; k0 < 32; k0 += 4) {
            float4 xr[4];
#pragma unroll
            for (int r = 0; r < 4; ++r) {
                xr[r] = *(const float4*)(xbase + r * K + kc + k0);
                if (RELU_IN) {
                    xr[r].x = fmaxf(xr[r].x, 0.f);
                    xr[r].y = fmaxf(xr[r].y, 0.f);
                    xr[r].z = fmaxf(xr[r].z, 0.f);
                    xr[r].w = fmaxf(xr[r].w, 0.f);
                }
            }
            float4 wv[4];
#pragma unroll
            for (int kk = 0; kk < 4; ++kk)
                wv[kk] = *(const float4*)(wch + (k0 + kk) * CDIM + c0);
#pragma unroll
            for (int r = 0; r < 4; ++r) {
                const float* xf = (const float*)&xr[r];
#pragma unroll
                for (int kk = 0; kk < 4; ++kk) {
                    const float* wf = (const float*)&wv[kk];
#pragma unroll
                    for (int j = 0; j < 4; ++j)
                        acc[r][j] = fmaf(xf[kk], wf[j], acc[r][j]);
                }
            }
        }
    }
}

// ---- projection: H = X@W + b, fused per-edge-type per-head attention dots ----
template<int K>
__global__ __launch_bounds__(256, 4)
void proj_kernel3(const float* __restrict__ X, const float* __restrict__ W,
                  const float* __restrict__ bias,
                  const float* __restrict__ att_src, const float* __restrict__ att_dst,
                  float* __restrict__ Hout,
                  float* __restrict__ a_src, float* __restrict__ a_dst) {
    __shared__ float wch[32 * CDIM];
    float acc[4][4];
    int row0 = blockIdx.x * 32;
    gemm_tile3<K, false>(X, W, bias, row0, acc, wch);
    int tid = threadIdx.x, rb = tid >> 5, cb = tid & 31;
    int c0 = cb * 4;
#pragma unroll
    for (int r = 0; r < 4; ++r) {
        int row = row0 + rb * 4 + r;
        float4 o = make_float4(acc[r][0], acc[r][1], acc[r][2], acc[r][3]);
        *(float4*)(Hout + (long)row * CDIM + c0) = o;
    }
#pragma unroll
    for (int i = 0; i < 2; ++i) {
        float as4[4], ad4[4];
#pragma unroll
        for (int j = 0; j < 4; ++j) {
            as4[j] = att_src[i * CDIM + c0 + j];
            ad4[j] = att_dst[i * CDIM + c0 + j];
        }
#pragma unroll
        for (int r = 0; r < 4; ++r) {
            float s = acc[r][0] * as4[0] + acc[r][1] * as4[1]
                    + acc[r][2] * as4[2] + acc[r][3] * as4[3];
            float d = acc[r][0] * ad4[0] + acc[r][1] * ad4[1]
                    + acc[r][2] * ad4[2] + acc[r][3] * ad4[3];
#pragma unroll
            for (int m = 8; m >= 1; m >>= 1) {
                s += __shfl_xor(s, m, 64);
                d += __shfl_xor(d, m, 64);
            }
            if ((cb & 15) == 0) {
                int hh = cb >> 4;
                int row = row0 + rb * 4 + r;
                long base = (long)i * NNODES * HHEADS + (long)row * HHEADS + hh;
                a_src[base] = s;
                a_dst[base] = d;
            }
        }
    }
}

// ---- kw -> transposed bf16 (once per layer): kwT_b[c][k] = bf16(kw[k][c]) ----
__global__ __launch_bounds__(256)
void cvt_kwT_kernel(const float* __restrict__ kw, unsigned short* __restrict__ kwT_b) {
    int idx = blockIdx.x * 256 + threadIdx.x;  // 64 blocks x 256 = 16384
    int c = idx >> 7, k = idx & 127;
    kwT_b[idx] = f2bf(kw[k * CDIM + c]);
}

// ---- semantic score via MFMA ----
__global__ __launch_bounds__(256, 3)
void score_mfma(const float* __restrict__ Om, const unsigned short* __restrict__ kwT_b,
                const float* __restrict__ kb, const float* __restrict__ q,
                float* __restrict__ sacc) {
    __shared__ ushort8 As8[64 * 16];    // 16 KB: [row][u] swizzled
    __shared__ ushort8 Bs8[128 * 16];   // 32 KB: [c][u] swizzled
    int tid = threadIdx.x;
    int row0 = blockIdx.x * 64;

#pragma unroll
    for (int i = 0; i < 4; ++i) {
        int idx = tid + i * 256;
        int row = idx >> 4, u = idx & 15;
        int grow = row0 + row;
        ushort8 v;
        if (grow < NNODES) {
            const float* p = Om + (long)grow * CDIM + u * 8;
            float4 a = *(const float4*)p;
            float4 b = *(const float4*)(p + 4);
            v[0] = f2bf(fmaxf(a.x, 0.f)); v[1] = f2bf(fmaxf(a.y, 0.f));
            v[2] = f2bf(fmaxf(a.z, 0.f)); v[3] = f2bf(fmaxf(a.w, 0.f));
            v[4] = f2bf(fmaxf(b.x, 0.f)); v[5] = f2bf(fmaxf(b.y, 0.f));
            v[6] = f2bf(fmaxf(b.z, 0.f)); v[7] = f2bf(fmaxf(b.w, 0.f));
        } else {
            v = (ushort8)0;
        }
        As8[row * 16 + (u ^ (row & 7))] = v;
    }
#pragma unroll
    for (int i = 0; i < 8; ++i) {
        int idx = tid + i * 256;
        int c = idx >> 4, u = idx & 15;
        Bs8[c * 16 + (u ^ (c & 7))] = ((const ushort8*)kwT_b)[idx];
    }
    __syncthreads();

    int l = tid & 63, w = tid >> 6;
    int lrow = w * 16 + (l & 15);
    int ug = l >> 4;
    f32x4 acc[8];
#pragma unroll
    for (int ct = 0; ct < 8; ++ct) acc[ct] = (f32x4)0.f;

#pragma unroll
    for (int kc = 0; kc < 4; ++kc) {
        int u = kc * 4 + ug;
        bf16x8 af = *(const bf16x8*)&As8[lrow * 16 + (u ^ (lrow & 7))];
#pragma unroll
        for (int ct = 0; ct < 8; ++ct) {
            int c = ct * 16 + (l & 15);
            bf16x8 bf = *(const bf16x8*)&Bs8[c * 16 + (u ^ (c & 7))];
            acc[ct] = __builtin_amdgcn_mfma_f32_16x16x32_bf16(af, bf, acc[ct], 0, 0, 0);
        }
    }

    float s = 0.f;
#pragma unroll
    for (int ct = 0; ct < 8; ++ct) {
        int c = ct * 16 + (l & 15);
        float qc = q[c], kbc = kb[c];
#pragma unroll
        for (int v = 0; v < 4; ++v) {
            int grow = row0 + w * 16 + (l >> 4) * 4 + v;
            if (grow < NNODES) s += qc * tanh_fast(acc[ct][v] + kbc);
        }
    }
#pragma unroll
    for (int m = 32; m >= 1; m >>= 1) s += __shfl_xor(s, m, 64);
    if (l == 0) atomicAdd(sacc, s);
}

// ============ CSR build ============
__global__ void hist_kernel(const int* __restrict__ dst, int* __restrict__ deg) {
    int e = blockIdx.x * blockDim.x + threadIdx.x;
    if (e < EEDGES) atomicAdd(&deg[dst[e]], 1);
}

// 3-phase decoupled scan over deg[NNODES] -> exclusive rowptr
__global__ __launch_bounds__(256)
void scan_partial(const int* __restrict__ deg, int* __restrict__ bsum) {
    __shared__ int red[256];
    int b = blockIdx.x, t = threadIdx.x;
    int s = 0;
    if (t < 250) {
        int base = b * SCH + t * 2;
        s = deg[base] + deg[base + 1];
    }
    red[t] = s;
    __syncthreads();
#pragma unroll
    for (int off = 128; off >= 1; off >>= 1) {
        if (t < off) red[t] += red[t + off];
        __syncthreads();
    }
    if (t == 0) bsum[b] = red[0];
}

__global__ void scan_bsum(int* __restrict__ bsum) {
    if (threadIdx.x == 0) {
        int run = 0;
        for (int i = 0; i < SB; ++i) { int v = bsum[i]; bsum[i] = run; run += v; }
    }
}

__global__ __launch_bounds__(256)
void scan_final(const int* __restrict__ deg, const int* __restrict__ bsum,
                int* __restrict__ rowptr) {
    __shared__ int ts[256];
    int b = blockIdx.x, t = threadIdx.x;
    int d0 = 0, d1 = 0;
    int base = b * SCH + t * 2;
    if (t < 250) { d0 = deg[base]; d1 = deg[base + 1]; }
    ts[t] = d0 + d1;
    __syncthreads();
#pragma unroll
    for (int off = 1; off < 256; off <<= 1) {
        int v = (t >= off) ? ts[t - off] : 0;
        __syncthreads();
        ts[t] += v;
        __syncthreads();
    }
    if (t < 250) {
        int excl = bsum[b] + (t > 0 ? ts[t - 1] : 0);
        rowptr[base] = excl;
        rowptr[base + 1] = excl + d0;
    }
    if (b == 0 && t == 0) rowptr[NNODES] = EEDGES;
}

__global__ void fill_kernel(const int* __restrict__ src, const int* __restrict__ dst,
                            int* __restrict__ cursor, int* __restrict__ csr_src) {
    int e = blockIdx.x * blockDim.x + threadIdx.x;
    if (e < EEDGES) {
        int pos = atomicAdd(&cursor[dst[e]], 1);
        csr_src[pos] = src[e];
    }
}

// ============ single-pass fused edge softmax + aggregation, both edge types ============
// Softmax is shift-invariant: alpha = e^r / sum(e^r) needs no max subtraction when
// |r| is bounded (here |r| <~ 3 by data scale), so one pass accumulates both
// sum(e) and sum(e*h) and normalizes at the end. Lane l holds channels 2l,2l+1;
// lanes 0-31 = head 0 (weight e0), lanes 32-63 = head 1 (weight e1).
__global__ __launch_bounds__(256)
void seg_aggregate_dual(const int* __restrict__ rowptr0, const int* __restrict__ csr0,
                        const float* __restrict__ as0, const float* __restrict__ ad0,
                        float* __restrict__ O0,
                        const int* __restrict__ rowptr1, const int* __restrict__ csr1,
                        const float* __restrict__ as1, const float* __restrict__ ad1,
                        float* __restrict__ O1,
                        const float* __restrict__ Hfeat, int gseg) {
    int bid = blockIdx.x;
    int type = bid >= gseg;
    const int* rowptr = type ? rowptr1 : rowptr0;
    const int* csr_src = type ? csr1 : csr0;
    const float* asv = type ? as1 : as0;
    const float* adv = type ? ad1 : ad0;
    float* Out = type ? O1 : O0;
    int node = (bid - (type ? gseg : 0)) * 4 + (threadIdx.x >> 6);
    if (node >= NNODES) return;
    int lane = threadIdx.x & 63;
    int start = rowptr[node], end = rowptr[node + 1];
    float2 adn = *(const float2*)(adv + node * 2);
    const float2* H2 = (const float2*)Hfeat;

    float s0 = 0.f, s1 = 0.f;
    float accx = 0.f, accy = 0.f;
    int i = start;
    // 2-unrolled for memory-level parallelism (gathers of both edges in flight)
    for (; i + 1 < end; i += 2) {
        int sA = csr_src[i], sB = csr_src[i + 1];
        float2 asA = *(const float2*)(asv + sA * 2);
        float2 asB = *(const float2*)(asv + sB * 2);
        float2 hA = H2[(long)sA * 64 + lane];
        float2 hB = H2[(long)sB * 64 + lane];
        float rA0 = asA.x + adn.x; rA0 = rA0 >= 0.f ? rA0 : NEG * rA0;
        float rA1 = asA.y + adn.y; rA1 = rA1 >= 0.f ? rA1 : NEG * rA1;
        float rB0 = asB.x + adn.x; rB0 = rB0 >= 0.f ? rB0 : NEG * rB0;
        float rB1 = asB.y + adn.y; rB1 = rB1 >= 0.f ? rB1 : NEG * rB1;
        float eA0 = __expf(rA0), eA1 = __expf(rA1);
        float eB0 = __expf(rB0), eB1 = __expf(rB1);
        s0 += eA0 + eB0; s1 += eA1 + eB1;
        float wA = lane < 32 ? eA0 : eA1;
        float wB = lane < 32 ? eB0 : eB1;
        accx = fmaf(hA.x, wA, accx); accy = fmaf(hA.y, wA, accy);
        accx = fmaf(hB.x, wB, accx); accy = fmaf(hB.y, wB, accy);
    }
    if (i < end) {
        int sA = csr_src[i];
        float2 asA = *(const float2*)(asv + sA * 2);
        float2 hA = H2[(long)sA * 64 + lane];
        float rA0 = asA.x + adn.x; rA0 = rA0 >= 0.f ? rA0 : NEG * rA0;
        float rA1 = asA.y + adn.y; rA1 = rA1 >= 0.f ? rA1 : NEG * rA1;
        float eA0 = __expf(rA0), eA1 = __expf(rA1);
        s0 += eA0; s1 += eA1;
        float wA = lane < 32 ? eA0 : eA1;
        accx = fmaf(hA.x, wA, accx); accy = fmaf(hA.y, wA, accy);
    }
    float ssel = lane < 32 ? s0 : s1;
    float inv = ssel > 0.f ? 1.f / ssel : 0.f;
    float2 o = make_float2(accx * inv, accy * inv);
    ((float2*)Out)[(long)node * 64 + lane] = o;
}

__global__ void attn_finalize_kernel(const float* __restrict__ sacc, float* __restrict__ attn) {
    float s0 = sacc[0] / (float)NNODES;
    float s1 = sacc[1] / (float)NNODES;
    float m = fmaxf(s0, s1);
    float e0 = expf(s0 - m), e1 = expf(s1 - m);
    float inv = 1.f / (e0 + e1);
    attn[0] = e0 * inv;
    attn[1] = e1 * inv;
}

__global__ __launch_bounds__(256)
void combine_kernel(const float* __restrict__ O0, const float* __restrict__ O1,
                    const float* __restrict__ attn, float* __restrict__ Hn) {
    long i = (long)blockIdx.x * blockDim.x + threadIdx.x;
    long total = (long)NNODES * CDIM / 4;
    if (i >= total) return;
    float a0 = attn[0], a1 = attn[1];
    float4 v0 = ((const float4*)O0)[i];
    float4 v1 = ((const float4*)O1)[i];
    float4 o;
    o.x = a0 * fmaxf(v0.x, 0.f) + a1 * fmaxf(v1.x, 0.f);
    o.y = a0 * fmaxf(v0.y, 0.f) + a1 * fmaxf(v1.y, 0.f);
    o.z = a0 * fmaxf(v0.z, 0.f) + a1 * fmaxf(v1.z, 0.f);
    o.w = a0 * fmaxf(v0.w, 0.f) + a1 * fmaxf(v1.w, 0.f);
    ((float4*)Hn)[i] = o;
}

__global__ __launch_bounds__(256)
void final_linear_kernel(const float* __restrict__ Hn, const float* __restrict__ lw,
                         const float* __restrict__ lb, float* __restrict__ out) {
    __shared__ float lws[CDIM * FOUT];
    int tid = threadIdx.x;
    for (int i = tid; i < CDIM * FOUT; i += 256) lws[i] = lw[i];
    __syncthreads();
    int idx = blockIdx.x * 256 + tid;
    if (idx >= NNODES * FOUT) return;
    int n = idx >> 3, o = idx & 7;
    const float4* row = (const float4*)(Hn + (long)n * CDIM);
    float acc = lb[o];
#pragma unroll
    for (int k4 = 0; k4 < 32; ++k4) {
        float4 v = row[k4];
        acc = fmaf(v.x, lws[(k4 * 4 + 0) * FOUT + o], acc);
        acc = fmaf(v.y, lws[(k4 * 4 + 1) * FOUT + o], acc);
        acc = fmaf(v.z, lws[(k4 * 4 + 2) * FOUT + o], acc);
        acc = fmaf(v.w, lws[(k4 * 4 + 3) * FOUT + o], acc);
    }
    out[idx] = acc;
}

static void run_layer(const float* X, int K,
                      const float* pw, const float* pb,
                      const float* ats, const float* atd,
                      const float* q, const float* kw, const float* kb,
                      const int* rowptr0, const int* csr0,
                      const int* rowptr1, const int* csr1,
                      float* Hbuf, float* O0, float* O1, float* OutBuf,
                      float* asrc, float* adst,
                      float* sacc, float* attn, unsigned short* kwT_b,
                      hipStream_t stream) {
    const int gtile = NNODES / 32;  // 3125 exactly
    if (K == 64)
        proj_kernel3<64><<<gtile, 256, 0, stream>>>(X, pw, pb, ats, atd, Hbuf, asrc, adst);
    else
        proj_kernel3<128><<<gtile, 256, 0, stream>>>(X, pw, pb, ats, atd, Hbuf, asrc, adst);

    cvt_kwT_kernel<<<64, 256, 0, stream>>>(kw, kwT_b);

    const int nh = NNODES * HHEADS;
    const int gseg = (NNODES + 3) / 4;
    seg_aggregate_dual<<<2 * gseg, 256, 0, stream>>>(
        rowptr0, csr0, asrc, adst, O0,
        rowptr1, csr1, asrc + nh, adst + nh, O1, Hbuf, gseg);

    hipMemsetAsync(sacc, 0, 2 * sizeof(float), stream);
    const int gsc = (NNODES + 63) / 64;  // 1563
    score_mfma<<<gsc, 256, 0, stream>>>(O0, kwT_b, kb, q, sacc + 0);
    score_mfma<<<gsc, 256, 0, stream>>>(O1, kwT_b, kb, q, sacc + 1);
    attn_finalize_kernel<<<1, 1, 0, stream>>>(sacc, attn);
    const long q4 = (long)NNODES * CDIM / 4;
    combine_kernel<<<(int)((q4 + 255) / 256), 256, 0, stream>>>(O0, O1, attn, OutBuf);
}

extern "C" void kernel_launch(void* const* d_in, const int* in_sizes, int n_in,
                              void* d_out, int out_size, void* d_ws, size_t ws_size,
                              hipStream_t stream) {
    const float* x          = (const float*)d_in[0];
    const int*   ei_spatial = (const int*)d_in[1];
    const int*   ei_similar = (const int*)d_in[2];
    const float* p1_proj_w  = (const float*)d_in[3];
    const float* p1_proj_b  = (const float*)d_in[4];
    const float* p1_att_src = (const float*)d_in[5];
    const float* p1_att_dst = (const float*)d_in[6];
    const float* p1_q       = (const float*)d_in[7];
    const float* p1_kw      = (const float*)d_in[8];
    const float* p1_kb      = (const float*)d_in[9];
    const float* p2_proj_w  = (const float*)d_in[10];
    const float* p2_proj_b  = (const float*)d_in[11];
    const float* p2_att_src = (const float*)d_in[12];
    const float* p2_att_dst = (const float*)d_in[13];
    const float* p2_q       = (const float*)d_in[14];
    const float* p2_kw      = (const float*)d_in[15];
    const float* p2_kb      = (const float*)d_in[16];
    const float* lin_w      = (const float*)d_in[17];
    const float* lin_b      = (const float*)d_in[18];

    float* ws = (float*)d_ws;
    const size_t nc = (size_t)NNODES * CDIM;
    const size_t nh2 = (size_t)NNODES * HHEADS;

    float* A    = ws;
    float* B    = A + nc;
    float* Cb   = B + nc;
    float* asrc = Cb + nc;               // 2*N*H
    float* adst = asrc + 2 * nh2;        // 2*N*H
    float* sacc = adst + 2 * nh2;        // 2
    float* attn = sacc + 2;              // 2
    int* rowptr0 = (int*)(attn + 2);
    int* rowptr1 = rowptr0 + (NNODES + 1);
    int* csr0    = rowptr1 + (NNODES + 1);
    int* csr1    = csr0 + EEDGES;
    int* scratch = csr1 + EEDGES;        // deg/cursor, NNODES ints
    int* bsum    = scratch + NNODES;     // SB ints
    uintptr_t kp = (uintptr_t)(bsum + SB);
    kp = (kp + 15) & ~(uintptr_t)15;
    unsigned short* kwT_b = (unsigned short*)kp;  // 128*128 bf16

    // ---- build CSR for both edge types (structure reused across layers) ----
    const int g_e = (EEDGES + 255) / 256;
    const int* eis[2] = {ei_spatial, ei_similar};
    int* rps[2] = {rowptr0, rowptr1};
    int* csrs[2] = {csr0, csr1};
    for (int i = 0; i < 2; ++i) {
        const int* src = eis[i];
        const int* dst = eis[i] + EEDGES;
        hipMemsetAsync(scratch, 0, NNODES * sizeof(int), stream);
        hist_kernel<<<g_e, 256, 0, stream>>>(dst, scratch);
        scan_partial<<<SB, 256, 0, stream>>>(scratch, bsum);
        scan_bsum<<<1, 64, 0, stream>>>(bsum);
        scan_final<<<SB, 256, 0, stream>>>(scratch, bsum, rps[i]);
        hipMemcpyAsync(scratch, rps[i], NNODES * sizeof(int),
                       hipMemcpyDeviceToDevice, stream);
        fill_kernel<<<g_e, 256, 0, stream>>>(src, dst, scratch, csrs[i]);
    }

    // Layer 1: h1 -> A ; per-type outs -> B, Cb ; combined -> A
    run_layer(x, FIN, p1_proj_w, p1_proj_b, p1_att_src, p1_att_dst,
              p1_q, p1_kw, p1_kb, rowptr0, csr0, rowptr1, csr1,
              A, B, Cb, A, asrc, adst, sacc, attn, kwT_b, stream);

    // Layer 2: X = A ; h2 -> B ; per-type outs -> Cb, A ; combined -> B
    run_layer(A, CDIM, p2_proj_w, p2_proj_b, p2_att_src, p2_att_dst,
              p2_q, p2_kw, p2_kb, rowptr0, csr0, rowptr1, csr1,
              B, Cb, A, B, asrc, adst, sacc, attn, kwT_b, stream);

    // Final classifier
    const int gfin = (NNODES * FOUT + 255) / 256;
    final_linear_kernel<<<gfin, 256, 0, stream>>>(B, lin_w, lin_b, (float*)d_out);
}

// Round 8
// 871.665 us; speedup vs baseline: 3.4694x; 1.0539x over previous
//
#include <hip/hip_runtime.h>

#define NNODES 100000
#define EEDGES 600000
#define CDIM 128
#define HHEADS 2
#define DDIM 64
#define FIN 64
#define FOUT 8
#define NEG 0.2f

#define SB 200    // scan blocks
#define SCH 500   // nodes per scan block (200*500 = 100000 exactly)

typedef short bf16x8 __attribute__((ext_vector_type(8)));
typedef unsigned short ushort8 __attribute__((ext_vector_type(8)));
typedef float f32x4 __attribute__((ext_vector_type(4)));

__device__ __forceinline__ float tanh_fast(float x) {
    float e = __expf(2.f * x);
    return 1.f - 2.f / (e + 1.f);  // stable: x->+inf => 1, x->-inf => -1
}

__device__ __forceinline__ unsigned short f2bf(float x) {
    unsigned int u = __float_as_uint(x);
    unsigned int r = (u + 0x7FFFu + ((u >> 16) & 1u)) >> 16;  // RNE
    return (unsigned short)r;
}
__device__ __forceinline__ float bf2f(unsigned short u) {
    return __uint_as_float(((unsigned int)u) << 16);
}

// ============ register-tiled GEMM core v3 (f32): for projection ============
template<int K, bool RELU_IN>
__device__ __forceinline__ void gemm_tile3(const float* __restrict__ X,
                                           const float* __restrict__ W,
                                           const float* __restrict__ bias,
                                           int row0, float acc[4][4], float* wch) {
    int tid = threadIdx.x;
    int rb = tid >> 5, cb = tid & 31;
    int c0 = cb * 4;
#pragma unroll
    for (int j = 0; j < 4; ++j) {
        float b = bias[c0 + j];
#pragma unroll
        for (int r = 0; r < 4; ++r) acc[r][j] = b;
    }
    const float* xbase = X + (long)(row0 + rb * 4) * K;

    for (int kc = 0; kc < K; kc += 32) {
        __syncthreads();
#pragma unroll
        for (int i = 0; i < 4; ++i) {
            int idx = tid + i * 256;
            ((float4*)wch)[idx] = ((const float4*)(W + kc * CDIM))[idx];
        }
        __syncthreads();
#pragma unroll
        for (int k0 = 0; k0 < 32; k0 += 4) {
            float4 xr[4];
#pragma unroll
            for (int r = 0; r < 4; ++r) {
                xr[r] = *(const float4*)(xbase + r * K + kc + k0);
                if (RELU_IN) {
                    xr[r].x = fmaxf(xr[r].x, 0.f);
                    xr[r].y = fmaxf(xr[r].y, 0.f);
                    xr[r].z = fmaxf(xr[r].z, 0.f);
                    xr[r].w = fmaxf(xr[r].w, 0.f);
                }
            }
            float4 wv[4];
#pragma unroll
            for (int kk = 0; kk < 4; ++kk)
                wv[kk] = *(const float4*)(wch + (k0 + kk) * CDIM + c0);
#pragma unroll
            for (int r = 0; r < 4; ++r) {
                const float* xf = (const float*)&xr[r];
#pragma unroll
                for (int kk = 0; kk < 4; ++kk) {
                    const float* wf = (const float*)&wv[kk];
#pragma unroll
                    for (int j = 0; j < 4; ++j)
                        acc[r][j] = fmaf(xf[kk], wf[j], acc[r][j]);
                }
            }
        }
    }
}

// ---- projection: H = X@W + b -> bf16, fused per-edge-type per-head attention dots ----
// attention dots use the f32 accumulators (full precision); only stored H is bf16.
template<int K>
__global__ __launch_bounds__(256, 4)
void proj_kernel3(const float* __restrict__ X, const float* __restrict__ W,
                  const float* __restrict__ bias,
                  const float* __restrict__ att_src, const float* __restrict__ att_dst,
                  unsigned short* __restrict__ Hout,
                  float* __restrict__ a_src, float* __restrict__ a_dst) {
    __shared__ float wch[32 * CDIM];
    float acc[4][4];
    int row0 = blockIdx.x * 32;
    gemm_tile3<K, false>(X, W, bias, row0, acc, wch);
    int tid = threadIdx.x, rb = tid >> 5, cb = tid & 31;
    int c0 = cb * 4;
#pragma unroll
    for (int r = 0; r < 4; ++r) {
        int row = row0 + rb * 4 + r;
        ushort4 st;
        st.x = f2bf(acc[r][0]); st.y = f2bf(acc[r][1]);
        st.z = f2bf(acc[r][2]); st.w = f2bf(acc[r][3]);
        *(ushort4*)(Hout + (long)row * CDIM + c0) = st;
    }
#pragma unroll
    for (int i = 0; i < 2; ++i) {
        float as4[4], ad4[4];
#pragma unroll
        for (int j = 0; j < 4; ++j) {
            as4[j] = att_src[i * CDIM + c0 + j];
            ad4[j] = att_dst[i * CDIM + c0 + j];
        }
#pragma unroll
        for (int r = 0; r < 4; ++r) {
            float s = acc[r][0] * as4[0] + acc[r][1] * as4[1]
                    + acc[r][2] * as4[2] + acc[r][3] * as4[3];
            float d = acc[r][0] * ad4[0] + acc[r][1] * ad4[1]
                    + acc[r][2] * ad4[2] + acc[r][3] * ad4[3];
#pragma unroll
            for (int m = 8; m >= 1; m >>= 1) {
                s += __shfl_xor(s, m, 64);
                d += __shfl_xor(d, m, 64);
            }
            if ((cb & 15) == 0) {
                int hh = cb >> 4;
                int row = row0 + rb * 4 + r;
                long base = (long)i * NNODES * HHEADS + (long)row * HHEADS + hh;
                a_src[base] = s;
                a_dst[base] = d;
            }
        }
    }
}

// ---- kw -> transposed bf16 (once per layer): kwT_b[c][k] = bf16(kw[k][c]) ----
__global__ __launch_bounds__(256)
void cvt_kwT_kernel(const float* __restrict__ kw, unsigned short* __restrict__ kwT_b) {
    int idx = blockIdx.x * 256 + threadIdx.x;  // 64 blocks x 256 = 16384
    int c = idx >> 7, k = idx & 127;
    kwT_b[idx] = f2bf(kw[k * CDIM + c]);
}

// ---- semantic score via MFMA; Om is bf16, relu applied bitwise during staging ----
__global__ __launch_bounds__(256, 3)
void score_mfma(const unsigned short* __restrict__ Omb,
                const unsigned short* __restrict__ kwT_b,
                const float* __restrict__ kb, const float* __restrict__ q,
                float* __restrict__ sacc) {
    __shared__ ushort8 As8[64 * 16];    // 16 KB: [row][u] swizzled
    __shared__ ushort8 Bs8[128 * 16];   // 32 KB: [c][u] swizzled
    int tid = threadIdx.x;
    int row0 = blockIdx.x * 64;

#pragma unroll
    for (int i = 0; i < 4; ++i) {
        int idx = tid + i * 256;
        int row = idx >> 4, u = idx & 15;
        int grow = row0 + row;
        ushort8 v;
        if (grow < NNODES) {
            v = ((const ushort8*)Omb)[(long)grow * 16 + u];
#pragma unroll
            for (int e = 0; e < 8; ++e) v[e] = (v[e] & 0x8000) ? 0 : v[e];  // bf16 relu
        } else {
            v = (ushort8)0;
        }
        As8[row * 16 + (u ^ (row & 7))] = v;
    }
#pragma unroll
    for (int i = 0; i < 8; ++i) {
        int idx = tid + i * 256;
        int c = idx >> 4, u = idx & 15;
        Bs8[c * 16 + (u ^ (c & 7))] = ((const ushort8*)kwT_b)[idx];
    }
    __syncthreads();

    int l = tid & 63, w = tid >> 6;
    int lrow = w * 16 + (l & 15);
    int ug = l >> 4;
    f32x4 acc[8];
#pragma unroll
    for (int ct = 0; ct < 8; ++ct) acc[ct] = (f32x4)0.f;

#pragma unroll
    for (int kc = 0; kc < 4; ++kc) {
        int u = kc * 4 + ug;
        bf16x8 af = *(const bf16x8*)&As8[lrow * 16 + (u ^ (lrow & 7))];
#pragma unroll
        for (int ct = 0; ct < 8; ++ct) {
            int c = ct * 16 + (l & 15);
            bf16x8 bf = *(const bf16x8*)&Bs8[c * 16 + (u ^ (c & 7))];
            acc[ct] = __builtin_amdgcn_mfma_f32_16x16x32_bf16(af, bf, acc[ct], 0, 0, 0);
        }
    }

    float s = 0.f;
#pragma unroll
    for (int ct = 0; ct < 8; ++ct) {
        int c = ct * 16 + (l & 15);
        float qc = q[c], kbc = kb[c];
#pragma unroll
        for (int v = 0; v < 4; ++v) {
            int grow = row0 + w * 16 + (l >> 4) * 4 + v;
            if (grow < NNODES) s += qc * tanh_fast(acc[ct][v] + kbc);
        }
    }
#pragma unroll
    for (int m = 32; m >= 1; m >>= 1) s += __shfl_xor(s, m, 64);
    if (l == 0) atomicAdd(sacc, s);
}

// ============ CSR build ============
__global__ void hist_kernel(const int* __restrict__ dst, int* __restrict__ deg) {
    int e = blockIdx.x * blockDim.x + threadIdx.x;
    if (e < EEDGES) atomicAdd(&deg[dst[e]], 1);
}

__global__ __launch_bounds__(256)
void scan_partial(const int* __restrict__ deg, int* __restrict__ bsum) {
    __shared__ int red[256];
    int b = blockIdx.x, t = threadIdx.x;
    int s = 0;
    if (t < 250) {
        int base = b * SCH + t * 2;
        s = deg[base] + deg[base + 1];
    }
    red[t] = s;
    __syncthreads();
#pragma unroll
    for (int off = 128; off >= 1; off >>= 1) {
        if (t < off) red[t] += red[t + off];
        __syncthreads();
    }
    if (t == 0) bsum[b] = red[0];
}

__global__ void scan_bsum(int* __restrict__ bsum) {
    if (threadIdx.x == 0) {
        int run = 0;
        for (int i = 0; i < SB; ++i) { int v = bsum[i]; bsum[i] = run; run += v; }
    }
}

__global__ __launch_bounds__(256)
void scan_final(const int* __restrict__ deg, const int* __restrict__ bsum,
                int* __restrict__ rowptr) {
    __shared__ int ts[256];
    int b = blockIdx.x, t = threadIdx.x;
    int d0 = 0, d1 = 0;
    int base = b * SCH + t * 2;
    if (t < 250) { d0 = deg[base]; d1 = deg[base + 1]; }
    ts[t] = d0 + d1;
    __syncthreads();
#pragma unroll
    for (int off = 1; off < 256; off <<= 1) {
        int v = (t >= off) ? ts[t - off] : 0;
        __syncthreads();
        ts[t] += v;
        __syncthreads();
    }
    if (t < 250) {
        int excl = bsum[b] + (t > 0 ? ts[t - 1] : 0);
        rowptr[base] = excl;
        rowptr[base + 1] = excl + d0;
    }
    if (b == 0 && t == 0) rowptr[NNODES] = EEDGES;
}

__global__ void fill_kernel(const int* __restrict__ src, const int* __restrict__ dst,
                            int* __restrict__ cursor, int* __restrict__ csr_src) {
    int e = blockIdx.x * blockDim.x + threadIdx.x;
    if (e < EEDGES) {
        int pos = atomicAdd(&cursor[dst[e]], 1);
        csr_src[pos] = src[e];
    }
}

// ============ single-pass fused edge softmax + aggregation (bf16 H, bf16 O) ============
// shift-invariant softmax (|logit| bounded by data scale): one pass accumulates
// sum(e) and sum(e*h). Lane l holds channels 2l,2l+1 (uint = 2 bf16);
// lanes 0-31 = head 0, lanes 32-63 = head 1.
__global__ __launch_bounds__(256)
void seg_aggregate_dual(const int* __restrict__ rowptr0, const int* __restrict__ csr0,
                        const float* __restrict__ as0, const float* __restrict__ ad0,
                        unsigned short* __restrict__ O0,
                        const int* __restrict__ rowptr1, const int* __restrict__ csr1,
                        const float* __restrict__ as1, const float* __restrict__ ad1,
                        unsigned short* __restrict__ O1,
                        const unsigned short* __restrict__ Hfeat, int gseg) {
    int bid = blockIdx.x;
    int type = bid >= gseg;
    const int* rowptr = type ? rowptr1 : rowptr0;
    const int* csr_src = type ? csr1 : csr0;
    const float* asv = type ? as1 : as0;
    const float* adv = type ? ad1 : ad0;
    unsigned short* Out = type ? O1 : O0;
    int node = (bid - (type ? gseg : 0)) * 4 + (threadIdx.x >> 6);
    if (node >= NNODES) return;
    int lane = threadIdx.x & 63;
    int start = rowptr[node], end = rowptr[node + 1];
    float2 adn = *(const float2*)(adv + node * 2);

    float s0 = 0.f, s1 = 0.f;
    float accx = 0.f, accy = 0.f;
    int i = start;
    for (; i + 1 < end; i += 2) {
        int sA = csr_src[i], sB = csr_src[i + 1];
        float2 asA = *(const float2*)(asv + sA * 2);
        float2 asB = *(const float2*)(asv + sB * 2);
        unsigned int hA = *(const unsigned int*)(Hfeat + (long)sA * CDIM + lane * 2);
        unsigned int hB = *(const unsigned int*)(Hfeat + (long)sB * CDIM + lane * 2);
        float rA0 = asA.x + adn.x; rA0 = rA0 >= 0.f ? rA0 : NEG * rA0;
        float rA1 = asA.y + adn.y; rA1 = rA1 >= 0.f ? rA1 : NEG * rA1;
        float rB0 = asB.x + adn.x; rB0 = rB0 >= 0.f ? rB0 : NEG * rB0;
        float rB1 = asB.y + adn.y; rB1 = rB1 >= 0.f ? rB1 : NEG * rB1;
        float eA0 = __expf(rA0), eA1 = __expf(rA1);
        float eB0 = __expf(rB0), eB1 = __expf(rB1);
        s0 += eA0 + eB0; s1 += eA1 + eB1;
        float wA = lane < 32 ? eA0 : eA1;
        float wB = lane < 32 ? eB0 : eB1;
        accx = fmaf(bf2f((unsigned short)hA), wA, accx);
        accy = fmaf(bf2f((unsigned short)(hA >> 16)), wA, accy);
        accx = fmaf(bf2f((unsigned short)hB), wB, accx);
        accy = fmaf(bf2f((unsigned short)(hB >> 16)), wB, accy);
    }
    if (i < end) {
        int sA = csr_src[i];
        float2 asA = *(const float2*)(asv + sA * 2);
        unsigned int hA = *(const unsigned int*)(Hfeat + (long)sA * CDIM + lane * 2);
        float rA0 = asA.x + adn.x; rA0 = rA0 >= 0.f ? rA0 : NEG * rA0;
        float rA1 = asA.y + adn.y; rA1 = rA1 >= 0.f ? rA1 : NEG * rA1;
        float eA0 = __expf(rA0), eA1 = __expf(rA1);
        s0 += eA0; s1 += eA1;
        float wA = lane < 32 ? eA0 : eA1;
        accx = fmaf(bf2f((unsigned short)hA), wA, accx);
        accy = fmaf(bf2f((unsigned short)(hA >> 16)), wA, accy);
    }
    float ssel = lane < 32 ? s0 : s1;
    float inv = ssel > 0.f ? 1.f / ssel : 0.f;
    unsigned int pack = ((unsigned int)f2bf(accy * inv) << 16) | f2bf(accx * inv);
    *(unsigned int*)(Out + (long)node * CDIM + lane * 2) = pack;
}

__global__ void attn_finalize_kernel(const float* __restrict__ sacc, float* __restrict__ attn) {
    float s0 = sacc[0] / (float)NNODES;
    float s1 = sacc[1] / (float)NNODES;
    float m = fmaxf(s0, s1);
    float e0 = expf(s0 - m), e1 = expf(s1 - m);
    float inv = 1.f / (e0 + e1);
    attn[0] = e0 * inv;
    attn[1] = e1 * inv;
}

__global__ __launch_bounds__(256)
void combine_kernel(const unsigned short* __restrict__ O0,
                    const unsigned short* __restrict__ O1,
                    const float* __restrict__ attn, float* __restrict__ Hn) {
    long i = (long)blockIdx.x * blockDim.x + threadIdx.x;
    long total = (long)NNODES * CDIM / 4;
    if (i >= total) return;
    float a0 = attn[0], a1 = attn[1];
    ushort4 u0 = ((const ushort4*)O0)[i];
    ushort4 u1 = ((const ushort4*)O1)[i];
    float4 o;
    o.x = a0 * fmaxf(bf2f(u0.x), 0.f) + a1 * fmaxf(bf2f(u1.x), 0.f);
    o.y = a0 * fmaxf(bf2f(u0.y), 0.f) + a1 * fmaxf(bf2f(u1.y), 0.f);
    o.z = a0 * fmaxf(bf2f(u0.z), 0.f) + a1 * fmaxf(bf2f(u1.z), 0.f);
    o.w = a0 * fmaxf(bf2f(u0.w), 0.f) + a1 * fmaxf(bf2f(u1.w), 0.f);
    ((float4*)Hn)[i] = o;
}

__global__ __launch_bounds__(256)
void final_linear_kernel(const float* __restrict__ Hn, const float* __restrict__ lw,
                         const float* __restrict__ lb, float* __restrict__ out) {
    __shared__ float lws[CDIM * FOUT];
    int tid = threadIdx.x;
    for (int i = tid; i < CDIM * FOUT; i += 256) lws[i] = lw[i];
    __syncthreads();
    int idx = blockIdx.x * 256 + tid;
    if (idx >= NNODES * FOUT) return;
    int n = idx >> 3, o = idx & 7;
    const float4* row = (const float4*)(Hn + (long)n * CDIM);
    float acc = lb[o];
#pragma unroll
    for (int k4 = 0; k4 < 32; ++k4) {
        float4 v = row[k4];
        acc = fmaf(v.x, lws[(k4 * 4 + 0) * FOUT + o], acc);
        acc = fmaf(v.y, lws[(k4 * 4 + 1) * FOUT + o], acc);
        acc = fmaf(v.z, lws[(k4 * 4 + 2) * FOUT + o], acc);
        acc = fmaf(v.w, lws[(k4 * 4 + 3) * FOUT + o], acc);
    }
    out[idx] = acc;
}

static void run_layer(const float* X, int K,
                      const float* pw, const float* pb,
                      const float* ats, const float* atd,
                      const float* q, const float* kw, const float* kb,
                      const int* rowptr0, const int* csr0,
                      const int* rowptr1, const int* csr1,
                      unsigned short* Hb, unsigned short* O0b, unsigned short* O1b,
                      float* OutBuf,
                      float* asrc, float* adst,
                      float* sacc, float* attn, unsigned short* kwT_b,
                      hipStream_t stream) {
    const int gtile = NNODES / 32;  // 3125 exactly
    if (K == 64)
        proj_kernel3<64><<<gtile, 256, 0, stream>>>(X, pw, pb, ats, atd, Hb, asrc, adst);
    else
        proj_kernel3<128><<<gtile, 256, 0, stream>>>(X, pw, pb, ats, atd, Hb, asrc, adst);

    cvt_kwT_kernel<<<64, 256, 0, stream>>>(kw, kwT_b);

    const int nh = NNODES * HHEADS;
    const int gseg = (NNODES + 3) / 4;
    seg_aggregate_dual<<<2 * gseg, 256, 0, stream>>>(
        rowptr0, csr0, asrc, adst, O0b,
        rowptr1, csr1, asrc + nh, adst + nh, O1b, Hb, gseg);

    hipMemsetAsync(sacc, 0, 2 * sizeof(float), stream);
    const int gsc = (NNODES + 63) / 64;  // 1563
    score_mfma<<<gsc, 256, 0, stream>>>(O0b, kwT_b, kb, q, sacc + 0);
    score_mfma<<<gsc, 256, 0, stream>>>(O1b, kwT_b, kb, q, sacc + 1);
    attn_finalize_kernel<<<1, 1, 0, stream>>>(sacc, attn);
    const long q4 = (long)NNODES * CDIM / 4;
    combine_kernel<<<(int)((q4 + 255) / 256), 256, 0, stream>>>(O0b, O1b, attn, OutBuf);
}

extern "C" void kernel_launch(void* const* d_in, const int* in_sizes, int n_in,
                              void* d_out, int out_size, void* d_ws, size_t ws_size,
                              hipStream_t stream) {
    const float* x          = (const float*)d_in[0];
    const int*   ei_spatial = (const int*)d_in[1];
    const int*   ei_similar = (const int*)d_in[2];
    const float* p1_proj_w  = (const float*)d_in[3];
    const float* p1_proj_b  = (const float*)d_in[4];
    const float* p1_att_src = (const float*)d_in[5];
    const float* p1_att_dst = (const float*)d_in[6];
    const float* p1_q       = (const float*)d_in[7];
    const float* p1_kw      = (const float*)d_in[8];
    const float* p1_kb      = (const float*)d_in[9];
    const float* p2_proj_w  = (const float*)d_in[10];
    const float* p2_proj_b  = (const float*)d_in[11];
    const float* p2_att_src = (const float*)d_in[12];
    const float* p2_att_dst = (const float*)d_in[13];
    const float* p2_q       = (const float*)d_in[14];
    const float* p2_kw      = (const float*)d_in[15];
    const float* p2_kb      = (const float*)d_in[16];
    const float* lin_w      = (const float*)d_in[17];
    const float* lin_b      = (const float*)d_in[18];

    float* ws = (float*)d_ws;
    const size_t nc = (size_t)NNODES * CDIM;
    const size_t nh2 = (size_t)NNODES * HHEADS;

    float* A    = ws;                    // combined layer output (f32)
    float* asrc = A + nc;                // 2*N*H
    float* adst = asrc + 2 * nh2;        // 2*N*H
    float* sacc = adst + 2 * nh2;        // 2
    float* attn = sacc + 2;              // 2
    int* rowptr0 = (int*)(attn + 2);
    int* rowptr1 = rowptr0 + (NNODES + 1);
    int* csr0    = rowptr1 + (NNODES + 1);
    int* csr1    = csr0 + EEDGES;
    int* scratch = csr1 + EEDGES;        // deg/cursor, NNODES ints
    int* bsum    = scratch + NNODES;     // SB ints
    uintptr_t kp = (uintptr_t)(bsum + SB);
    kp = (kp + 15) & ~(uintptr_t)15;
    unsigned short* kwT_b = (unsigned short*)kp;   // 128*128 bf16
    unsigned short* Hb    = kwT_b + CDIM * CDIM;   // N*C bf16
    unsigned short* O0b   = Hb + nc;               // N*C bf16
    unsigned short* O1b   = O0b + nc;              // N*C bf16

    // ---- build CSR for both edge types (structure reused across layers) ----
    const int g_e = (EEDGES + 255) / 256;
    const int* eis[2] = {ei_spatial, ei_similar};
    int* rps[2] = {rowptr0, rowptr1};
    int* csrs[2] = {csr0, csr1};
    for (int i = 0; i < 2; ++i) {
        const int* src = eis[i];
        const int* dst = eis[i] + EEDGES;
        hipMemsetAsync(scratch, 0, NNODES * sizeof(int), stream);
        hist_kernel<<<g_e, 256, 0, stream>>>(dst, scratch);
        scan_partial<<<SB, 256, 0, stream>>>(scratch, bsum);
        scan_bsum<<<1, 64, 0, stream>>>(bsum);
        scan_final<<<SB, 256, 0, stream>>>(scratch, bsum, rps[i]);
        hipMemcpyAsync(scratch, rps[i], NNODES * sizeof(int),
                       hipMemcpyDeviceToDevice, stream);
        fill_kernel<<<g_e, 256, 0, stream>>>(src, dst, scratch, csrs[i]);
    }

    // Layer 1: proj(x)->Hb ; seg->O0b,O1b ; combine->A
    run_layer(x, FIN, p1_proj_w, p1_proj_b, p1_att_src, p1_att_dst,
              p1_q, p1_kw, p1_kb, rowptr0, csr0, rowptr1, csr1,
              Hb, O0b, O1b, A, asrc, adst, sacc, attn, kwT_b, stream);

    // Layer 2: proj(A)->Hb ; seg->O0b,O1b ; combine->A
    run_layer(A, CDIM, p2_proj_w, p2_proj_b, p2_att_src, p2_att_dst,
              p2_q, p2_kw, p2_kb, rowptr0, csr0, rowptr1, csr1,
              Hb, O0b, O1b, A, asrc, adst, sacc, attn, kwT_b, stream);

    // Final classifier
    const int gfin = (NNODES * FOUT + 255) / 256;
    final_linear_kernel<<<gfin, 256, 0, stream>>>(A, lin_w, lin_b, (float*)d_out);
}

// Round 9
// 850.896 us; speedup vs baseline: 3.5541x; 1.0244x over previous
//
#include <hip/hip_runtime.h>

#define NNODES 100000
#define EEDGES 600000
#define CDIM 128
#define HHEADS 2
#define DDIM 64
#define FIN 64
#define FOUT 8
#define NEG 0.2f

#define SB 200    // scan blocks
#define SCH 500   // nodes per scan block (200*500 = 100000 exactly)

typedef short bf16x8 __attribute__((ext_vector_type(8)));
typedef unsigned short ushort8 __attribute__((ext_vector_type(8)));
typedef float f32x4 __attribute__((ext_vector_type(4)));

__device__ __forceinline__ float tanh_fast(float x) {
    float e = __expf(2.f * x);
    return 1.f - 2.f / (e + 1.f);
}

__device__ __forceinline__ unsigned short f2bf(float x) {
    unsigned int u = __float_as_uint(x);
    unsigned int r = (u + 0x7FFFu + ((u >> 16) & 1u)) >> 16;  // RNE
    return (unsigned short)r;
}
__device__ __forceinline__ float bf2f(unsigned short u) {
    return __uint_as_float(((unsigned int)u) << 16);
}

// ---- weight -> transposed bf16 (once per layer): wT[c*K+k] = bf16(w[k*CDIM+c]) ----
template<int K>
__global__ __launch_bounds__(256)
void cvt_wT(const float* __restrict__ w, unsigned short* __restrict__ wT) {
    int idx = blockIdx.x * 256 + threadIdx.x;
    if (idx >= K * CDIM) return;
    int c = idx / K, k = idx % K;
    wT[idx] = f2bf(w[k * CDIM + c]);
}

// ============ projection via MFMA: H = bf16(X@W + b), fused attention dots ============
// 64 rows/block, 4 waves; wave w: rows w*16..+15, all 128 cols (8 16x16 tiles).
// XBF: X is bf16 (layer 2); else f32 converted during staging (layer 1).
template<int K, bool XBF>
__global__ __launch_bounds__(256)
void proj_mfma(const void* __restrict__ Xv, const unsigned short* __restrict__ pwT_b,
               const float* __restrict__ bias,
               const float* __restrict__ att_src, const float* __restrict__ att_dst,
               unsigned short* __restrict__ Hout,
               float* __restrict__ a_src, float* __restrict__ a_dst) {
    const int U = K / 8;
    __shared__ ushort8 smem[192 * (K / 8)];   // As8 [64][U] + Bs8 [128][U]
    ushort8* As8 = smem;
    ushort8* Bs8 = smem + 64 * U;
    int tid = threadIdx.x;
    int row0 = blockIdx.x * 64;

    // stage A (rows of X), swizzled
#pragma unroll
    for (int i = 0; i < (64 * U) / 256; ++i) {
        int idx = tid + i * 256;
        int row = idx / U, u = idx % U;
        int grow = row0 + row;
        ushort8 v;
        if (grow < NNODES) {
            if (XBF) {
                v = ((const ushort8*)Xv)[(long)grow * U + u];
            } else {
                const float* p = (const float*)Xv + (long)grow * K + u * 8;
                float4 a = *(const float4*)p;
                float4 b = *(const float4*)(p + 4);
                v[0] = f2bf(a.x); v[1] = f2bf(a.y); v[2] = f2bf(a.z); v[3] = f2bf(a.w);
                v[4] = f2bf(b.x); v[5] = f2bf(b.y); v[6] = f2bf(b.z); v[7] = f2bf(b.w);
            }
        } else v = (ushort8)0;
        As8[row * U + (u ^ (row & 7))] = v;
    }
    // stage B (pwT), swizzled
#pragma unroll
    for (int i = 0; i < (128 * U) / 256; ++i) {
        int idx = tid + i * 256;
        int c = idx / U, u = idx % U;
        Bs8[c * U + (u ^ (c & 7))] = ((const ushort8*)pwT_b)[idx];
    }
    __syncthreads();

    int l = tid & 63, w = tid >> 6;
    int lrow = w * 16 + (l & 15);
    int ug = l >> 4;
    f32x4 acc[8];
#pragma unroll
    for (int ct = 0; ct < 8; ++ct) acc[ct] = (f32x4)0.f;

#pragma unroll
    for (int kc = 0; kc < K / 32; ++kc) {
        int u = kc * 4 + ug;
        bf16x8 af = *(const bf16x8*)&As8[lrow * U + (u ^ (lrow & 7))];
#pragma unroll
        for (int ct = 0; ct < 8; ++ct) {
            int c = ct * 16 + (l & 15);
            bf16x8 bf = *(const bf16x8*)&Bs8[c * U + (u ^ (c & 7))];
            acc[ct] = __builtin_amdgcn_mfma_f32_16x16x32_bf16(af, bf, acc[ct], 0, 0, 0);
        }
    }

    // C (+bias) -> LDS bf16 (reuse smem; all reads of As8/Bs8 are done)
    __syncthreads();
    unsigned short* Cs = (unsigned short*)smem;  // [64][128]
#pragma unroll
    for (int ct = 0; ct < 8; ++ct) {
        int c = ct * 16 + (l & 15);
        float bc = bias[c];
#pragma unroll
        for (int v = 0; v < 4; ++v) {
            int rr = w * 16 + (l >> 4) * 4 + v;
            Cs[rr * 128 + c] = f2bf(acc[ct][v] + bc);
        }
    }
    __syncthreads();

    // coalesced H write + attention dots: thread = (row r, col quarter q)
    int r = tid >> 2, q = tid & 3;
    int grow = row0 + r;
    if (grow < NNODES) {
        float h[32];
        ushort8 hv[4];
#pragma unroll
        for (int j = 0; j < 4; ++j) {
            hv[j] = *(ushort8*)&Cs[r * 128 + q * 32 + j * 8];
#pragma unroll
            for (int e = 0; e < 8; ++e) h[j * 8 + e] = bf2f(hv[j][e]);
        }
#pragma unroll
        for (int j = 0; j < 4; ++j)
            *(ushort8*)(Hout + (long)grow * CDIM + q * 32 + j * 8) = hv[j];
#pragma unroll
        for (int i = 0; i < 2; ++i) {
            float s = 0.f, d = 0.f;
#pragma unroll
            for (int j = 0; j < 32; ++j) {
                s = fmaf(h[j], att_src[i * CDIM + q * 32 + j], s);
                d = fmaf(h[j], att_dst[i * CDIM + q * 32 + j], d);
            }
            s += __shfl_xor(s, 1, 64);
            d += __shfl_xor(d, 1, 64);
            if ((q & 1) == 0) {
                int hh = q >> 1;
                long base = (long)i * NNODES * HHEADS + (long)grow * HHEADS + hh;
                a_src[base] = s;
                a_dst[base] = d;
            }
        }
    }
}

// ---- semantic score via MFMA; Om is bf16, relu applied bitwise during staging ----
__global__ __launch_bounds__(256, 3)
void score_mfma(const unsigned short* __restrict__ Omb,
                const unsigned short* __restrict__ kwT_b,
                const float* __restrict__ kb, const float* __restrict__ q,
                float* __restrict__ sacc) {
    __shared__ ushort8 As8[64 * 16];
    __shared__ ushort8 Bs8[128 * 16];
    int tid = threadIdx.x;
    int row0 = blockIdx.x * 64;

#pragma unroll
    for (int i = 0; i < 4; ++i) {
        int idx = tid + i * 256;
        int row = idx >> 4, u = idx & 15;
        int grow = row0 + row;
        ushort8 v;
        if (grow < NNODES) {
            v = ((const ushort8*)Omb)[(long)grow * 16 + u];
#pragma unroll
            for (int e = 0; e < 8; ++e) v[e] = (v[e] & 0x8000) ? 0 : v[e];  // bf16 relu
        } else {
            v = (ushort8)0;
        }
        As8[row * 16 + (u ^ (row & 7))] = v;
    }
#pragma unroll
    for (int i = 0; i < 8; ++i) {
        int idx = tid + i * 256;
        int c = idx >> 4, u = idx & 15;
        Bs8[c * 16 + (u ^ (c & 7))] = ((const ushort8*)kwT_b)[idx];
    }
    __syncthreads();

    int l = tid & 63, w = tid >> 6;
    int lrow = w * 16 + (l & 15);
    int ug = l >> 4;
    f32x4 acc[8];
#pragma unroll
    for (int ct = 0; ct < 8; ++ct) acc[ct] = (f32x4)0.f;

#pragma unroll
    for (int kc = 0; kc < 4; ++kc) {
        int u = kc * 4 + ug;
        bf16x8 af = *(const bf16x8*)&As8[lrow * 16 + (u ^ (lrow & 7))];
#pragma unroll
        for (int ct = 0; ct < 8; ++ct) {
            int c = ct * 16 + (l & 15);
            bf16x8 bf = *(const bf16x8*)&Bs8[c * 16 + (u ^ (c & 7))];
            acc[ct] = __builtin_amdgcn_mfma_f32_16x16x32_bf16(af, bf, acc[ct], 0, 0, 0);
        }
    }

    float s = 0.f;
#pragma unroll
    for (int ct = 0; ct < 8; ++ct) {
        int c = ct * 16 + (l & 15);
        float qc = q[c], kbc = kb[c];
#pragma unroll
        for (int v = 0; v < 4; ++v) {
            int grow = row0 + w * 16 + (l >> 4) * 4 + v;
            if (grow < NNODES) s += qc * tanh_fast(acc[ct][v] + kbc);
        }
    }
#pragma unroll
    for (int m = 32; m >= 1; m >>= 1) s += __shfl_xor(s, m, 64);
    if (l == 0) atomicAdd(sacc, s);
}

// ============ CSR build ============
__global__ void hist_kernel(const int* __restrict__ dst, int* __restrict__ deg) {
    int e = blockIdx.x * blockDim.x + threadIdx.x;
    if (e < EEDGES) atomicAdd(&deg[dst[e]], 1);
}

__global__ __launch_bounds__(256)
void scan_partial(const int* __restrict__ deg, int* __restrict__ bsum) {
    __shared__ int red[256];
    int b = blockIdx.x, t = threadIdx.x;
    int s = 0;
    if (t < 250) {
        int base = b * SCH + t * 2;
        s = deg[base] + deg[base + 1];
    }
    red[t] = s;
    __syncthreads();
#pragma unroll
    for (int off = 128; off >= 1; off >>= 1) {
        if (t < off) red[t] += red[t + off];
        __syncthreads();
    }
    if (t == 0) bsum[b] = red[0];
}

__global__ void scan_bsum(int* __restrict__ bsum) {
    if (threadIdx.x == 0) {
        int run = 0;
        for (int i = 0; i < SB; ++i) { int v = bsum[i]; bsum[i] = run; run += v; }
    }
}

__global__ __launch_bounds__(256)
void scan_final(const int* __restrict__ deg, const int* __restrict__ bsum,
                int* __restrict__ rowptr) {
    __shared__ int ts[256];
    int b = blockIdx.x, t = threadIdx.x;
    int d0 = 0, d1 = 0;
    int base = b * SCH + t * 2;
    if (t < 250) { d0 = deg[base]; d1 = deg[base + 1]; }
    ts[t] = d0 + d1;
    __syncthreads();
#pragma unroll
    for (int off = 1; off < 256; off <<= 1) {
        int v = (t >= off) ? ts[t - off] : 0;
        __syncthreads();
        ts[t] += v;
        __syncthreads();
    }
    if (t < 250) {
        int excl = bsum[b] + (t > 0 ? ts[t - 1] : 0);
        rowptr[base] = excl;
        rowptr[base + 1] = excl + d0;
    }
    if (b == 0 && t == 0) rowptr[NNODES] = EEDGES;
}

__global__ void fill_kernel(const int* __restrict__ src, const int* __restrict__ dst,
                            int* __restrict__ cursor, int* __restrict__ csr_src) {
    int e = blockIdx.x * blockDim.x + threadIdx.x;
    if (e < EEDGES) {
        int pos = atomicAdd(&cursor[dst[e]], 1);
        csr_src[pos] = src[e];
    }
}

// ============ single-pass fused edge softmax + aggregation (bf16 H, bf16 O) ============
__global__ __launch_bounds__(256)
void seg_aggregate_dual(const int* __restrict__ rowptr0, const int* __restrict__ csr0,
                        const float* __restrict__ as0, const float* __restrict__ ad0,
                        unsigned short* __restrict__ O0,
                        const int* __restrict__ rowptr1, const int* __restrict__ csr1,
                        const float* __restrict__ as1, const float* __restrict__ ad1,
                        unsigned short* __restrict__ O1,
                        const unsigned short* __restrict__ Hfeat, int gseg) {
    int bid = blockIdx.x;
    int type = bid >= gseg;
    const int* rowptr = type ? rowptr1 : rowptr0;
    const int* csr_src = type ? csr1 : csr0;
    const float* asv = type ? as1 : as0;
    const float* adv = type ? ad1 : ad0;
    unsigned short* Out = type ? O1 : O0;
    int node = (bid - (type ? gseg : 0)) * 4 + (threadIdx.x >> 6);
    if (node >= NNODES) return;
    int lane = threadIdx.x & 63;
    int start = rowptr[node], end = rowptr[node + 1];
    float2 adn = *(const float2*)(adv + node * 2);

    float s0 = 0.f, s1 = 0.f;
    float accx = 0.f, accy = 0.f;
    int i = start;
    for (; i + 1 < end; i += 2) {
        int sA = csr_src[i], sB = csr_src[i + 1];
        float2 asA = *(const float2*)(asv + sA * 2);
        float2 asB = *(const float2*)(asv + sB * 2);
        unsigned int hA = *(const unsigned int*)(Hfeat + (long)sA * CDIM + lane * 2);
        unsigned int hB = *(const unsigned int*)(Hfeat + (long)sB * CDIM + lane * 2);
        float rA0 = asA.x + adn.x; rA0 = rA0 >= 0.f ? rA0 : NEG * rA0;
        float rA1 = asA.y + adn.y; rA1 = rA1 >= 0.f ? rA1 : NEG * rA1;
        float rB0 = asB.x + adn.x; rB0 = rB0 >= 0.f ? rB0 : NEG * rB0;
        float rB1 = asB.y + adn.y; rB1 = rB1 >= 0.f ? rB1 : NEG * rB1;
        float eA0 = __expf(rA0), eA1 = __expf(rA1);
        float eB0 = __expf(rB0), eB1 = __expf(rB1);
        s0 += eA0 + eB0; s1 += eA1 + eB1;
        float wA = lane < 32 ? eA0 : eA1;
        float wB = lane < 32 ? eB0 : eB1;
        accx = fmaf(bf2f((unsigned short)hA), wA, accx);
        accy = fmaf(bf2f((unsigned short)(hA >> 16)), wA, accy);
        accx = fmaf(bf2f((unsigned short)hB), wB, accx);
        accy = fmaf(bf2f((unsigned short)(hB >> 16)), wB, accy);
    }
    if (i < end) {
        int sA = csr_src[i];
        float2 asA = *(const float2*)(asv + sA * 2);
        unsigned int hA = *(const unsigned int*)(Hfeat + (long)sA * CDIM + lane * 2);
        float rA0 = asA.x + adn.x; rA0 = rA0 >= 0.f ? rA0 : NEG * rA0;
        float rA1 = asA.y + adn.y; rA1 = rA1 >= 0.f ? rA1 : NEG * rA1;
        float eA0 = __expf(rA0), eA1 = __expf(rA1);
        s0 += eA0; s1 += eA1;
        float wA = lane < 32 ? eA0 : eA1;
        accx = fmaf(bf2f((unsigned short)hA), wA, accx);
        accy = fmaf(bf2f((unsigned short)(hA >> 16)), wA, accy);
    }
    float ssel = lane < 32 ? s0 : s1;
    float inv = ssel > 0.f ? 1.f / ssel : 0.f;
    unsigned int pack = ((unsigned int)f2bf(accy * inv) << 16) | f2bf(accx * inv);
    *(unsigned int*)(Out + (long)node * CDIM + lane * 2) = pack;
}

__global__ void attn_finalize_kernel(const float* __restrict__ sacc, float* __restrict__ attn) {
    float s0 = sacc[0] / (float)NNODES;
    float s1 = sacc[1] / (float)NNODES;
    float m = fmaxf(s0, s1);
    float e0 = expf(s0 - m), e1 = expf(s1 - m);
    float inv = 1.f / (e0 + e1);
    attn[0] = e0 * inv;
    attn[1] = e1 * inv;
}

// combine -> bf16 output buffer
__global__ __launch_bounds__(256)
void combine_kernel(const unsigned short* __restrict__ O0,
                    const unsigned short* __restrict__ O1,
                    const float* __restrict__ attn, unsigned short* __restrict__ Hn) {
    long i = (long)blockIdx.x * blockDim.x + threadIdx.x;
    long total = (long)NNODES * CDIM / 4;
    if (i >= total) return;
    float a0 = attn[0], a1 = attn[1];
    ushort4 u0 = ((const ushort4*)O0)[i];
    ushort4 u1 = ((const ushort4*)O1)[i];
    ushort4 o;
    o.x = f2bf(a0 * fmaxf(bf2f(u0.x), 0.f) + a1 * fmaxf(bf2f(u1.x), 0.f));
    o.y = f2bf(a0 * fmaxf(bf2f(u0.y), 0.f) + a1 * fmaxf(bf2f(u1.y), 0.f));
    o.z = f2bf(a0 * fmaxf(bf2f(u0.z), 0.f) + a1 * fmaxf(bf2f(u1.z), 0.f));
    o.w = f2bf(a0 * fmaxf(bf2f(u0.w), 0.f) + a1 * fmaxf(bf2f(u1.w), 0.f));
    ((ushort4*)Hn)[i] = o;
}

__global__ __launch_bounds__(256)
void final_linear_kernel(const unsigned short* __restrict__ Hn, const float* __restrict__ lw,
                         const float* __restrict__ lb, float* __restrict__ out) {
    __shared__ float lws[CDIM * FOUT];
    int tid = threadIdx.x;
    for (int i = tid; i < CDIM * FOUT; i += 256) lws[i] = lw[i];
    __syncthreads();
    int idx = blockIdx.x * 256 + tid;
    if (idx >= NNODES * FOUT) return;
    int n = idx >> 3, o = idx & 7;
    const ushort8* row = (const ushort8*)(Hn + (long)n * CDIM);
    float acc = lb[o];
#pragma unroll
    for (int k8 = 0; k8 < 16; ++k8) {
        ushort8 v = row[k8];
#pragma unroll
        for (int e = 0; e < 8; ++e)
            acc = fmaf(bf2f(v[e]), lws[(k8 * 8 + e) * FOUT + o], acc);
    }
    out[idx] = acc;
}

static void run_layer(const void* X, int K,
                      const float* pw, const float* pb,
                      const float* ats, const float* atd,
                      const float* q, const float* kw, const float* kb,
                      const int* rowptr0, const int* csr0,
                      const int* rowptr1, const int* csr1,
                      unsigned short* Hb, unsigned short* O0b, unsigned short* O1b,
                      unsigned short* OutBuf,
                      float* asrc, float* adst,
                      float* sacc, float* attn,
                      unsigned short* pwT_b, unsigned short* kwT_b,
                      hipStream_t stream) {
    const int gm = (NNODES + 63) / 64;  // 1563
    if (K == 64) {
        cvt_wT<64><<<(64 * CDIM + 255) / 256, 256, 0, stream>>>(pw, pwT_b);
        proj_mfma<64, false><<<gm, 256, 0, stream>>>(X, pwT_b, pb, ats, atd,
                                                     Hb, asrc, adst);
    } else {
        cvt_wT<128><<<(128 * CDIM + 255) / 256, 256, 0, stream>>>(pw, pwT_b);
        proj_mfma<128, true><<<gm, 256, 0, stream>>>(X, pwT_b, pb, ats, atd,
                                                     Hb, asrc, adst);
    }
    cvt_wT<128><<<(128 * CDIM + 255) / 256, 256, 0, stream>>>(kw, kwT_b);

    const int nh = NNODES * HHEADS;
    const int gseg = (NNODES + 3) / 4;
    seg_aggregate_dual<<<2 * gseg, 256, 0, stream>>>(
        rowptr0, csr0, asrc, adst, O0b,
        rowptr1, csr1, asrc + nh, adst + nh, O1b, Hb, gseg);

    hipMemsetAsync(sacc, 0, 2 * sizeof(float), stream);
    score_mfma<<<gm, 256, 0, stream>>>(O0b, kwT_b, kb, q, sacc + 0);
    score_mfma<<<gm, 256, 0, stream>>>(O1b, kwT_b, kb, q, sacc + 1);
    attn_finalize_kernel<<<1, 1, 0, stream>>>(sacc, attn);
    const long q4 = (long)NNODES * CDIM / 4;
    combine_kernel<<<(int)((q4 + 255) / 256), 256, 0, stream>>>(O0b, O1b, attn, OutBuf);
}

extern "C" void kernel_launch(void* const* d_in, const int* in_sizes, int n_in,
                              void* d_out, int out_size, void* d_ws, size_t ws_size,
                              hipStream_t stream) {
    const float* x          = (const float*)d_in[0];
    const int*   ei_spatial = (const int*)d_in[1];
    const int*   ei_similar = (const int*)d_in[2];
    const float* p1_proj_w  = (const float*)d_in[3];
    const float* p1_proj_b  = (const float*)d_in[4];
    const float* p1_att_src = (const float*)d_in[5];
    const float* p1_att_dst = (const float*)d_in[6];
    const float* p1_q       = (const float*)d_in[7];
    const float* p1_kw      = (const float*)d_in[8];
    const float* p1_kb      = (const float*)d_in[9];
    const float* p2_proj_w  = (const float*)d_in[10];
    const float* p2_proj_b  = (const float*)d_in[11];
    const float* p2_att_src = (const float*)d_in[12];
    const float* p2_att_dst = (const float*)d_in[13];
    const float* p2_q       = (const float*)d_in[14];
    const float* p2_kw      = (const float*)d_in[15];
    const float* p2_kb      = (const float*)d_in[16];
    const float* lin_w      = (const float*)d_in[17];
    const float* lin_b      = (const float*)d_in[18];

    float* ws = (float*)d_ws;
    const size_t nc = (size_t)NNODES * CDIM;
    const size_t nh2 = (size_t)NNODES * HHEADS;

    float* asrc = ws;                    // 2*N*H
    float* adst = asrc + 2 * nh2;        // 2*N*H
    float* sacc = adst + 2 * nh2;        // 2
    float* attn = sacc + 2;              // 2
    int* rowptr0 = (int*)(attn + 2);
    int* rowptr1 = rowptr0 + (NNODES + 1);
    int* csr0    = rowptr1 + (NNODES + 1);
    int* csr1    = csr0 + EEDGES;
    int* scratch = csr1 + EEDGES;        // deg/cursor, NNODES ints
    int* bsum    = scratch + NNODES;     // SB ints
    uintptr_t kp = (uintptr_t)(bsum + SB);
    kp = (kp + 15) & ~(uintptr_t)15;
    unsigned short* pwT_b = (unsigned short*)kp;    // 128*128 bf16
    unsigned short* kwT_b = pwT_b + CDIM * CDIM;    // 128*128 bf16
    unsigned short* Hb    = kwT_b + CDIM * CDIM;    // N*C bf16
    unsigned short* O0b   = Hb + nc;                // N*C bf16
    unsigned short* O1b   = O0b + nc;               // N*C bf16
    unsigned short* Ab    = O1b + nc;               // N*C bf16 (combined layer out)

    // ---- build CSR for both edge types (structure reused across layers) ----
    const int g_e = (EEDGES + 255) / 256;
    const int* eis[2] = {ei_spatial, ei_similar};
    int* rps[2] = {rowptr0, rowptr1};
    int* csrs[2] = {csr0, csr1};
    for (int i = 0; i < 2; ++i) {
        const int* src = eis[i];
        const int* dst = eis[i] + EEDGES;
        hipMemsetAsync(scratch, 0, NNODES * sizeof(int), stream);
        hist_kernel<<<g_e, 256, 0, stream>>>(dst, scratch);
        scan_partial<<<SB, 256, 0, stream>>>(scratch, bsum);
        scan_bsum<<<1, 64, 0, stream>>>(bsum);
        scan_final<<<SB, 256, 0, stream>>>(scratch, bsum, rps[i]);
        hipMemcpyAsync(scratch, rps[i], NNODES * sizeof(int),
                       hipMemcpyDeviceToDevice, stream);
        fill_kernel<<<g_e, 256, 0, stream>>>(src, dst, scratch, csrs[i]);
    }

    // Layer 1: proj(x f32)->Hb ; seg->O0b,O1b ; combine->Ab (bf16)
    run_layer(x, FIN, p1_proj_w, p1_proj_b, p1_att_src, p1_att_dst,
              p1_q, p1_kw, p1_kb, rowptr0, csr0, rowptr1, csr1,
              Hb, O0b, O1b, Ab, asrc, adst, sacc, attn, pwT_b, kwT_b, stream);

    // Layer 2: proj(Ab bf16)->Hb ; seg->O0b,O1b ; combine->Ab
    run_layer(Ab, CDIM, p2_proj_w, p2_proj_b, p2_att_src, p2_att_dst,
              p2_q, p2_kw, p2_kb, rowptr0, csr0, rowptr1, csr1,
              Hb, O0b, O1b, Ab, asrc, adst, sacc, attn, pwT_b, kwT_b, stream);

    // Final classifier (bf16 input)
    const int gfin = (NNODES * FOUT + 255) / 256;
    final_linear_kernel<<<gfin, 256, 0, stream>>>(Ab, lin_w, lin_b, (float*)d_out);
}

// Round 10
// 828.915 us; speedup vs baseline: 3.6483x; 1.0265x over previous
//
#include <hip/hip_runtime.h>

#define NNODES 100000
#define EEDGES 600000
#define CDIM 128
#define HHEADS 2
#define DDIM 64
#define FIN 64
#define FOUT 8
#define NEG 0.2f

#define SB 200    // scan blocks
#define SCH 500   // nodes per scan block (200*500 = 100000 exactly)

typedef short bf16x8 __attribute__((ext_vector_type(8)));
typedef unsigned short ushort8 __attribute__((ext_vector_type(8)));
typedef float f32x4 __attribute__((ext_vector_type(4)));

__device__ __forceinline__ float tanh_fast(float x) {
    float e = __expf(2.f * x);
    return 1.f - 2.f / (e + 1.f);
}

__device__ __forceinline__ unsigned short f2bf(float x) {
    unsigned int u = __float_as_uint(x);
    unsigned int r = (u + 0x7FFFu + ((u >> 16) & 1u)) >> 16;  // RNE
    return (unsigned short)r;
}
__device__ __forceinline__ float bf2f(unsigned short u) {
    return __uint_as_float(((unsigned int)u) << 16);
}

// ---- weight -> transposed bf16 (once per layer): wT[c*K+k] = bf16(w[k*CDIM+c]) ----
template<int K>
__global__ __launch_bounds__(256)
void cvt_wT(const float* __restrict__ w, unsigned short* __restrict__ wT) {
    int idx = blockIdx.x * 256 + threadIdx.x;
    if (idx >= K * CDIM) return;
    int c = idx / K, k = idx % K;
    wT[idx] = f2bf(w[k * CDIM + c]);
}

// ============ projection via MFMA: H = bf16(X@W + b), fused attention dots ============
template<int K, bool XBF>
__global__ __launch_bounds__(256)
void proj_mfma(const void* __restrict__ Xv, const unsigned short* __restrict__ pwT_b,
               const float* __restrict__ bias,
               const float* __restrict__ att_src, const float* __restrict__ att_dst,
               unsigned short* __restrict__ Hout,
               float* __restrict__ a_src, float* __restrict__ a_dst) {
    const int U = K / 8;
    __shared__ ushort8 smem[192 * (K / 8)];   // As8 [64][U] + Bs8 [128][U]
    ushort8* As8 = smem;
    ushort8* Bs8 = smem + 64 * U;
    int tid = threadIdx.x;
    int row0 = blockIdx.x * 64;

#pragma unroll
    for (int i = 0; i < (64 * U) / 256; ++i) {
        int idx = tid + i * 256;
        int row = idx / U, u = idx % U;
        int grow = row0 + row;
        ushort8 v;
        if (grow < NNODES) {
            if (XBF) {
                v = ((const ushort8*)Xv)[(long)grow * U + u];
            } else {
                const float* p = (const float*)Xv + (long)grow * K + u * 8;
                float4 a = *(const float4*)p;
                float4 b = *(const float4*)(p + 4);
                v[0] = f2bf(a.x); v[1] = f2bf(a.y); v[2] = f2bf(a.z); v[3] = f2bf(a.w);
                v[4] = f2bf(b.x); v[5] = f2bf(b.y); v[6] = f2bf(b.z); v[7] = f2bf(b.w);
            }
        } else v = (ushort8)0;
        As8[row * U + (u ^ (row & 7))] = v;
    }
#pragma unroll
    for (int i = 0; i < (128 * U) / 256; ++i) {
        int idx = tid + i * 256;
        int c = idx / U, u = idx % U;
        Bs8[c * U + (u ^ (c & 7))] = ((const ushort8*)pwT_b)[idx];
    }
    __syncthreads();

    int l = tid & 63, w = tid >> 6;
    int lrow = w * 16 + (l & 15);
    int ug = l >> 4;
    f32x4 acc[8];
#pragma unroll
    for (int ct = 0; ct < 8; ++ct) acc[ct] = (f32x4)0.f;

#pragma unroll
    for (int kc = 0; kc < K / 32; ++kc) {
        int u = kc * 4 + ug;
        bf16x8 af = *(const bf16x8*)&As8[lrow * U + (u ^ (lrow & 7))];
#pragma unroll
        for (int ct = 0; ct < 8; ++ct) {
            int c = ct * 16 + (l & 15);
            bf16x8 bf = *(const bf16x8*)&Bs8[c * U + (u ^ (c & 7))];
            acc[ct] = __builtin_amdgcn_mfma_f32_16x16x32_bf16(af, bf, acc[ct], 0, 0, 0);
        }
    }

    __syncthreads();
    unsigned short* Cs = (unsigned short*)smem;  // [64][128]
#pragma unroll
    for (int ct = 0; ct < 8; ++ct) {
        int c = ct * 16 + (l & 15);
        float bc = bias[c];
#pragma unroll
        for (int v = 0; v < 4; ++v) {
            int rr = w * 16 + (l >> 4) * 4 + v;
            Cs[rr * 128 + c] = f2bf(acc[ct][v] + bc);
        }
    }
    __syncthreads();

    int r = tid >> 2, q = tid & 3;
    int grow = row0 + r;
    if (grow < NNODES) {
        float h[32];
        ushort8 hv[4];
#pragma unroll
        for (int j = 0; j < 4; ++j) {
            hv[j] = *(ushort8*)&Cs[r * 128 + q * 32 + j * 8];
#pragma unroll
            for (int e = 0; e < 8; ++e) h[j * 8 + e] = bf2f(hv[j][e]);
        }
#pragma unroll
        for (int j = 0; j < 4; ++j)
            *(ushort8*)(Hout + (long)grow * CDIM + q * 32 + j * 8) = hv[j];
#pragma unroll
        for (int i = 0; i < 2; ++i) {
            float s = 0.f, d = 0.f;
#pragma unroll
            for (int j = 0; j < 32; ++j) {
                s = fmaf(h[j], att_src[i * CDIM + q * 32 + j], s);
                d = fmaf(h[j], att_dst[i * CDIM + q * 32 + j], d);
            }
            s += __shfl_xor(s, 1, 64);
            d += __shfl_xor(d, 1, 64);
            if ((q & 1) == 0) {
                int hh = q >> 1;
                long base = (long)i * NNODES * HHEADS + (long)grow * HHEADS + hh;
                a_src[base] = s;
                a_dst[base] = d;
            }
        }
    }
}

// ---- semantic score via MFMA, BOTH edge types in one launch ----
__global__ __launch_bounds__(256, 3)
void score_mfma_dual(const unsigned short* __restrict__ O0b,
                     const unsigned short* __restrict__ O1b,
                     const unsigned short* __restrict__ kwT_b,
                     const float* __restrict__ kb, const float* __restrict__ q,
                     float* __restrict__ sacc, int gm) {
    __shared__ ushort8 As8[64 * 16];
    __shared__ ushort8 Bs8[128 * 16];
    int bid = blockIdx.x;
    int type = bid >= gm;
    const unsigned short* Omb = type ? O1b : O0b;
    int tid = threadIdx.x;
    int row0 = (bid - (type ? gm : 0)) * 64;

#pragma unroll
    for (int i = 0; i < 4; ++i) {
        int idx = tid + i * 256;
        int row = idx >> 4, u = idx & 15;
        int grow = row0 + row;
        ushort8 v;
        if (grow < NNODES) {
            v = ((const ushort8*)Omb)[(long)grow * 16 + u];
#pragma unroll
            for (int e = 0; e < 8; ++e) v[e] = (v[e] & 0x8000) ? 0 : v[e];  // bf16 relu
        } else {
            v = (ushort8)0;
        }
        As8[row * 16 + (u ^ (row & 7))] = v;
    }
#pragma unroll
    for (int i = 0; i < 8; ++i) {
        int idx = tid + i * 256;
        int c = idx >> 4, u = idx & 15;
        Bs8[c * 16 + (u ^ (c & 7))] = ((const ushort8*)kwT_b)[idx];
    }
    __syncthreads();

    int l = tid & 63, w = tid >> 6;
    int lrow = w * 16 + (l & 15);
    int ug = l >> 4;
    f32x4 acc[8];
#pragma unroll
    for (int ct = 0; ct < 8; ++ct) acc[ct] = (f32x4)0.f;

#pragma unroll
    for (int kc = 0; kc < 4; ++kc) {
        int u = kc * 4 + ug;
        bf16x8 af = *(const bf16x8*)&As8[lrow * 16 + (u ^ (lrow & 7))];
#pragma unroll
        for (int ct = 0; ct < 8; ++ct) {
            int c = ct * 16 + (l & 15);
            bf16x8 bf = *(const bf16x8*)&Bs8[c * 16 + (u ^ (c & 7))];
            acc[ct] = __builtin_amdgcn_mfma_f32_16x16x32_bf16(af, bf, acc[ct], 0, 0, 0);
        }
    }

    float s = 0.f;
#pragma unroll
    for (int ct = 0; ct < 8; ++ct) {
        int c = ct * 16 + (l & 15);
        float qc = q[c], kbc = kb[c];
#pragma unroll
        for (int v = 0; v < 4; ++v) {
            int grow = row0 + w * 16 + (l >> 4) * 4 + v;
            if (grow < NNODES) s += qc * tanh_fast(acc[ct][v] + kbc);
        }
    }
#pragma unroll
    for (int m = 32; m >= 1; m >>= 1) s += __shfl_xor(s, m, 64);
    if (l == 0) atomicAdd(sacc + type, s);
}

// ============ CSR build (dual-type fused) ============
__global__ void hist_dual(const int* __restrict__ dst0, int* __restrict__ deg0,
                          const int* __restrict__ dst1, int* __restrict__ deg1, int gE) {
    int bid = blockIdx.x;
    int type = bid >= gE;
    const int* dst = type ? dst1 : dst0;
    int* deg = type ? deg1 : deg0;
    int e = (bid - (type ? gE : 0)) * 256 + threadIdx.x;
    if (e < EEDGES) atomicAdd(&deg[dst[e]], 1);
}

__global__ __launch_bounds__(256)
void scan_partial_dual(const int* __restrict__ deg0, int* __restrict__ bsum0,
                       const int* __restrict__ deg1, int* __restrict__ bsum1) {
    __shared__ int red[256];
    int bid = blockIdx.x;
    int type = bid >= SB;
    const int* deg = type ? deg1 : deg0;
    int* bsum = type ? bsum1 : bsum0;
    int b = bid - (type ? SB : 0), t = threadIdx.x;
    int s = 0;
    if (t < 250) {
        int base = b * SCH + t * 2;
        s = deg[base] + deg[base + 1];
    }
    red[t] = s;
    __syncthreads();
#pragma unroll
    for (int off = 128; off >= 1; off >>= 1) {
        if (t < off) red[t] += red[t + off];
        __syncthreads();
    }
    if (t == 0) bsum[b] = red[0];
}

__global__ void scan_bsum_dual(int* __restrict__ bsum0, int* __restrict__ bsum1) {
    int t = threadIdx.x;
    if (t < 2) {
        int* bsum = t ? bsum1 : bsum0;
        int run = 0;
        for (int i = 0; i < SB; ++i) { int v = bsum[i]; bsum[i] = run; run += v; }
    }
}

__global__ __launch_bounds__(256)
void scan_final_dual(const int* __restrict__ deg0, const int* __restrict__ bsum0,
                     int* __restrict__ rowptr0,
                     const int* __restrict__ deg1, const int* __restrict__ bsum1,
                     int* __restrict__ rowptr1) {
    __shared__ int ts[256];
    int bid = blockIdx.x;
    int type = bid >= SB;
    const int* deg = type ? deg1 : deg0;
    const int* bsum = type ? bsum1 : bsum0;
    int* rowptr = type ? rowptr1 : rowptr0;
    int b = bid - (type ? SB : 0), t = threadIdx.x;
    int d0 = 0, d1 = 0;
    int base = b * SCH + t * 2;
    if (t < 250) { d0 = deg[base]; d1 = deg[base + 1]; }
    ts[t] = d0 + d1;
    __syncthreads();
#pragma unroll
    for (int off = 1; off < 256; off <<= 1) {
        int v = (t >= off) ? ts[t - off] : 0;
        __syncthreads();
        ts[t] += v;
        __syncthreads();
    }
    if (t < 250) {
        int excl = bsum[b] + (t > 0 ? ts[t - 1] : 0);
        rowptr[base] = excl;
        rowptr[base + 1] = excl + d0;
    }
    if (b == 0 && t == 0) rowptr[NNODES] = EEDGES;
}

__global__ void fill_dual(const int* __restrict__ src0, const int* __restrict__ dst0,
                          int* __restrict__ cur0, int* __restrict__ cs0, int* __restrict__ cd0,
                          const int* __restrict__ src1, const int* __restrict__ dst1,
                          int* __restrict__ cur1, int* __restrict__ cs1, int* __restrict__ cd1,
                          int gE) {
    int bid = blockIdx.x;
    int type = bid >= gE;
    const int* src = type ? src1 : src0;
    const int* dst = type ? dst1 : dst0;
    int* cursor = type ? cur1 : cur0;
    int* csr_src = type ? cs1 : cs0;
    int* csr_dst = type ? cd1 : cd0;
    int e = (bid - (type ? gE : 0)) * 256 + threadIdx.x;
    if (e < EEDGES) {
        int d = dst[e];
        int pos = atomicAdd(&cursor[d], 1);
        csr_src[pos] = src[e];
        csr_dst[pos] = d;
    }
}

// ---- per-edge softmax weights (unnormalized): w[j] = exp(leaky(as[s]+ad[d])) ----
__global__ __launch_bounds__(256)
void edge_w_dual(const int* __restrict__ cs0, const int* __restrict__ cd0,
                 const float* __restrict__ as0, const float* __restrict__ ad0,
                 float2* __restrict__ w0,
                 const int* __restrict__ cs1, const int* __restrict__ cd1,
                 const float* __restrict__ as1, const float* __restrict__ ad1,
                 float2* __restrict__ w1, int gE) {
    int bid = blockIdx.x;
    int type = bid >= gE;
    const int* cs = type ? cs1 : cs0;
    const int* cd = type ? cd1 : cd0;
    const float* as = type ? as1 : as0;
    const float* ad = type ? ad1 : ad0;
    float2* w = type ? w1 : w0;
    int j = (bid - (type ? gE : 0)) * 256 + threadIdx.x;
    if (j >= EEDGES) return;
    int s = cs[j], d = cd[j];
    float2 a = *(const float2*)(as + s * 2);
    float2 b = *(const float2*)(ad + d * 2);
    float r0 = a.x + b.x; r0 = r0 >= 0.f ? r0 : NEG * r0;
    float r1 = a.y + b.y; r1 = r1 >= 0.f ? r1 : NEG * r1;
    w[j] = make_float2(__expf(r0), __expf(r1));
}

// ============ single-pass aggregation with precomputed edge weights ============
// lane l holds channels 2l,2l+1 (uint = 2 bf16); lanes 0-31 head 0, 32-63 head 1.
__global__ __launch_bounds__(256)
void seg_aggregate_dual(const int* __restrict__ rowptr0, const int* __restrict__ csr0,
                        const float2* __restrict__ w0, unsigned short* __restrict__ O0,
                        const int* __restrict__ rowptr1, const int* __restrict__ csr1,
                        const float2* __restrict__ w1, unsigned short* __restrict__ O1,
                        const unsigned short* __restrict__ Hfeat, int gseg) {
    int bid = blockIdx.x;
    int type = bid >= gseg;
    const int* rowptr = type ? rowptr1 : rowptr0;
    const int* csr_src = type ? csr1 : csr0;
    const float2* wv = type ? w1 : w0;
    unsigned short* Out = type ? O1 : O0;
    int node = (bid - (type ? gseg : 0)) * 4 + (threadIdx.x >> 6);
    if (node >= NNODES) return;
    int lane = threadIdx.x & 63;
    int start = rowptr[node], end = rowptr[node + 1];

    float s0 = 0.f, s1 = 0.f;
    float accx = 0.f, accy = 0.f;
    int i = start;
    for (; i + 1 < end; i += 2) {
        int sA = csr_src[i], sB = csr_src[i + 1];
        float2 wA2 = wv[i], wB2 = wv[i + 1];
        unsigned int hA = *(const unsigned int*)(Hfeat + (long)sA * CDIM + lane * 2);
        unsigned int hB = *(const unsigned int*)(Hfeat + (long)sB * CDIM + lane * 2);
        s0 += wA2.x + wB2.x;
        s1 += wA2.y + wB2.y;
        float wA = lane < 32 ? wA2.x : wA2.y;
        float wB = lane < 32 ? wB2.x : wB2.y;
        accx = fmaf(bf2f((unsigned short)hA), wA, accx);
        accy = fmaf(bf2f((unsigned short)(hA >> 16)), wA, accy);
        accx = fmaf(bf2f((unsigned short)hB), wB, accx);
        accy = fmaf(bf2f((unsigned short)(hB >> 16)), wB, accy);
    }
    if (i < end) {
        int sA = csr_src[i];
        float2 wA2 = wv[i];
        unsigned int hA = *(const unsigned int*)(Hfeat + (long)sA * CDIM + lane * 2);
        s0 += wA2.x; s1 += wA2.y;
        float wA = lane < 32 ? wA2.x : wA2.y;
        accx = fmaf(bf2f((unsigned short)hA), wA, accx);
        accy = fmaf(bf2f((unsigned short)(hA >> 16)), wA, accy);
    }
    float ssel = lane < 32 ? s0 : s1;
    float inv = ssel > 0.f ? 1.f / ssel : 0.f;
    unsigned int pack = ((unsigned int)f2bf(accy * inv) << 16) | f2bf(accx * inv);
    *(unsigned int*)(Out + (long)node * CDIM + lane * 2) = pack;
}

__global__ void attn_finalize_kernel(const float* __restrict__ sacc, float* __restrict__ attn) {
    float s0 = sacc[0] / (float)NNODES;
    float s1 = sacc[1] / (float)NNODES;
    float m = fmaxf(s0, s1);
    float e0 = expf(s0 - m), e1 = expf(s1 - m);
    float inv = 1.f / (e0 + e1);
    attn[0] = e0 * inv;
    attn[1] = e1 * inv;
}

__global__ __launch_bounds__(256)
void combine_kernel(const unsigned short* __restrict__ O0,
                    const unsigned short* __restrict__ O1,
                    const float* __restrict__ attn, unsigned short* __restrict__ Hn) {
    long i = (long)blockIdx.x * blockDim.x + threadIdx.x;
    long total = (long)NNODES * CDIM / 4;
    if (i >= total) return;
    float a0 = attn[0], a1 = attn[1];
    ushort4 u0 = ((const ushort4*)O0)[i];
    ushort4 u1 = ((const ushort4*)O1)[i];
    ushort4 o;
    o.x = f2bf(a0 * fmaxf(bf2f(u0.x), 0.f) + a1 * fmaxf(bf2f(u1.x), 0.f));
    o.y = f2bf(a0 * fmaxf(bf2f(u0.y), 0.f) + a1 * fmaxf(bf2f(u1.y), 0.f));
    o.z = f2bf(a0 * fmaxf(bf2f(u0.z), 0.f) + a1 * fmaxf(bf2f(u1.z), 0.f));
    o.w = f2bf(a0 * fmaxf(bf2f(u0.w), 0.f) + a1 * fmaxf(bf2f(u1.w), 0.f));
    ((ushort4*)Hn)[i] = o;
}

__global__ __launch_bounds__(256)
void final_linear_kernel(const unsigned short* __restrict__ Hn, const float* __restrict__ lw,
                         const float* __restrict__ lb, float* __restrict__ out) {
    __shared__ float lws[CDIM * FOUT];
    int tid = threadIdx.x;
    for (int i = tid; i < CDIM * FOUT; i += 256) lws[i] = lw[i];
    __syncthreads();
    int idx = blockIdx.x * 256 + tid;
    if (idx >= NNODES * FOUT) return;
    int n = idx >> 3, o = idx & 7;
    const ushort8* row = (const ushort8*)(Hn + (long)n * CDIM);
    float acc = lb[o];
#pragma unroll
    for (int k8 = 0; k8 < 16; ++k8) {
        ushort8 v = row[k8];
#pragma unroll
        for (int e = 0; e < 8; ++e)
            acc = fmaf(bf2f(v[e]), lws[(k8 * 8 + e) * FOUT + o], acc);
    }
    out[idx] = acc;
}

struct Graph {
    const int *rp0, *cs0, *cd0, *rp1, *cs1, *cd1;
    float2 *w0, *w1;
};

static void run_layer(const void* X, int K,
                      const float* pw, const float* pb,
                      const float* ats, const float* atd,
                      const float* q, const float* kw, const float* kb,
                      const Graph& g,
                      unsigned short* Hb, unsigned short* O0b, unsigned short* O1b,
                      unsigned short* OutBuf,
                      float* asrc, float* adst,
                      float* sacc, float* attn,
                      unsigned short* pwT_b, unsigned short* kwT_b,
                      hipStream_t stream) {
    const int gm = (NNODES + 63) / 64;  // 1563
    const int gE = (EEDGES + 255) / 256;
    if (K == 64) {
        cvt_wT<64><<<(64 * CDIM + 255) / 256, 256, 0, stream>>>(pw, pwT_b);
        proj_mfma<64, false><<<gm, 256, 0, stream>>>(X, pwT_b, pb, ats, atd,
                                                     Hb, asrc, adst);
    } else {
        cvt_wT<128><<<(128 * CDIM + 255) / 256, 256, 0, stream>>>(pw, pwT_b);
        proj_mfma<128, true><<<gm, 256, 0, stream>>>(X, pwT_b, pb, ats, atd,
                                                     Hb, asrc, adst);
    }
    cvt_wT<128><<<(128 * CDIM + 255) / 256, 256, 0, stream>>>(kw, kwT_b);

    const int nh = NNODES * HHEADS;
    edge_w_dual<<<2 * gE, 256, 0, stream>>>(
        g.cs0, g.cd0, asrc, adst, g.w0,
        g.cs1, g.cd1, asrc + nh, adst + nh, g.w1, gE);

    const int gseg = (NNODES + 3) / 4;
    seg_aggregate_dual<<<2 * gseg, 256, 0, stream>>>(
        g.rp0, g.cs0, g.w0, O0b,
        g.rp1, g.cs1, g.w1, O1b, Hb, gseg);

    hipMemsetAsync(sacc, 0, 2 * sizeof(float), stream);
    score_mfma_dual<<<2 * gm, 256, 0, stream>>>(O0b, O1b, kwT_b, kb, q, sacc, gm);
    attn_finalize_kernel<<<1, 1, 0, stream>>>(sacc, attn);
    const long q4 = (long)NNODES * CDIM / 4;
    combine_kernel<<<(int)((q4 + 255) / 256), 256, 0, stream>>>(O0b, O1b, attn, OutBuf);
}

extern "C" void kernel_launch(void* const* d_in, const int* in_sizes, int n_in,
                              void* d_out, int out_size, void* d_ws, size_t ws_size,
                              hipStream_t stream) {
    const float* x          = (const float*)d_in[0];
    const int*   ei_spatial = (const int*)d_in[1];
    const int*   ei_similar = (const int*)d_in[2];
    const float* p1_proj_w  = (const float*)d_in[3];
    const float* p1_proj_b  = (const float*)d_in[4];
    const float* p1_att_src = (const float*)d_in[5];
    const float* p1_att_dst = (const float*)d_in[6];
    const float* p1_q       = (const float*)d_in[7];
    const float* p1_kw      = (const float*)d_in[8];
    const float* p1_kb      = (const float*)d_in[9];
    const float* p2_proj_w  = (const float*)d_in[10];
    const float* p2_proj_b  = (const float*)d_in[11];
    const float* p2_att_src = (const float*)d_in[12];
    const float* p2_att_dst = (const float*)d_in[13];
    const float* p2_q       = (const float*)d_in[14];
    const float* p2_kw      = (const float*)d_in[15];
    const float* p2_kb      = (const float*)d_in[16];
    const float* lin_w      = (const float*)d_in[17];
    const float* lin_b      = (const float*)d_in[18];

    float* ws = (float*)d_ws;
    const size_t nc = (size_t)NNODES * CDIM;
    const size_t nh2 = (size_t)NNODES * HHEADS;

    float* asrc = ws;                    // 2*N*H
    float* adst = asrc + 2 * nh2;        // 2*N*H
    float* sacc = adst + 2 * nh2;        // 2
    float* attn = sacc + 2;              // 2
    int* rowptr0 = (int*)(attn + 2);     // N+1
    int* rowptr1 = rowptr0 + (NNODES + 1);
    int* cursor0 = rowptr1 + (NNODES + 1);  // N+1 (contiguous with cursor1)
    int* cursor1 = cursor0 + (NNODES + 1);
    int* cs0     = cursor1 + (NNODES + 1);  // E
    int* cd0     = cs0 + EEDGES;            // E
    int* cs1     = cd0 + EEDGES;            // E
    int* cd1     = cs1 + EEDGES;            // E
    int* deg0    = cd1 + EEDGES;            // N (deg0/deg1 contiguous for one memset)
    int* deg1    = deg0 + NNODES;           // N
    int* bsum0   = deg1 + NNODES;           // SB
    int* bsum1   = bsum0 + SB;              // SB
    uintptr_t kp = (uintptr_t)(bsum1 + SB);
    kp = (kp + 15) & ~(uintptr_t)15;
    float2* w0 = (float2*)kp;                       // E float2
    float2* w1 = w0 + EEDGES;                       // E float2
    unsigned short* pwT_b = (unsigned short*)(w1 + EEDGES);  // 128*128 bf16
    unsigned short* kwT_b = pwT_b + CDIM * CDIM;
    unsigned short* Hb    = kwT_b + CDIM * CDIM;    // N*C bf16
    unsigned short* O0b   = Hb + nc;
    unsigned short* O1b   = O0b + nc;
    unsigned short* Ab    = O1b + nc;

    // ---- build CSR for both edge types (structure reused across layers) ----
    const int gE = (EEDGES + 255) / 256;
    hipMemsetAsync(deg0, 0, 2 * NNODES * sizeof(int), stream);
    hist_dual<<<2 * gE, 256, 0, stream>>>(ei_spatial + EEDGES, deg0,
                                          ei_similar + EEDGES, deg1, gE);
    scan_partial_dual<<<2 * SB, 256, 0, stream>>>(deg0, bsum0, deg1, bsum1);
    scan_bsum_dual<<<1, 64, 0, stream>>>(bsum0, bsum1);
    scan_final_dual<<<2 * SB, 256, 0, stream>>>(deg0, bsum0, rowptr0, deg1, bsum1, rowptr1);
    hipMemcpyAsync(cursor0, rowptr0, 2 * (NNODES + 1) * sizeof(int),
                   hipMemcpyDeviceToDevice, stream);
    fill_dual<<<2 * gE, 256, 0, stream>>>(ei_spatial, ei_spatial + EEDGES, cursor0, cs0, cd0,
                                          ei_similar, ei_similar + EEDGES, cursor1, cs1, cd1, gE);

    Graph g = {rowptr0, cs0, cd0, rowptr1, cs1, cd1, w0, w1};

    // Layer 1: proj(x f32)->Hb ; edge_w ; seg->O0b,O1b ; combine->Ab (bf16)
    run_layer(x, FIN, p1_proj_w, p1_proj_b, p1_att_src, p1_att_dst,
              p1_q, p1_kw, p1_kb, g,
              Hb, O0b, O1b, Ab, asrc, adst, sacc, attn, pwT_b, kwT_b, stream);

    // Layer 2: proj(Ab bf16)->Hb ; edge_w ; seg->O0b,O1b ; combine->Ab
    run_layer(Ab, CDIM, p2_proj_w, p2_proj_b, p2_att_src, p2_att_dst,
              p2_q, p2_kw, p2_kb, g,
              Hb, O0b, O1b, Ab, asrc, adst, sacc, attn, pwT_b, kwT_b, stream);

    // Final classifier (bf16 input)
    const int gfin = (NNODES * FOUT + 255) / 256;
    final_linear_kernel<<<gfin, 256, 0, stream>>>(Ab, lin_w, lin_b, (float*)d_out);
}

// Round 11
// 545.850 us; speedup vs baseline: 5.5402x; 1.5186x over previous
//
#include <hip/hip_runtime.h>

#define NNODES 100000
#define EEDGES 600000
#define CDIM 128
#define HHEADS 2
#define DDIM 64
#define FIN 64
#define FOUT 8
#define NEG 0.2f

#define SB 200    // scan blocks
#define SCH 500   // nodes per scan block (200*500 = 100000 exactly)
#define SNB 384   // persistent score blocks per edge type

typedef short bf16x8 __attribute__((ext_vector_type(8)));
typedef unsigned short ushort8 __attribute__((ext_vector_type(8)));
typedef float f32x4 __attribute__((ext_vector_type(4)));

__device__ __forceinline__ float tanh_fast(float x) {
    float e = __expf(2.f * x);
    return 1.f - 2.f / (e + 1.f);
}

__device__ __forceinline__ unsigned short f2bf(float x) {
    unsigned int u = __float_as_uint(x);
    unsigned int r = (u + 0x7FFFu + ((u >> 16) & 1u)) >> 16;  // RNE
    return (unsigned short)r;
}
__device__ __forceinline__ float bf2f(unsigned short u) {
    return __uint_as_float(((unsigned int)u) << 16);
}

// ---- weight -> transposed bf16 (once per layer): wT[c*K+k] = bf16(w[k*CDIM+c]) ----
template<int K>
__global__ __launch_bounds__(256)
void cvt_wT(const float* __restrict__ w, unsigned short* __restrict__ wT) {
    int idx = blockIdx.x * 256 + threadIdx.x;
    if (idx >= K * CDIM) return;
    int c = idx / K, k = idx % K;
    wT[idx] = f2bf(w[k * CDIM + c]);
}

// ============ projection via MFMA: H = bf16(X@W + b), fused attention dots ============
template<int K, bool XBF>
__global__ __launch_bounds__(256)
void proj_mfma(const void* __restrict__ Xv, const unsigned short* __restrict__ pwT_b,
               const float* __restrict__ bias,
               const float* __restrict__ att_src, const float* __restrict__ att_dst,
               unsigned short* __restrict__ Hout,
               float* __restrict__ a_src, float* __restrict__ a_dst) {
    const int U = K / 8;
    __shared__ ushort8 smem[192 * (K / 8)];   // As8 [64][U] + Bs8 [128][U]
    ushort8* As8 = smem;
    ushort8* Bs8 = smem + 64 * U;
    int tid = threadIdx.x;
    int row0 = blockIdx.x * 64;

#pragma unroll
    for (int i = 0; i < (64 * U) / 256; ++i) {
        int idx = tid + i * 256;
        int row = idx / U, u = idx % U;
        int grow = row0 + row;
        ushort8 v;
        if (grow < NNODES) {
            if (XBF) {
                v = ((const ushort8*)Xv)[(long)grow * U + u];
            } else {
                const float* p = (const float*)Xv + (long)grow * K + u * 8;
                float4 a = *(const float4*)p;
                float4 b = *(const float4*)(p + 4);
                v[0] = f2bf(a.x); v[1] = f2bf(a.y); v[2] = f2bf(a.z); v[3] = f2bf(a.w);
                v[4] = f2bf(b.x); v[5] = f2bf(b.y); v[6] = f2bf(b.z); v[7] = f2bf(b.w);
            }
        } else v = (ushort8)0;
        As8[row * U + (u ^ (row & 7))] = v;
    }
#pragma unroll
    for (int i = 0; i < (128 * U) / 256; ++i) {
        int idx = tid + i * 256;
        int c = idx / U, u = idx % U;
        Bs8[c * U + (u ^ (c & 7))] = ((const ushort8*)pwT_b)[idx];
    }
    __syncthreads();

    int l = tid & 63, w = tid >> 6;
    int lrow = w * 16 + (l & 15);
    int ug = l >> 4;
    f32x4 acc[8];
#pragma unroll
    for (int ct = 0; ct < 8; ++ct) acc[ct] = (f32x4)0.f;

#pragma unroll
    for (int kc = 0; kc < K / 32; ++kc) {
        int u = kc * 4 + ug;
        bf16x8 af = *(const bf16x8*)&As8[lrow * U + (u ^ (lrow & 7))];
#pragma unroll
        for (int ct = 0; ct < 8; ++ct) {
            int c = ct * 16 + (l & 15);
            bf16x8 bf = *(const bf16x8*)&Bs8[c * U + (u ^ (c & 7))];
            acc[ct] = __builtin_amdgcn_mfma_f32_16x16x32_bf16(af, bf, acc[ct], 0, 0, 0);
        }
    }

    __syncthreads();
    unsigned short* Cs = (unsigned short*)smem;  // [64][128]
#pragma unroll
    for (int ct = 0; ct < 8; ++ct) {
        int c = ct * 16 + (l & 15);
        float bc = bias[c];
#pragma unroll
        for (int v = 0; v < 4; ++v) {
            int rr = w * 16 + (l >> 4) * 4 + v;
            Cs[rr * 128 + c] = f2bf(acc[ct][v] + bc);
        }
    }
    __syncthreads();

    int r = tid >> 2, q = tid & 3;
    int grow = row0 + r;
    if (grow < NNODES) {
        float h[32];
        ushort8 hv[4];
#pragma unroll
        for (int j = 0; j < 4; ++j) {
            hv[j] = *(ushort8*)&Cs[r * 128 + q * 32 + j * 8];
#pragma unroll
            for (int e = 0; e < 8; ++e) h[j * 8 + e] = bf2f(hv[j][e]);
        }
#pragma unroll
        for (int j = 0; j < 4; ++j)
            *(ushort8*)(Hout + (long)grow * CDIM + q * 32 + j * 8) = hv[j];
#pragma unroll
        for (int i = 0; i < 2; ++i) {
            float s = 0.f, d = 0.f;
#pragma unroll
            for (int j = 0; j < 32; ++j) {
                s = fmaf(h[j], att_src[i * CDIM + q * 32 + j], s);
                d = fmaf(h[j], att_dst[i * CDIM + q * 32 + j], d);
            }
            s += __shfl_xor(s, 1, 64);
            d += __shfl_xor(d, 1, 64);
            if ((q & 1) == 0) {
                int hh = q >> 1;
                long base = (long)i * NNODES * HHEADS + (long)grow * HHEADS + hh;
                a_src[base] = s;
                a_dst[base] = d;
            }
        }
    }
}

// ---- semantic score via MFMA: persistent blocks, kw staged ONCE, grid-stride over ----
// row tiles with register prefetch of next tile's Om (hides HBM under MFMA).
__global__ __launch_bounds__(256, 3)
void score_mfma_dual(const unsigned short* __restrict__ O0b,
                     const unsigned short* __restrict__ O1b,
                     const unsigned short* __restrict__ kwT_b,
                     const float* __restrict__ kb, const float* __restrict__ q,
                     float* __restrict__ sacc) {
    __shared__ ushort8 As8[64 * 16];    // 16 KB
    __shared__ ushort8 Bs8[128 * 16];   // 32 KB
    __shared__ float red[4];
    const int NT = (NNODES + 63) / 64;  // 1563 row tiles
    int bid = blockIdx.x;
    int type = bid >= SNB;
    const unsigned short* Omb = type ? O1b : O0b;
    int bt = bid - (type ? SNB : 0);
    int tid = threadIdx.x;

    // stage B once per block
#pragma unroll
    for (int i = 0; i < 8; ++i) {
        int idx = tid + i * 256;
        int c = idx >> 4, u = idx & 15;
        Bs8[c * 16 + (u ^ (c & 7))] = ((const ushort8*)kwT_b)[idx];
    }

    int l = tid & 63, w = tid >> 6;
    int lrow = w * 16 + (l & 15);
    int ug = l >> 4;
    float s = 0.f;

    // prefetch first tile into registers
    ushort8 pre[4];
    {
        int row0 = bt * 64;
#pragma unroll
        for (int i = 0; i < 4; ++i) {
            int idx = tid + i * 256;
            int row = idx >> 4, u = idx & 15;
            int grow = row0 + row;
            ushort8 v = (ushort8)0;
            if (bt < NT && grow < NNODES) {
                v = ((const ushort8*)Omb)[(long)grow * 16 + u];
#pragma unroll
                for (int e = 0; e < 8; ++e) v[e] = (v[e] & 0x8000) ? 0 : v[e];  // relu
            }
            pre[i] = v;
        }
    }

    for (int t = bt; t < NT; t += SNB) {
        __syncthreads();   // As8 free (prev MFMAs done); 1st iter: B writes done below anyway
#pragma unroll
        for (int i = 0; i < 4; ++i) {
            int idx = tid + i * 256;
            int row = idx >> 4, u = idx & 15;
            As8[row * 16 + (u ^ (row & 7))] = pre[i];
        }
        // issue next tile's loads now; waitcnt lands at next iteration's As8 write,
        // so the latency hides under this tile's MFMA phase
        int tn = t + SNB;
        if (tn < NT) {
            int row0n = tn * 64;
#pragma unroll
            for (int i = 0; i < 4; ++i) {
                int idx = tid + i * 256;
                int row = idx >> 4, u = idx & 15;
                int grow = row0n + row;
                ushort8 v = (ushort8)0;
                if (grow < NNODES) {
                    v = ((const ushort8*)Omb)[(long)grow * 16 + u];
#pragma unroll
                    for (int e = 0; e < 8; ++e) v[e] = (v[e] & 0x8000) ? 0 : v[e];
                }
                pre[i] = v;
            }
        }
        __syncthreads();

        f32x4 acc[8];
#pragma unroll
        for (int ct = 0; ct < 8; ++ct) acc[ct] = (f32x4)0.f;
#pragma unroll
        for (int kc = 0; kc < 4; ++kc) {
            int u = kc * 4 + ug;
            bf16x8 af = *(const bf16x8*)&As8[lrow * 16 + (u ^ (lrow & 7))];
#pragma unroll
            for (int ct = 0; ct < 8; ++ct) {
                int c = ct * 16 + (l & 15);
                bf16x8 bf = *(const bf16x8*)&Bs8[c * 16 + (u ^ (c & 7))];
                acc[ct] = __builtin_amdgcn_mfma_f32_16x16x32_bf16(af, bf, acc[ct], 0, 0, 0);
            }
        }
        int row0 = t * 64;
#pragma unroll
        for (int ct = 0; ct < 8; ++ct) {
            int c = ct * 16 + (l & 15);
            float qc = q[c], kbc = kb[c];
#pragma unroll
            for (int v = 0; v < 4; ++v) {
                int grow = row0 + w * 16 + (l >> 4) * 4 + v;
                if (grow < NNODES) s += qc * tanh_fast(acc[ct][v] + kbc);
            }
        }
    }

#pragma unroll
    for (int m = 32; m >= 1; m >>= 1) s += __shfl_xor(s, m, 64);
    if (l == 0) red[w] = s;
    __syncthreads();
    if (tid == 0) atomicAdd(sacc + type, red[0] + red[1] + red[2] + red[3]);
}

// ============ CSR build (dual-type fused) ============
__global__ void hist_dual(const int* __restrict__ dst0, int* __restrict__ deg0,
                          const int* __restrict__ dst1, int* __restrict__ deg1, int gE) {
    int bid = blockIdx.x;
    int type = bid >= gE;
    const int* dst = type ? dst1 : dst0;
    int* deg = type ? deg1 : deg0;
    int e = (bid - (type ? gE : 0)) * 256 + threadIdx.x;
    if (e < EEDGES) atomicAdd(&deg[dst[e]], 1);
}

__global__ __launch_bounds__(256)
void scan_partial_dual(const int* __restrict__ deg0, int* __restrict__ bsum0,
                       const int* __restrict__ deg1, int* __restrict__ bsum1) {
    __shared__ int red[256];
    int bid = blockIdx.x;
    int type = bid >= SB;
    const int* deg = type ? deg1 : deg0;
    int* bsum = type ? bsum1 : bsum0;
    int b = bid - (type ? SB : 0), t = threadIdx.x;
    int s = 0;
    if (t < 250) {
        int base = b * SCH + t * 2;
        s = deg[base] + deg[base + 1];
    }
    red[t] = s;
    __syncthreads();
#pragma unroll
    for (int off = 128; off >= 1; off >>= 1) {
        if (t < off) red[t] += red[t + off];
        __syncthreads();
    }
    if (t == 0) bsum[b] = red[0];
}

__global__ void scan_bsum_dual(int* __restrict__ bsum0, int* __restrict__ bsum1) {
    int t = threadIdx.x;
    if (t < 2) {
        int* bsum = t ? bsum1 : bsum0;
        int run = 0;
        for (int i = 0; i < SB; ++i) { int v = bsum[i]; bsum[i] = run; run += v; }
    }
}

__global__ __launch_bounds__(256)
void scan_final_dual(const int* __restrict__ deg0, const int* __restrict__ bsum0,
                     int* __restrict__ rowptr0,
                     const int* __restrict__ deg1, const int* __restrict__ bsum1,
                     int* __restrict__ rowptr1) {
    __shared__ int ts[256];
    int bid = blockIdx.x;
    int type = bid >= SB;
    const int* deg = type ? deg1 : deg0;
    const int* bsum = type ? bsum1 : bsum0;
    int* rowptr = type ? rowptr1 : rowptr0;
    int b = bid - (type ? SB : 0), t = threadIdx.x;
    int d0 = 0, d1 = 0;
    int base = b * SCH + t * 2;
    if (t < 250) { d0 = deg[base]; d1 = deg[base + 1]; }
    ts[t] = d0 + d1;
    __syncthreads();
#pragma unroll
    for (int off = 1; off < 256; off <<= 1) {
        int v = (t >= off) ? ts[t - off] : 0;
        __syncthreads();
        ts[t] += v;
        __syncthreads();
    }
    if (t < 250) {
        int excl = bsum[b] + (t > 0 ? ts[t - 1] : 0);
        rowptr[base] = excl;
        rowptr[base + 1] = excl + d0;
    }
    if (b == 0 && t == 0) rowptr[NNODES] = EEDGES;
}

__global__ void fill_dual(const int* __restrict__ src0, const int* __restrict__ dst0,
                          int* __restrict__ cur0, int* __restrict__ cs0, int* __restrict__ cd0,
                          const int* __restrict__ src1, const int* __restrict__ dst1,
                          int* __restrict__ cur1, int* __restrict__ cs1, int* __restrict__ cd1,
                          int gE) {
    int bid = blockIdx.x;
    int type = bid >= gE;
    const int* src = type ? src1 : src0;
    const int* dst = type ? dst1 : dst0;
    int* cursor = type ? cur1 : cur0;
    int* csr_src = type ? cs1 : cs0;
    int* csr_dst = type ? cd1 : cd0;
    int e = (bid - (type ? gE : 0)) * 256 + threadIdx.x;
    if (e < EEDGES) {
        int d = dst[e];
        int pos = atomicAdd(&cursor[d], 1);
        csr_src[pos] = src[e];
        csr_dst[pos] = d;
    }
}

// ---- per-edge softmax weights (unnormalized): w[j] = exp(leaky(as[s]+ad[d])) ----
__global__ __launch_bounds__(256)
void edge_w_dual(const int* __restrict__ cs0, const int* __restrict__ cd0,
                 const float* __restrict__ as0, const float* __restrict__ ad0,
                 float2* __restrict__ w0,
                 const int* __restrict__ cs1, const int* __restrict__ cd1,
                 const float* __restrict__ as1, const float* __restrict__ ad1,
                 float2* __restrict__ w1, int gE) {
    int bid = blockIdx.x;
    int type = bid >= gE;
    const int* cs = type ? cs1 : cs0;
    const int* cd = type ? cd1 : cd0;
    const float* as = type ? as1 : as0;
    const float* ad = type ? ad1 : ad0;
    float2* w = type ? w1 : w0;
    int j = (bid - (type ? gE : 0)) * 256 + threadIdx.x;
    if (j >= EEDGES) return;
    int s = cs[j], d = cd[j];
    float2 a = *(const float2*)(as + s * 2);
    float2 b = *(const float2*)(ad + d * 2);
    float r0 = a.x + b.x; r0 = r0 >= 0.f ? r0 : NEG * r0;
    float r1 = a.y + b.y; r1 = r1 >= 0.f ? r1 : NEG * r1;
    w[j] = make_float2(__expf(r0), __expf(r1));
}

// ============ single-pass aggregation with precomputed edge weights ============
__global__ __launch_bounds__(256)
void seg_aggregate_dual(const int* __restrict__ rowptr0, const int* __restrict__ csr0,
                        const float2* __restrict__ w0, unsigned short* __restrict__ O0,
                        const int* __restrict__ rowptr1, const int* __restrict__ csr1,
                        const float2* __restrict__ w1, unsigned short* __restrict__ O1,
                        const unsigned short* __restrict__ Hfeat, int gseg) {
    int bid = blockIdx.x;
    int type = bid >= gseg;
    const int* rowptr = type ? rowptr1 : rowptr0;
    const int* csr_src = type ? csr1 : csr0;
    const float2* wv = type ? w1 : w0;
    unsigned short* Out = type ? O1 : O0;
    int node = (bid - (type ? gseg : 0)) * 4 + (threadIdx.x >> 6);
    if (node >= NNODES) return;
    int lane = threadIdx.x & 63;
    int start = rowptr[node], end = rowptr[node + 1];

    float s0 = 0.f, s1 = 0.f;
    float accx = 0.f, accy = 0.f;
    int i = start;
    for (; i + 1 < end; i += 2) {
        int sA = csr_src[i], sB = csr_src[i + 1];
        float2 wA2 = wv[i], wB2 = wv[i + 1];
        unsigned int hA = *(const unsigned int*)(Hfeat + (long)sA * CDIM + lane * 2);
        unsigned int hB = *(const unsigned int*)(Hfeat + (long)sB * CDIM + lane * 2);
        s0 += wA2.x + wB2.x;
        s1 += wA2.y + wB2.y;
        float wA = lane < 32 ? wA2.x : wA2.y;
        float wB = lane < 32 ? wB2.x : wB2.y;
        accx = fmaf(bf2f((unsigned short)hA), wA, accx);
        accy = fmaf(bf2f((unsigned short)(hA >> 16)), wA, accy);
        accx = fmaf(bf2f((unsigned short)hB), wB, accx);
        accy = fmaf(bf2f((unsigned short)(hB >> 16)), wB, accy);
    }
    if (i < end) {
        int sA = csr_src[i];
        float2 wA2 = wv[i];
        unsigned int hA = *(const unsigned int*)(Hfeat + (long)sA * CDIM + lane * 2);
        s0 += wA2.x; s1 += wA2.y;
        float wA = lane < 32 ? wA2.x : wA2.y;
        accx = fmaf(bf2f((unsigned short)hA), wA, accx);
        accy = fmaf(bf2f((unsigned short)(hA >> 16)), wA, accy);
    }
    float ssel = lane < 32 ? s0 : s1;
    float inv = ssel > 0.f ? 1.f / ssel : 0.f;
    unsigned int pack = ((unsigned int)f2bf(accy * inv) << 16) | f2bf(accx * inv);
    *(unsigned int*)(Out + (long)node * CDIM + lane * 2) = pack;
}

__global__ void attn_finalize_kernel(const float* __restrict__ sacc, float* __restrict__ attn) {
    float s0 = sacc[0] / (float)NNODES;
    float s1 = sacc[1] / (float)NNODES;
    float m = fmaxf(s0, s1);
    float e0 = expf(s0 - m), e1 = expf(s1 - m);
    float inv = 1.f / (e0 + e1);
    attn[0] = e0 * inv;
    attn[1] = e1 * inv;
}

__global__ __launch_bounds__(256)
void combine_kernel(const unsigned short* __restrict__ O0,
                    const unsigned short* __restrict__ O1,
                    const float* __restrict__ attn, unsigned short* __restrict__ Hn) {
    long i = (long)blockIdx.x * blockDim.x + threadIdx.x;
    long total = (long)NNODES * CDIM / 4;
    if (i >= total) return;
    float a0 = attn[0], a1 = attn[1];
    ushort4 u0 = ((const ushort4*)O0)[i];
    ushort4 u1 = ((const ushort4*)O1)[i];
    ushort4 o;
    o.x = f2bf(a0 * fmaxf(bf2f(u0.x), 0.f) + a1 * fmaxf(bf2f(u1.x), 0.f));
    o.y = f2bf(a0 * fmaxf(bf2f(u0.y), 0.f) + a1 * fmaxf(bf2f(u1.y), 0.f));
    o.z = f2bf(a0 * fmaxf(bf2f(u0.z), 0.f) + a1 * fmaxf(bf2f(u1.z), 0.f));
    o.w = f2bf(a0 * fmaxf(bf2f(u0.w), 0.f) + a1 * fmaxf(bf2f(u1.w), 0.f));
    ((ushort4*)Hn)[i] = o;
}

__global__ __launch_bounds__(256)
void final_linear_kernel(const unsigned short* __restrict__ Hn, const float* __restrict__ lw,
                         const float* __restrict__ lb, float* __restrict__ out) {
    __shared__ float lws[CDIM * FOUT];
    int tid = threadIdx.x;
    for (int i = tid; i < CDIM * FOUT; i += 256) lws[i] = lw[i];
    __syncthreads();
    int idx = blockIdx.x * 256 + tid;
    if (idx >= NNODES * FOUT) return;
    int n = idx >> 3, o = idx & 7;
    const ushort8* row = (const ushort8*)(Hn + (long)n * CDIM);
    float acc = lb[o];
#pragma unroll
    for (int k8 = 0; k8 < 16; ++k8) {
        ushort8 v = row[k8];
#pragma unroll
        for (int e = 0; e < 8; ++e)
            acc = fmaf(bf2f(v[e]), lws[(k8 * 8 + e) * FOUT + o], acc);
    }
    out[idx] = acc;
}

struct Graph {
    const int *rp0, *cs0, *cd0, *rp1, *cs1, *cd1;
    float2 *w0, *w1;
};

static void run_layer(const void* X, int K,
                      const float* pw, const float* pb,
                      const float* ats, const float* atd,
                      const float* q, const float* kw, const float* kb,
                      const Graph& g,
                      unsigned short* Hb, unsigned short* O0b, unsigned short* O1b,
                      unsigned short* OutBuf,
                      float* asrc, float* adst,
                      float* sacc, float* attn,
                      unsigned short* pwT_b, unsigned short* kwT_b,
                      hipStream_t stream) {
    const int gm = (NNODES + 63) / 64;  // 1563
    const int gE = (EEDGES + 255) / 256;
    if (K == 64) {
        cvt_wT<64><<<(64 * CDIM + 255) / 256, 256, 0, stream>>>(pw, pwT_b);
        proj_mfma<64, false><<<gm, 256, 0, stream>>>(X, pwT_b, pb, ats, atd,
                                                     Hb, asrc, adst);
    } else {
        cvt_wT<128><<<(128 * CDIM + 255) / 256, 256, 0, stream>>>(pw, pwT_b);
        proj_mfma<128, true><<<gm, 256, 0, stream>>>(X, pwT_b, pb, ats, atd,
                                                     Hb, asrc, adst);
    }
    cvt_wT<128><<<(128 * CDIM + 255) / 256, 256, 0, stream>>>(kw, kwT_b);

    const int nh = NNODES * HHEADS;
    edge_w_dual<<<2 * gE, 256, 0, stream>>>(
        g.cs0, g.cd0, asrc, adst, g.w0,
        g.cs1, g.cd1, asrc + nh, adst + nh, g.w1, gE);

    const int gseg = (NNODES + 3) / 4;
    seg_aggregate_dual<<<2 * gseg, 256, 0, stream>>>(
        g.rp0, g.cs0, g.w0, O0b,
        g.rp1, g.cs1, g.w1, O1b, Hb, gseg);

    hipMemsetAsync(sacc, 0, 2 * sizeof(float), stream);
    score_mfma_dual<<<2 * SNB, 256, 0, stream>>>(O0b, O1b, kwT_b, kb, q, sacc);
    attn_finalize_kernel<<<1, 1, 0, stream>>>(sacc, attn);
    const long q4 = (long)NNODES * CDIM / 4;
    combine_kernel<<<(int)((q4 + 255) / 256), 256, 0, stream>>>(O0b, O1b, attn, OutBuf);
}

extern "C" void kernel_launch(void* const* d_in, const int* in_sizes, int n_in,
                              void* d_out, int out_size, void* d_ws, size_t ws_size,
                              hipStream_t stream) {
    const float* x          = (const float*)d_in[0];
    const int*   ei_spatial = (const int*)d_in[1];
    const int*   ei_similar = (const int*)d_in[2];
    const float* p1_proj_w  = (const float*)d_in[3];
    const float* p1_proj_b  = (const float*)d_in[4];
    const float* p1_att_src = (const float*)d_in[5];
    const float* p1_att_dst = (const float*)d_in[6];
    const float* p1_q       = (const float*)d_in[7];
    const float* p1_kw      = (const float*)d_in[8];
    const float* p1_kb      = (const float*)d_in[9];
    const float* p2_proj_w  = (const float*)d_in[10];
    const float* p2_proj_b  = (const float*)d_in[11];
    const float* p2_att_src = (const float*)d_in[12];
    const float* p2_att_dst = (const float*)d_in[13];
    const float* p2_q       = (const float*)d_in[14];
    const float* p2_kw      = (const float*)d_in[15];
    const float* p2_kb      = (const float*)d_in[16];
    const float* lin_w      = (const float*)d_in[17];
    const float* lin_b      = (const float*)d_in[18];

    float* ws = (float*)d_ws;
    const size_t nc = (size_t)NNODES * CDIM;
    const size_t nh2 = (size_t)NNODES * HHEADS;

    float* asrc = ws;                    // 2*N*H
    float* adst = asrc + 2 * nh2;        // 2*N*H
    float* sacc = adst + 2 * nh2;        // 2
    float* attn = sacc + 2;              // 2
    int* rowptr0 = (int*)(attn + 2);     // N+1
    int* rowptr1 = rowptr0 + (NNODES + 1);
    int* cursor0 = rowptr1 + (NNODES + 1);  // N+1 (contiguous with cursor1)
    int* cursor1 = cursor0 + (NNODES + 1);
    int* cs0     = cursor1 + (NNODES + 1);  // E
    int* cd0     = cs0 + EEDGES;            // E
    int* cs1     = cd0 + EEDGES;            // E
    int* cd1     = cs1 + EEDGES;            // E
    int* deg0    = cd1 + EEDGES;            // N (deg0/deg1 contiguous for one memset)
    int* deg1    = deg0 + NNODES;           // N
    int* bsum0   = deg1 + NNODES;           // SB
    int* bsum1   = bsum0 + SB;              // SB
    uintptr_t kp = (uintptr_t)(bsum1 + SB);
    kp = (kp + 15) & ~(uintptr_t)15;
    float2* w0 = (float2*)kp;                       // E float2
    float2* w1 = w0 + EEDGES;                       // E float2
    unsigned short* pwT_b = (unsigned short*)(w1 + EEDGES);  // 128*128 bf16
    unsigned short* kwT_b = pwT_b + CDIM * CDIM;
    unsigned short* Hb    = kwT_b + CDIM * CDIM;    // N*C bf16
    unsigned short* O0b   = Hb + nc;
    unsigned short* O1b   = O0b + nc;
    unsigned short* Ab    = O1b + nc;

    // ---- build CSR for both edge types (structure reused across layers) ----
    const int gE = (EEDGES + 255) / 256;
    hipMemsetAsync(deg0, 0, 2 * NNODES * sizeof(int), stream);
    hist_dual<<<2 * gE, 256, 0, stream>>>(ei_spatial + EEDGES, deg0,
                                          ei_similar + EEDGES, deg1, gE);
    scan_partial_dual<<<2 * SB, 256, 0, stream>>>(deg0, bsum0, deg1, bsum1);
    scan_bsum_dual<<<1, 64, 0, stream>>>(bsum0, bsum1);
    scan_final_dual<<<2 * SB, 256, 0, stream>>>(deg0, bsum0, rowptr0, deg1, bsum1, rowptr1);
    hipMemcpyAsync(cursor0, rowptr0, 2 * (NNODES + 1) * sizeof(int),
                   hipMemcpyDeviceToDevice, stream);
    fill_dual<<<2 * gE, 256, 0, stream>>>(ei_spatial, ei_spatial + EEDGES, cursor0, cs0, cd0,
                                          ei_similar, ei_similar + EEDGES, cursor1, cs1, cd1, gE);

    Graph g = {rowptr0, cs0, cd0, rowptr1, cs1, cd1, w0, w1};

    // Layer 1: proj(x f32)->Hb ; edge_w ; seg->O0b,O1b ; combine->Ab (bf16)
    run_layer(x, FIN, p1_proj_w, p1_proj_b, p1_att_src, p1_att_dst,
              p1_q, p1_kw, p1_kb, g,
              Hb, O0b, O1b, Ab, asrc, adst, sacc, attn, pwT_b, kwT_b, stream);

    // Layer 2: proj(Ab bf16)->Hb ; edge_w ; seg->O0b,O1b ; combine->Ab
    run_layer(Ab, CDIM, p2_proj_w, p2_proj_b, p2_att_src, p2_att_dst,
              p2_q, p2_kw, p2_kb, g,
              Hb, O0b, O1b, Ab, asrc, adst, sacc, attn, pwT_b, kwT_b, stream);

    // Final classifier (bf16 input)
    const int gfin = (NNODES * FOUT + 255) / 256;
    final_linear_kernel<<<gfin, 256, 0, stream>>>(Ab, lin_w, lin_b, (float*)d_out);
}

// Round 12
// 530.216 us; speedup vs baseline: 5.7036x; 1.0295x over previous
//
#include <hip/hip_runtime.h>

#define NNODES 100000
#define EEDGES 600000
#define CDIM 128
#define HHEADS 2
#define DDIM 64
#define FIN 64
#define FOUT 8
#define NEG 0.2f

#define SB 200    // scan blocks
#define SCH 500   // nodes per scan block (200*500 = 100000 exactly)
#define SNB 384   // persistent score blocks per edge type

typedef short bf16x8 __attribute__((ext_vector_type(8)));
typedef unsigned short ushort8 __attribute__((ext_vector_type(8)));
typedef float f32x4 __attribute__((ext_vector_type(4)));

__device__ __forceinline__ float tanh_fast(float x) {
    float e = __expf(2.f * x);
    return 1.f - 2.f / (e + 1.f);
}

__device__ __forceinline__ unsigned short f2bf(float x) {
    unsigned int u = __float_as_uint(x);
    unsigned int r = (u + 0x7FFFu + ((u >> 16) & 1u)) >> 16;  // RNE
    return (unsigned short)r;
}
__device__ __forceinline__ float bf2f(unsigned short u) {
    return __uint_as_float(((unsigned int)u) << 16);
}

// ---- weight -> transposed bf16 (once per layer): wT[c*K+k] = bf16(w[k*CDIM+c]) ----
template<int K>
__global__ __launch_bounds__(256)
void cvt_wT(const float* __restrict__ w, unsigned short* __restrict__ wT) {
    int idx = blockIdx.x * 256 + threadIdx.x;
    if (idx >= K * CDIM) return;
    int c = idx / K, k = idx % K;
    wT[idx] = f2bf(w[k * CDIM + c]);
}

// ============ projection via MFMA: H = bf16(X@W + b), fused attention dots ============
template<int K, bool XBF>
__global__ __launch_bounds__(256)
void proj_mfma(const void* __restrict__ Xv, const unsigned short* __restrict__ pwT_b,
               const float* __restrict__ bias,
               const float* __restrict__ att_src, const float* __restrict__ att_dst,
               unsigned short* __restrict__ Hout,
               float* __restrict__ a_src, float* __restrict__ a_dst) {
    const int U = K / 8;
    __shared__ ushort8 smem[192 * (K / 8)];   // As8 [64][U] + Bs8 [128][U]
    ushort8* As8 = smem;
    ushort8* Bs8 = smem + 64 * U;
    int tid = threadIdx.x;
    int row0 = blockIdx.x * 64;

#pragma unroll
    for (int i = 0; i < (64 * U) / 256; ++i) {
        int idx = tid + i * 256;
        int row = idx / U, u = idx % U;
        int grow = row0 + row;
        ushort8 v;
        if (grow < NNODES) {
            if (XBF) {
                v = ((const ushort8*)Xv)[(long)grow * U + u];
            } else {
                const float* p = (const float*)Xv + (long)grow * K + u * 8;
                float4 a = *(const float4*)p;
                float4 b = *(const float4*)(p + 4);
                v[0] = f2bf(a.x); v[1] = f2bf(a.y); v[2] = f2bf(a.z); v[3] = f2bf(a.w);
                v[4] = f2bf(b.x); v[5] = f2bf(b.y); v[6] = f2bf(b.z); v[7] = f2bf(b.w);
            }
        } else v = (ushort8)0;
        As8[row * U + (u ^ (row & 7))] = v;
    }
#pragma unroll
    for (int i = 0; i < (128 * U) / 256; ++i) {
        int idx = tid + i * 256;
        int c = idx / U, u = idx % U;
        Bs8[c * U + (u ^ (c & 7))] = ((const ushort8*)pwT_b)[idx];
    }
    __syncthreads();

    int l = tid & 63, w = tid >> 6;
    int lrow = w * 16 + (l & 15);
    int ug = l >> 4;
    f32x4 acc[8];
#pragma unroll
    for (int ct = 0; ct < 8; ++ct) acc[ct] = (f32x4)0.f;

#pragma unroll
    for (int kc = 0; kc < K / 32; ++kc) {
        int u = kc * 4 + ug;
        bf16x8 af = *(const bf16x8*)&As8[lrow * U + (u ^ (lrow & 7))];
#pragma unroll
        for (int ct = 0; ct < 8; ++ct) {
            int c = ct * 16 + (l & 15);
            bf16x8 bf = *(const bf16x8*)&Bs8[c * U + (u ^ (c & 7))];
            acc[ct] = __builtin_amdgcn_mfma_f32_16x16x32_bf16(af, bf, acc[ct], 0, 0, 0);
        }
    }

    __syncthreads();
    unsigned short* Cs = (unsigned short*)smem;  // [64][128]
#pragma unroll
    for (int ct = 0; ct < 8; ++ct) {
        int c = ct * 16 + (l & 15);
        float bc = bias[c];
#pragma unroll
        for (int v = 0; v < 4; ++v) {
            int rr = w * 16 + (l >> 4) * 4 + v;
            Cs[rr * 128 + c] = f2bf(acc[ct][v] + bc);
        }
    }
    __syncthreads();

    int r = tid >> 2, q = tid & 3;
    int grow = row0 + r;
    if (grow < NNODES) {
        float h[32];
        ushort8 hv[4];
#pragma unroll
        for (int j = 0; j < 4; ++j) {
            hv[j] = *(ushort8*)&Cs[r * 128 + q * 32 + j * 8];
#pragma unroll
            for (int e = 0; e < 8; ++e) h[j * 8 + e] = bf2f(hv[j][e]);
        }
#pragma unroll
        for (int j = 0; j < 4; ++j)
            *(ushort8*)(Hout + (long)grow * CDIM + q * 32 + j * 8) = hv[j];
#pragma unroll
        for (int i = 0; i < 2; ++i) {
            float s = 0.f, d = 0.f;
#pragma unroll
            for (int j = 0; j < 32; ++j) {
                s = fmaf(h[j], att_src[i * CDIM + q * 32 + j], s);
                d = fmaf(h[j], att_dst[i * CDIM + q * 32 + j], d);
            }
            s += __shfl_xor(s, 1, 64);
            d += __shfl_xor(d, 1, 64);
            if ((q & 1) == 0) {
                int hh = q >> 1;
                long base = (long)i * NNODES * HHEADS + (long)grow * HHEADS + hh;
                a_src[base] = s;
                a_dst[base] = d;
            }
        }
    }
}

// ---- semantic score via MFMA: persistent blocks, kw staged ONCE ----
__global__ __launch_bounds__(256, 3)
void score_mfma_dual(const unsigned short* __restrict__ O0b,
                     const unsigned short* __restrict__ O1b,
                     const unsigned short* __restrict__ kwT_b,
                     const float* __restrict__ kb, const float* __restrict__ q,
                     float* __restrict__ sacc) {
    __shared__ ushort8 As8[64 * 16];    // 16 KB
    __shared__ ushort8 Bs8[128 * 16];   // 32 KB
    __shared__ float red[4];
    const int NT = (NNODES + 63) / 64;  // 1563 row tiles
    int bid = blockIdx.x;
    int type = bid >= SNB;
    const unsigned short* Omb = type ? O1b : O0b;
    int bt = bid - (type ? SNB : 0);
    int tid = threadIdx.x;

#pragma unroll
    for (int i = 0; i < 8; ++i) {
        int idx = tid + i * 256;
        int c = idx >> 4, u = idx & 15;
        Bs8[c * 16 + (u ^ (c & 7))] = ((const ushort8*)kwT_b)[idx];
    }

    int l = tid & 63, w = tid >> 6;
    int lrow = w * 16 + (l & 15);
    int ug = l >> 4;
    float s = 0.f;

    ushort8 pre[4];
    {
        int row0 = bt * 64;
#pragma unroll
        for (int i = 0; i < 4; ++i) {
            int idx = tid + i * 256;
            int row = idx >> 4, u = idx & 15;
            int grow = row0 + row;
            ushort8 v = (ushort8)0;
            if (bt < NT && grow < NNODES) {
                v = ((const ushort8*)Omb)[(long)grow * 16 + u];
#pragma unroll
                for (int e = 0; e < 8; ++e) v[e] = (v[e] & 0x8000) ? 0 : v[e];  // relu
            }
            pre[i] = v;
        }
    }

    for (int t = bt; t < NT; t += SNB) {
        __syncthreads();
#pragma unroll
        for (int i = 0; i < 4; ++i) {
            int idx = tid + i * 256;
            int row = idx >> 4, u = idx & 15;
            As8[row * 16 + (u ^ (row & 7))] = pre[i];
        }
        int tn = t + SNB;
        if (tn < NT) {
            int row0n = tn * 64;
#pragma unroll
            for (int i = 0; i < 4; ++i) {
                int idx = tid + i * 256;
                int row = idx >> 4, u = idx & 15;
                int grow = row0n + row;
                ushort8 v = (ushort8)0;
                if (grow < NNODES) {
                    v = ((const ushort8*)Omb)[(long)grow * 16 + u];
#pragma unroll
                    for (int e = 0; e < 8; ++e) v[e] = (v[e] & 0x8000) ? 0 : v[e];
                }
                pre[i] = v;
            }
        }
        __syncthreads();

        f32x4 acc[8];
#pragma unroll
        for (int ct = 0; ct < 8; ++ct) acc[ct] = (f32x4)0.f;
#pragma unroll
        for (int kc = 0; kc < 4; ++kc) {
            int u = kc * 4 + ug;
            bf16x8 af = *(const bf16x8*)&As8[lrow * 16 + (u ^ (lrow & 7))];
#pragma unroll
            for (int ct = 0; ct < 8; ++ct) {
                int c = ct * 16 + (l & 15);
                bf16x8 bf = *(const bf16x8*)&Bs8[c * 16 + (u ^ (c & 7))];
                acc[ct] = __builtin_amdgcn_mfma_f32_16x16x32_bf16(af, bf, acc[ct], 0, 0, 0);
            }
        }
        int row0 = t * 64;
#pragma unroll
        for (int ct = 0; ct < 8; ++ct) {
            int c = ct * 16 + (l & 15);
            float qc = q[c], kbc = kb[c];
#pragma unroll
            for (int v = 0; v < 4; ++v) {
                int grow = row0 + w * 16 + (l >> 4) * 4 + v;
                if (grow < NNODES) s += qc * tanh_fast(acc[ct][v] + kbc);
            }
        }
    }

#pragma unroll
    for (int m = 32; m >= 1; m >>= 1) s += __shfl_xor(s, m, 64);
    if (l == 0) red[w] = s;
    __syncthreads();
    if (tid == 0) atomicAdd(sacc + type, red[0] + red[1] + red[2] + red[3]);
}

// ============ CSR build (dual-type fused) ============
__global__ void hist_dual(const int* __restrict__ dst0, int* __restrict__ deg0,
                          const int* __restrict__ dst1, int* __restrict__ deg1, int gE) {
    int bid = blockIdx.x;
    int type = bid >= gE;
    const int* dst = type ? dst1 : dst0;
    int* deg = type ? deg1 : deg0;
    int e = (bid - (type ? gE : 0)) * 256 + threadIdx.x;
    if (e < EEDGES) atomicAdd(&deg[dst[e]], 1);
}

__global__ __launch_bounds__(256)
void scan_partial_dual(const int* __restrict__ deg0, int* __restrict__ bsum0,
                       const int* __restrict__ deg1, int* __restrict__ bsum1) {
    __shared__ int red[256];
    int bid = blockIdx.x;
    int type = bid >= SB;
    const int* deg = type ? deg1 : deg0;
    int* bsum = type ? bsum1 : bsum0;
    int b = bid - (type ? SB : 0), t = threadIdx.x;
    int s = 0;
    if (t < 250) {
        int base = b * SCH + t * 2;
        s = deg[base] + deg[base + 1];
    }
    red[t] = s;
    __syncthreads();
#pragma unroll
    for (int off = 128; off >= 1; off >>= 1) {
        if (t < off) red[t] += red[t + off];
        __syncthreads();
    }
    if (t == 0) bsum[b] = red[0];
}

__global__ void scan_bsum_dual(int* __restrict__ bsum0, int* __restrict__ bsum1) {
    int t = threadIdx.x;
    if (t < 2) {
        int* bsum = t ? bsum1 : bsum0;
        int run = 0;
        for (int i = 0; i < SB; ++i) { int v = bsum[i]; bsum[i] = run; run += v; }
    }
}

__global__ __launch_bounds__(256)
void scan_final_dual(const int* __restrict__ deg0, const int* __restrict__ bsum0,
                     int* __restrict__ rowptr0,
                     const int* __restrict__ deg1, const int* __restrict__ bsum1,
                     int* __restrict__ rowptr1) {
    __shared__ int ts[256];
    int bid = blockIdx.x;
    int type = bid >= SB;
    const int* deg = type ? deg1 : deg0;
    const int* bsum = type ? bsum1 : bsum0;
    int* rowptr = type ? rowptr1 : rowptr0;
    int b = bid - (type ? SB : 0), t = threadIdx.x;
    int d0 = 0, d1 = 0;
    int base = b * SCH + t * 2;
    if (t < 250) { d0 = deg[base]; d1 = deg[base + 1]; }
    ts[t] = d0 + d1;
    __syncthreads();
#pragma unroll
    for (int off = 1; off < 256; off <<= 1) {
        int v = (t >= off) ? ts[t - off] : 0;
        __syncthreads();
        ts[t] += v;
        __syncthreads();
    }
    if (t < 250) {
        int excl = bsum[b] + (t > 0 ? ts[t - 1] : 0);
        rowptr[base] = excl;
        rowptr[base + 1] = excl + d0;
    }
    if (b == 0 && t == 0) rowptr[NNODES] = EEDGES;
}

__global__ void fill_dual(const int* __restrict__ src0, const int* __restrict__ dst0,
                          int* __restrict__ cur0, int* __restrict__ cs0, int* __restrict__ cd0,
                          const int* __restrict__ src1, const int* __restrict__ dst1,
                          int* __restrict__ cur1, int* __restrict__ cs1, int* __restrict__ cd1,
                          int gE) {
    int bid = blockIdx.x;
    int type = bid >= gE;
    const int* src = type ? src1 : src0;
    const int* dst = type ? dst1 : dst0;
    int* cursor = type ? cur1 : cur0;
    int* csr_src = type ? cs1 : cs0;
    int* csr_dst = type ? cd1 : cd0;
    int e = (bid - (type ? gE : 0)) * 256 + threadIdx.x;
    if (e < EEDGES) {
        int d = dst[e];
        int pos = atomicAdd(&cursor[d], 1);
        csr_src[pos] = src[e];
        csr_dst[pos] = d;
    }
}

// ---- per-edge softmax weights (unnormalized): w[j] = exp(leaky(as[s]+ad[d])) ----
__global__ __launch_bounds__(256)
void edge_w_dual(const int* __restrict__ cs0, const int* __restrict__ cd0,
                 const float* __restrict__ as0, const float* __restrict__ ad0,
                 float2* __restrict__ w0,
                 const int* __restrict__ cs1, const int* __restrict__ cd1,
                 const float* __restrict__ as1, const float* __restrict__ ad1,
                 float2* __restrict__ w1, int gE) {
    int bid = blockIdx.x;
    int type = bid >= gE;
    const int* cs = type ? cs1 : cs0;
    const int* cd = type ? cd1 : cd0;
    const float* as = type ? as1 : as0;
    const float* ad = type ? ad1 : ad0;
    float2* w = type ? w1 : w0;
    int j = (bid - (type ? gE : 0)) * 256 + threadIdx.x;
    if (j >= EEDGES) return;
    int s = cs[j], d = cd[j];
    float2 a = *(const float2*)(as + s * 2);
    float2 b = *(const float2*)(ad + d * 2);
    float r0 = a.x + b.x; r0 = r0 >= 0.f ? r0 : NEG * r0;
    float r1 = a.y + b.y; r1 = r1 >= 0.f ? r1 : NEG * r1;
    w[j] = make_float2(__expf(r0), __expf(r1));
}

// ============ single-pass aggregation v2: cooperative edge staging + 2 edges/gather ======
// lanes 0-31 = even edges, lanes 32-63 = odd edges; lane covers 4 channels (uint2 of bf16).
// channel c = 4*(lane&31)+j; head0 = c<64 -> (lane&31)<16.
__global__ __launch_bounds__(256)
void seg_aggregate_dual(const int* __restrict__ rowptr0, const int* __restrict__ csr0,
                        const float2* __restrict__ w0, unsigned short* __restrict__ O0,
                        const int* __restrict__ rowptr1, const int* __restrict__ csr1,
                        const float2* __restrict__ w1, unsigned short* __restrict__ O1,
                        const unsigned short* __restrict__ Hfeat, int gseg) {
    int bid = blockIdx.x;
    int type = bid >= gseg;
    const int* rowptr = type ? rowptr1 : rowptr0;
    const int* csr_src = type ? csr1 : csr0;
    const float2* wv = type ? w1 : w0;
    unsigned short* Out = type ? O1 : O0;
    int node = (bid - (type ? gseg : 0)) * 4 + (threadIdx.x >> 6);
    if (node >= NNODES) return;
    int lane = threadIdx.x & 63;
    int cl = lane & 31, eg = lane >> 5;
    int start = rowptr[node], end = rowptr[node + 1];
    int deg = end - start;

    float a0 = 0.f, a1 = 0.f, a2 = 0.f, a3 = 0.f;
    float s0 = 0.f, s1 = 0.f;
    for (int base = 0; base < deg; base += 64) {
        int n = deg - base; if (n > 64) n = 64;
        // cooperative stage: lane i holds edge base+i (coalesced)
        int sA = 0; float wx = 0.f, wy = 0.f;
        if (lane < n) {
            sA = csr_src[start + base + lane];
            float2 t = wv[start + base + lane];
            wx = t.x; wy = t.y;
        }
        s0 += wx; s1 += wy;
        for (int e0 = 0; e0 < n; e0 += 4) {
            // pair A: edges e0 (lanes 0-31) and e0+1 (lanes 32-63)
            int eA = e0 + eg;
            int siA = __shfl(sA, eA, 64);
            float wxA = __shfl(wx, eA, 64);
            float wyA = __shfl(wy, eA, 64);
            float wA = cl < 16 ? wxA : wyA;   // zero if eA >= n (lane eA holds zeros)
            uint2 hA = *(const uint2*)(Hfeat + (long)siA * CDIM + cl * 4);
            a0 = fmaf(bf2f((unsigned short)hA.x), wA, a0);
            a1 = fmaf(bf2f((unsigned short)(hA.x >> 16)), wA, a1);
            a2 = fmaf(bf2f((unsigned short)hA.y), wA, a2);
            a3 = fmaf(bf2f((unsigned short)(hA.y >> 16)), wA, a3);
            if (e0 + 2 < n) {  // wave-uniform
                int eB = e0 + 2 + eg;
                int siB = __shfl(sA, eB, 64);
                float wxB = __shfl(wx, eB, 64);
                float wyB = __shfl(wy, eB, 64);
                float wB = cl < 16 ? wxB : wyB;
                uint2 hB = *(const uint2*)(Hfeat + (long)siB * CDIM + cl * 4);
                a0 = fmaf(bf2f((unsigned short)hB.x), wB, a0);
                a1 = fmaf(bf2f((unsigned short)(hB.x >> 16)), wB, a1);
                a2 = fmaf(bf2f((unsigned short)hB.y), wB, a2);
                a3 = fmaf(bf2f((unsigned short)(hB.y >> 16)), wB, a3);
            }
        }
    }
    // total softmax denominators over all lanes
#pragma unroll
    for (int m = 32; m >= 1; m >>= 1) {
        s0 += __shfl_xor(s0, m, 64);
        s1 += __shfl_xor(s1, m, 64);
    }
    // merge even/odd edge groups
    a0 += __shfl_xor(a0, 32, 64);
    a1 += __shfl_xor(a1, 32, 64);
    a2 += __shfl_xor(a2, 32, 64);
    a3 += __shfl_xor(a3, 32, 64);
    if (lane < 32) {
        float ssel = lane < 16 ? s0 : s1;
        float inv = ssel > 0.f ? 1.f / ssel : 0.f;
        uint2 o;
        o.x = (unsigned int)f2bf(a0 * inv) | ((unsigned int)f2bf(a1 * inv) << 16);
        o.y = (unsigned int)f2bf(a2 * inv) | ((unsigned int)f2bf(a3 * inv) << 16);
        *(uint2*)(Out + (long)node * CDIM + lane * 4) = o;
    }
}

__global__ void attn_finalize_kernel(const float* __restrict__ sacc, float* __restrict__ attn) {
    float s0 = sacc[0] / (float)NNODES;
    float s1 = sacc[1] / (float)NNODES;
    float m = fmaxf(s0, s1);
    float e0 = expf(s0 - m), e1 = expf(s1 - m);
    float inv = 1.f / (e0 + e1);
    attn[0] = e0 * inv;
    attn[1] = e1 * inv;
}

__global__ __launch_bounds__(256)
void combine_kernel(const unsigned short* __restrict__ O0,
                    const unsigned short* __restrict__ O1,
                    const float* __restrict__ attn, unsigned short* __restrict__ Hn) {
    long i = (long)blockIdx.x * blockDim.x + threadIdx.x;
    long total = (long)NNODES * CDIM / 4;
    if (i >= total) return;
    float a0 = attn[0], a1 = attn[1];
    ushort4 u0 = ((const ushort4*)O0)[i];
    ushort4 u1 = ((const ushort4*)O1)[i];
    ushort4 o;
    o.x = f2bf(a0 * fmaxf(bf2f(u0.x), 0.f) + a1 * fmaxf(bf2f(u1.x), 0.f));
    o.y = f2bf(a0 * fmaxf(bf2f(u0.y), 0.f) + a1 * fmaxf(bf2f(u1.y), 0.f));
    o.z = f2bf(a0 * fmaxf(bf2f(u0.z), 0.f) + a1 * fmaxf(bf2f(u1.z), 0.f));
    o.w = f2bf(a0 * fmaxf(bf2f(u0.w), 0.f) + a1 * fmaxf(bf2f(u1.w), 0.f));
    ((ushort4*)Hn)[i] = o;
}

__global__ __launch_bounds__(256)
void final_linear_kernel(const unsigned short* __restrict__ Hn, const float* __restrict__ lw,
                         const float* __restrict__ lb, float* __restrict__ out) {
    __shared__ float lws[CDIM * FOUT];
    int tid = threadIdx.x;
    for (int i = tid; i < CDIM * FOUT; i += 256) lws[i] = lw[i];
    __syncthreads();
    int idx = blockIdx.x * 256 + tid;
    if (idx >= NNODES * FOUT) return;
    int n = idx >> 3, o = idx & 7;
    const ushort8* row = (const ushort8*)(Hn + (long)n * CDIM);
    float acc = lb[o];
#pragma unroll
    for (int k8 = 0; k8 < 16; ++k8) {
        ushort8 v = row[k8];
#pragma unroll
        for (int e = 0; e < 8; ++e)
            acc = fmaf(bf2f(v[e]), lws[(k8 * 8 + e) * FOUT + o], acc);
    }
    out[idx] = acc;
}

struct Graph {
    const int *rp0, *cs0, *cd0, *rp1, *cs1, *cd1;
    float2 *w0, *w1;
};

static void run_layer(const void* X, int K,
                      const float* pw, const float* pb,
                      const float* ats, const float* atd,
                      const float* q, const float* kw, const float* kb,
                      const Graph& g,
                      unsigned short* Hb, unsigned short* O0b, unsigned short* O1b,
                      unsigned short* OutBuf,
                      float* asrc, float* adst,
                      float* sacc, float* attn,
                      unsigned short* pwT_b, unsigned short* kwT_b,
                      hipStream_t stream) {
    const int gm = (NNODES + 63) / 64;  // 1563
    const int gE = (EEDGES + 255) / 256;
    if (K == 64) {
        cvt_wT<64><<<(64 * CDIM + 255) / 256, 256, 0, stream>>>(pw, pwT_b);
        proj_mfma<64, false><<<gm, 256, 0, stream>>>(X, pwT_b, pb, ats, atd,
                                                     Hb, asrc, adst);
    } else {
        cvt_wT<128><<<(128 * CDIM + 255) / 256, 256, 0, stream>>>(pw, pwT_b);
        proj_mfma<128, true><<<gm, 256, 0, stream>>>(X, pwT_b, pb, ats, atd,
                                                     Hb, asrc, adst);
    }
    cvt_wT<128><<<(128 * CDIM + 255) / 256, 256, 0, stream>>>(kw, kwT_b);

    const int nh = NNODES * HHEADS;
    edge_w_dual<<<2 * gE, 256, 0, stream>>>(
        g.cs0, g.cd0, asrc, adst, g.w0,
        g.cs1, g.cd1, asrc + nh, adst + nh, g.w1, gE);

    const int gseg = (NNODES + 3) / 4;
    seg_aggregate_dual<<<2 * gseg, 256, 0, stream>>>(
        g.rp0, g.cs0, g.w0, O0b,
        g.rp1, g.cs1, g.w1, O1b, Hb, gseg);

    hipMemsetAsync(sacc, 0, 2 * sizeof(float), stream);
    score_mfma_dual<<<2 * SNB, 256, 0, stream>>>(O0b, O1b, kwT_b, kb, q, sacc);
    attn_finalize_kernel<<<1, 1, 0, stream>>>(sacc, attn);
    const long q4 = (long)NNODES * CDIM / 4;
    combine_kernel<<<(int)((q4 + 255) / 256), 256, 0, stream>>>(O0b, O1b, attn, OutBuf);
}

extern "C" void kernel_launch(void* const* d_in, const int* in_sizes, int n_in,
                              void* d_out, int out_size, void* d_ws, size_t ws_size,
                              hipStream_t stream) {
    const float* x          = (const float*)d_in[0];
    const int*   ei_spatial = (const int*)d_in[1];
    const int*   ei_similar = (const int*)d_in[2];
    const float* p1_proj_w  = (const float*)d_in[3];
    const float* p1_proj_b  = (const float*)d_in[4];
    const float* p1_att_src = (const float*)d_in[5];
    const float* p1_att_dst = (const float*)d_in[6];
    const float* p1_q       = (const float*)d_in[7];
    const float* p1_kw      = (const float*)d_in[8];
    const float* p1_kb      = (const float*)d_in[9];
    const float* p2_proj_w  = (const float*)d_in[10];
    const float* p2_proj_b  = (const float*)d_in[11];
    const float* p2_att_src = (const float*)d_in[12];
    const float* p2_att_dst = (const float*)d_in[13];
    const float* p2_q       = (const float*)d_in[14];
    const float* p2_kw      = (const float*)d_in[15];
    const float* p2_kb      = (const float*)d_in[16];
    const float* lin_w      = (const float*)d_in[17];
    const float* lin_b      = (const float*)d_in[18];

    float* ws = (float*)d_ws;
    const size_t nc = (size_t)NNODES * CDIM;
    const size_t nh2 = (size_t)NNODES * HHEADS;

    float* asrc = ws;                    // 2*N*H
    float* adst = asrc + 2 * nh2;        // 2*N*H
    float* sacc = adst + 2 * nh2;        // 2
    float* attn = sacc + 2;              // 2
    int* rowptr0 = (int*)(attn + 2);     // N+1
    int* rowptr1 = rowptr0 + (NNODES + 1);
    int* cursor0 = rowptr1 + (NNODES + 1);  // N+1 (contiguous with cursor1)
    int* cursor1 = cursor0 + (NNODES + 1);
    int* cs0     = cursor1 + (NNODES + 1);  // E
    int* cd0     = cs0 + EEDGES;            // E
    int* cs1     = cd0 + EEDGES;            // E
    int* cd1     = cs1 + EEDGES;            // E
    int* deg0    = cd1 + EEDGES;            // N (deg0/deg1 contiguous for one memset)
    int* deg1    = deg0 + NNODES;           // N
    int* bsum0   = deg1 + NNODES;           // SB
    int* bsum1   = bsum0 + SB;              // SB
    uintptr_t kp = (uintptr_t)(bsum1 + SB);
    kp = (kp + 15) & ~(uintptr_t)15;
    float2* w0 = (float2*)kp;                       // E float2
    float2* w1 = w0 + EEDGES;                       // E float2
    unsigned short* pwT_b = (unsigned short*)(w1 + EEDGES);  // 128*128 bf16
    unsigned short* kwT_b = pwT_b + CDIM * CDIM;
    unsigned short* Hb    = kwT_b + CDIM * CDIM;    // N*C bf16
    unsigned short* O0b   = Hb + nc;
    unsigned short* O1b   = O0b + nc;
    unsigned short* Ab    = O1b + nc;

    // ---- build CSR for both edge types (structure reused across layers) ----
    const int gE = (EEDGES + 255) / 256;
    hipMemsetAsync(deg0, 0, 2 * NNODES * sizeof(int), stream);
    hist_dual<<<2 * gE, 256, 0, stream>>>(ei_spatial + EEDGES, deg0,
                                          ei_similar + EEDGES, deg1, gE);
    scan_partial_dual<<<2 * SB, 256, 0, stream>>>(deg0, bsum0, deg1, bsum1);
    scan_bsum_dual<<<1, 64, 0, stream>>>(bsum0, bsum1);
    scan_final_dual<<<2 * SB, 256, 0, stream>>>(deg0, bsum0, rowptr0, deg1, bsum1, rowptr1);
    hipMemcpyAsync(cursor0, rowptr0, 2 * (NNODES + 1) * sizeof(int),
                   hipMemcpyDeviceToDevice, stream);
    fill_dual<<<2 * gE, 256, 0, stream>>>(ei_spatial, ei_spatial + EEDGES, cursor0, cs0, cd0,
                                          ei_similar, ei_similar + EEDGES, cursor1, cs1, cd1, gE);

    Graph g = {rowptr0, cs0, cd0, rowptr1, cs1, cd1, w0, w1};

    // Layer 1: proj(x f32)->Hb ; edge_w ; seg->O0b,O1b ; combine->Ab (bf16)
    run_layer(x, FIN, p1_proj_w, p1_proj_b, p1_att_src, p1_att_dst,
              p1_q, p1_kw, p1_kb, g,
              Hb, O0b, O1b, Ab, asrc, adst, sacc, attn, pwT_b, kwT_b, stream);

    // Layer 2: proj(Ab bf16)->Hb ; edge_w ; seg->O0b,O1b ; combine->Ab
    run_layer(Ab, CDIM, p2_proj_w, p2_proj_b, p2_att_src, p2_att_dst,
              p2_q, p2_kw, p2_kb, g,
              Hb, O0b, O1b, Ab, asrc, adst, sacc, attn, pwT_b, kwT_b, stream);

    // Final classifier (bf16 input)
    const int gfin = (NNODES * FOUT + 255) / 256;
    final_linear_kernel<<<gfin, 256, 0, stream>>>(Ab, lin_w, lin_b, (float*)d_out);
}

// Round 13
// 519.813 us; speedup vs baseline: 5.8177x; 1.0200x over previous
//
#include <hip/hip_runtime.h>

#define NNODES 100000
#define EEDGES 600000
#define CDIM 128
#define HHEADS 2
#define DDIM 64
#define FIN 64
#define FOUT 8
#define NEG 0.2f

#define SB 200    // scan blocks
#define SCH 500   // nodes per scan block (200*500 = 100000 exactly)
#define SNB 384   // persistent score blocks per edge type

typedef short bf16x8 __attribute__((ext_vector_type(8)));
typedef unsigned short ushort8 __attribute__((ext_vector_type(8)));
typedef float f32x4 __attribute__((ext_vector_type(4)));

__device__ __forceinline__ float tanh_fast(float x) {
    float e = __expf(2.f * x);
    return 1.f - 2.f / (e + 1.f);
}

__device__ __forceinline__ unsigned short f2bf(float x) {
    unsigned int u = __float_as_uint(x);
    unsigned int r = (u + 0x7FFFu + ((u >> 16) & 1u)) >> 16;  // RNE
    return (unsigned short)r;
}
__device__ __forceinline__ float bf2f(unsigned short u) {
    return __uint_as_float(((unsigned int)u) << 16);
}
__device__ __forceinline__ float bfrelu2f(unsigned short u) {
    return (u & 0x8000) ? 0.f : __uint_as_float(((unsigned int)u) << 16);
}

// ---- both weights -> transposed bf16, one launch per layer ----
template<int K>
__global__ __launch_bounds__(256)
void cvt_wT2(const float* __restrict__ pw, const float* __restrict__ kw,
             unsigned short* __restrict__ pwT, unsigned short* __restrict__ kwT) {
    int idx = blockIdx.x * 256 + threadIdx.x;
    if (idx < K * CDIM) {
        int c = idx / K, k = idx % K;
        pwT[idx] = f2bf(pw[k * CDIM + c]);
    } else if (idx < (K + CDIM) * CDIM) {
        int j = idx - K * CDIM;
        int c = j >> 7, k = j & 127;
        kwT[j] = f2bf(kw[k * CDIM + c]);
    }
}

// ============ projection via MFMA: H = bf16(X@W + b), fused attention dots ============
// MODE 0: X f32 (layer 1). MODE 2: X = a0*relu(O0)+a1*relu(O1) combine (layer 2).
template<int K, int MODE>
__global__ __launch_bounds__(256)
void proj_mfma(const void* __restrict__ Xv, const void* __restrict__ Xv2,
               const float* __restrict__ attnp,
               const unsigned short* __restrict__ pwT_b,
               const float* __restrict__ bias,
               const float* __restrict__ att_src, const float* __restrict__ att_dst,
               unsigned short* __restrict__ Hout,
               float* __restrict__ a_src, float* __restrict__ a_dst) {
    const int U = K / 8;
    __shared__ ushort8 smem[192 * (K / 8)];   // As8 [64][U] + Bs8 [128][U]
    ushort8* As8 = smem;
    ushort8* Bs8 = smem + 64 * U;
    int tid = threadIdx.x;
    int row0 = blockIdx.x * 64;
    float fa0 = 0.f, fa1 = 0.f;
    if (MODE == 2) { fa0 = attnp[0]; fa1 = attnp[1]; }

#pragma unroll
    for (int i = 0; i < (64 * U) / 256; ++i) {
        int idx = tid + i * 256;
        int row = idx / U, u = idx % U;
        int grow = row0 + row;
        ushort8 v;
        if (grow < NNODES) {
            if (MODE == 2) {
                ushort8 v0 = ((const ushort8*)Xv)[(long)grow * U + u];
                ushort8 v1 = ((const ushort8*)Xv2)[(long)grow * U + u];
#pragma unroll
                for (int e = 0; e < 8; ++e)
                    v[e] = f2bf(fa0 * bfrelu2f(v0[e]) + fa1 * bfrelu2f(v1[e]));
            } else {
                const float* p = (const float*)Xv + (long)grow * K + u * 8;
                float4 a = *(const float4*)p;
                float4 b = *(const float4*)(p + 4);
                v[0] = f2bf(a.x); v[1] = f2bf(a.y); v[2] = f2bf(a.z); v[3] = f2bf(a.w);
                v[4] = f2bf(b.x); v[5] = f2bf(b.y); v[6] = f2bf(b.z); v[7] = f2bf(b.w);
            }
        } else v = (ushort8)0;
        As8[row * U + (u ^ (row & 7))] = v;
    }
#pragma unroll
    for (int i = 0; i < (128 * U) / 256; ++i) {
        int idx = tid + i * 256;
        int c = idx / U, u = idx % U;
        Bs8[c * U + (u ^ (c & 7))] = ((const ushort8*)pwT_b)[idx];
    }
    __syncthreads();

    int l = tid & 63, w = tid >> 6;
    int lrow = w * 16 + (l & 15);
    int ug = l >> 4;
    f32x4 acc[8];
#pragma unroll
    for (int ct = 0; ct < 8; ++ct) acc[ct] = (f32x4)0.f;

#pragma unroll
    for (int kc = 0; kc < K / 32; ++kc) {
        int u = kc * 4 + ug;
        bf16x8 af = *(const bf16x8*)&As8[lrow * U + (u ^ (lrow & 7))];
#pragma unroll
        for (int ct = 0; ct < 8; ++ct) {
            int c = ct * 16 + (l & 15);
            bf16x8 bf = *(const bf16x8*)&Bs8[c * U + (u ^ (c & 7))];
            acc[ct] = __builtin_amdgcn_mfma_f32_16x16x32_bf16(af, bf, acc[ct], 0, 0, 0);
        }
    }

    __syncthreads();
    unsigned short* Cs = (unsigned short*)smem;  // [64][128]
#pragma unroll
    for (int ct = 0; ct < 8; ++ct) {
        int c = ct * 16 + (l & 15);
        float bc = bias[c];
#pragma unroll
        for (int v = 0; v < 4; ++v) {
            int rr = w * 16 + (l >> 4) * 4 + v;
            Cs[rr * 128 + c] = f2bf(acc[ct][v] + bc);
        }
    }
    __syncthreads();

    int r = tid >> 2, q = tid & 3;
    int grow = row0 + r;
    if (grow < NNODES) {
        float h[32];
        ushort8 hv[4];
#pragma unroll
        for (int j = 0; j < 4; ++j) {
            hv[j] = *(ushort8*)&Cs[r * 128 + q * 32 + j * 8];
#pragma unroll
            for (int e = 0; e < 8; ++e) h[j * 8 + e] = bf2f(hv[j][e]);
        }
#pragma unroll
        for (int j = 0; j < 4; ++j)
            *(ushort8*)(Hout + (long)grow * CDIM + q * 32 + j * 8) = hv[j];
#pragma unroll
        for (int i = 0; i < 2; ++i) {
            float s = 0.f, d = 0.f;
#pragma unroll
            for (int j = 0; j < 32; ++j) {
                s = fmaf(h[j], att_src[i * CDIM + q * 32 + j], s);
                d = fmaf(h[j], att_dst[i * CDIM + q * 32 + j], d);
            }
            s += __shfl_xor(s, 1, 64);
            d += __shfl_xor(d, 1, 64);
            if ((q & 1) == 0) {
                int hh = q >> 1;
                long base = (long)i * NNODES * HHEADS + (long)grow * HHEADS + hh;
                a_src[base] = s;
                a_dst[base] = d;
            }
        }
    }
}

// ---- semantic score via MFMA: persistent blocks, kw staged ONCE ----
__global__ __launch_bounds__(256, 3)
void score_mfma_dual(const unsigned short* __restrict__ O0b,
                     const unsigned short* __restrict__ O1b,
                     const unsigned short* __restrict__ kwT_b,
                     const float* __restrict__ kb, const float* __restrict__ q,
                     float* __restrict__ sacc) {
    __shared__ ushort8 As8[64 * 16];    // 16 KB
    __shared__ ushort8 Bs8[128 * 16];   // 32 KB
    __shared__ float red[4];
    const int NT = (NNODES + 63) / 64;  // 1563 row tiles
    int bid = blockIdx.x;
    int type = bid >= SNB;
    const unsigned short* Omb = type ? O1b : O0b;
    int bt = bid - (type ? SNB : 0);
    int tid = threadIdx.x;

#pragma unroll
    for (int i = 0; i < 8; ++i) {
        int idx = tid + i * 256;
        int c = idx >> 4, u = idx & 15;
        Bs8[c * 16 + (u ^ (c & 7))] = ((const ushort8*)kwT_b)[idx];
    }

    int l = tid & 63, w = tid >> 6;
    int lrow = w * 16 + (l & 15);
    int ug = l >> 4;
    float s = 0.f;

    ushort8 pre[4];
    {
        int row0 = bt * 64;
#pragma unroll
        for (int i = 0; i < 4; ++i) {
            int idx = tid + i * 256;
            int row = idx >> 4, u = idx & 15;
            int grow = row0 + row;
            ushort8 v = (ushort8)0;
            if (bt < NT && grow < NNODES) {
                v = ((const ushort8*)Omb)[(long)grow * 16 + u];
#pragma unroll
                for (int e = 0; e < 8; ++e) v[e] = (v[e] & 0x8000) ? 0 : v[e];  // relu
            }
            pre[i] = v;
        }
    }

    for (int t = bt; t < NT; t += SNB) {
        __syncthreads();
#pragma unroll
        for (int i = 0; i < 4; ++i) {
            int idx = tid + i * 256;
            int row = idx >> 4, u = idx & 15;
            As8[row * 16 + (u ^ (row & 7))] = pre[i];
        }
        int tn = t + SNB;
        if (tn < NT) {
            int row0n = tn * 64;
#pragma unroll
            for (int i = 0; i < 4; ++i) {
                int idx = tid + i * 256;
                int row = idx >> 4, u = idx & 15;
                int grow = row0n + row;
                ushort8 v = (ushort8)0;
                if (grow < NNODES) {
                    v = ((const ushort8*)Omb)[(long)grow * 16 + u];
#pragma unroll
                    for (int e = 0; e < 8; ++e) v[e] = (v[e] & 0x8000) ? 0 : v[e];
                }
                pre[i] = v;
            }
        }
        __syncthreads();

        f32x4 acc[8];
#pragma unroll
        for (int ct = 0; ct < 8; ++ct) acc[ct] = (f32x4)0.f;
#pragma unroll
        for (int kc = 0; kc < 4; ++kc) {
            int u = kc * 4 + ug;
            bf16x8 af = *(const bf16x8*)&As8[lrow * 16 + (u ^ (lrow & 7))];
#pragma unroll
            for (int ct = 0; ct < 8; ++ct) {
                int c = ct * 16 + (l & 15);
                bf16x8 bf = *(const bf16x8*)&Bs8[c * 16 + (u ^ (c & 7))];
                acc[ct] = __builtin_amdgcn_mfma_f32_16x16x32_bf16(af, bf, acc[ct], 0, 0, 0);
            }
        }
        int row0 = t * 64;
#pragma unroll
        for (int ct = 0; ct < 8; ++ct) {
            int c = ct * 16 + (l & 15);
            float qc = q[c], kbc = kb[c];
#pragma unroll
            for (int v = 0; v < 4; ++v) {
                int grow = row0 + w * 16 + (l >> 4) * 4 + v;
                if (grow < NNODES) s += qc * tanh_fast(acc[ct][v] + kbc);
            }
        }
    }

#pragma unroll
    for (int m = 32; m >= 1; m >>= 1) s += __shfl_xor(s, m, 64);
    if (l == 0) red[w] = s;
    __syncthreads();
    if (tid == 0) atomicAdd(sacc + type, red[0] + red[1] + red[2] + red[3]);
}

// ============ CSR build (dual-type fused) ============
__global__ void hist_dual(const int* __restrict__ dst0, int* __restrict__ deg0,
                          const int* __restrict__ dst1, int* __restrict__ deg1, int gE) {
    int bid = blockIdx.x;
    int type = bid >= gE;
    const int* dst = type ? dst1 : dst0;
    int* deg = type ? deg1 : deg0;
    int e = (bid - (type ? gE : 0)) * 256 + threadIdx.x;
    if (e < EEDGES) atomicAdd(&deg[dst[e]], 1);
}

__global__ __launch_bounds__(256)
void scan_partial_dual(const int* __restrict__ deg0, int* __restrict__ bsum0,
                       const int* __restrict__ deg1, int* __restrict__ bsum1) {
    __shared__ int red[256];
    int bid = blockIdx.x;
    int type = bid >= SB;
    const int* deg = type ? deg1 : deg0;
    int* bsum = type ? bsum1 : bsum0;
    int b = bid - (type ? SB : 0), t = threadIdx.x;
    int s = 0;
    if (t < 250) {
        int base = b * SCH + t * 2;
        s = deg[base] + deg[base + 1];
    }
    red[t] = s;
    __syncthreads();
#pragma unroll
    for (int off = 128; off >= 1; off >>= 1) {
        if (t < off) red[t] += red[t + off];
        __syncthreads();
    }
    if (t == 0) bsum[b] = red[0];
}

__global__ void scan_bsum_dual(int* __restrict__ bsum0, int* __restrict__ bsum1) {
    int t = threadIdx.x;
    if (t < 2) {
        int* bsum = t ? bsum1 : bsum0;
        int run = 0;
        for (int i = 0; i < SB; ++i) { int v = bsum[i]; bsum[i] = run; run += v; }
    }
}

__global__ __launch_bounds__(256)
void scan_final_dual(const int* __restrict__ deg0, const int* __restrict__ bsum0,
                     int* __restrict__ rowptr0,
                     const int* __restrict__ deg1, const int* __restrict__ bsum1,
                     int* __restrict__ rowptr1) {
    __shared__ int ts[256];
    int bid = blockIdx.x;
    int type = bid >= SB;
    const int* deg = type ? deg1 : deg0;
    const int* bsum = type ? bsum1 : bsum0;
    int* rowptr = type ? rowptr1 : rowptr0;
    int b = bid - (type ? SB : 0), t = threadIdx.x;
    int d0 = 0, d1 = 0;
    int base = b * SCH + t * 2;
    if (t < 250) { d0 = deg[base]; d1 = deg[base + 1]; }
    ts[t] = d0 + d1;
    __syncthreads();
#pragma unroll
    for (int off = 1; off < 256; off <<= 1) {
        int v = (t >= off) ? ts[t - off] : 0;
        __syncthreads();
        ts[t] += v;
        __syncthreads();
    }
    if (t < 250) {
        int excl = bsum[b] + (t > 0 ? ts[t - 1] : 0);
        rowptr[base] = excl;
        rowptr[base + 1] = excl + d0;
    }
    if (b == 0 && t == 0) rowptr[NNODES] = EEDGES;
}

__global__ void fill_dual(const int* __restrict__ src0, const int* __restrict__ dst0,
                          int* __restrict__ cur0, int* __restrict__ cs0,
                          const int* __restrict__ src1, const int* __restrict__ dst1,
                          int* __restrict__ cur1, int* __restrict__ cs1, int gE) {
    int bid = blockIdx.x;
    int type = bid >= gE;
    const int* src = type ? src1 : src0;
    const int* dst = type ? dst1 : dst0;
    int* cursor = type ? cur1 : cur0;
    int* csr_src = type ? cs1 : cs0;
    int e = (bid - (type ? gE : 0)) * 256 + threadIdx.x;
    if (e < EEDGES) {
        int pos = atomicAdd(&cursor[dst[e]], 1);
        csr_src[pos] = src[e];
    }
}

// ============ single-pass aggregation v3: fused edge weights + LDS edge records ============
// Staging (lane-parallel): lane i computes edge base+i's softmax weight (exp(leaky(..)))
// once and stores {src,wx},{src,wy} records in per-wave LDS. Consumers (lanes 0-31 even
// edges, 32-63 odd edges; lane covers 4 channels) read one 8B broadcast ds_read per edge.
__global__ __launch_bounds__(256)
void seg_aggregate_dual(const int* __restrict__ rp0, const int* __restrict__ cs0,
                        const float* __restrict__ as0, const float* __restrict__ ad0,
                        unsigned short* __restrict__ O0,
                        const int* __restrict__ rp1, const int* __restrict__ cs1,
                        const float* __restrict__ as1, const float* __restrict__ ad1,
                        unsigned short* __restrict__ O1,
                        const unsigned short* __restrict__ Hfeat, int gseg) {
    __shared__ uint4 erec[4 * 64];   // per-wave 64 edge records: {src, wx, src, wy}
    int bid = blockIdx.x;
    int type = bid >= gseg;
    const int* rowptr = type ? rp1 : rp0;
    const int* csr_src = type ? cs1 : cs0;
    const float* asv = type ? as1 : as0;
    const float* adv = type ? ad1 : ad0;
    unsigned short* Out = type ? O1 : O0;
    int wid = threadIdx.x >> 6;
    int node = (bid - (type ? gseg : 0)) * 4 + wid;
    if (node >= NNODES) return;
    int lane = threadIdx.x & 63;
    int cl = lane & 31, eg = lane >> 5;
    int start = rowptr[node], end = rowptr[node + 1];
    int deg = end - start;
    float2 adn = *(const float2*)(adv + node * 2);
    const uint2* lds2 = (const uint2*)&erec[wid * 64];
    int hsel = cl >> 4;   // 0: head0 (channels 0-63), 1: head1

    float a0 = 0.f, a1 = 0.f, a2 = 0.f, a3 = 0.f;
    float s0 = 0.f, s1 = 0.f;
    for (int base = 0; base < deg; base += 64) {
        int n = deg - base; if (n > 64) n = 64;
        int sA = 0; float wx = 0.f, wy = 0.f;
        if (lane < n) {
            sA = csr_src[start + base + lane];
            float2 av = *(const float2*)(asv + sA * 2);
            float r0 = av.x + adn.x; r0 = r0 >= 0.f ? r0 : NEG * r0;
            float r1 = av.y + adn.y; r1 = r1 >= 0.f ? r1 : NEG * r1;
            wx = __expf(r0); wy = __expf(r1);
        }
        s0 += wx; s1 += wy;
        erec[wid * 64 + lane] = make_uint4((unsigned int)sA, __float_as_uint(wx),
                                           (unsigned int)sA, __float_as_uint(wy));
        __builtin_amdgcn_wave_barrier();  // DS ops are in-order per wave; pin schedule
        for (int e0 = 0; e0 < n; e0 += 4) {
            int eA = e0 + eg;
            uint2 rA = lds2[eA * 2 + hsel];
            float wA = __uint_as_float(rA.y);
            uint2 hA = *(const uint2*)(Hfeat + (long)(int)rA.x * CDIM + cl * 4);
            a0 = fmaf(bf2f((unsigned short)hA.x), wA, a0);
            a1 = fmaf(bf2f((unsigned short)(hA.x >> 16)), wA, a1);
            a2 = fmaf(bf2f((unsigned short)hA.y), wA, a2);
            a3 = fmaf(bf2f((unsigned short)(hA.y >> 16)), wA, a3);
            if (e0 + 2 < n) {  // wave-uniform
                int eB = e0 + 2 + eg;
                uint2 rB = lds2[eB * 2 + hsel];
                float wB = __uint_as_float(rB.y);
                uint2 hB = *(const uint2*)(Hfeat + (long)(int)rB.x * CDIM + cl * 4);
                a0 = fmaf(bf2f((unsigned short)hB.x), wB, a0);
                a1 = fmaf(bf2f((unsigned short)(hB.x >> 16)), wB, a1);
                a2 = fmaf(bf2f((unsigned short)hB.y), wB, a2);
                a3 = fmaf(bf2f((unsigned short)(hB.y >> 16)), wB, a3);
            }
        }
        __builtin_amdgcn_wave_barrier();  // all reads done before next chunk's writes
    }
#pragma unroll
    for (int m = 32; m >= 1; m >>= 1) {
        s0 += __shfl_xor(s0, m, 64);
        s1 += __shfl_xor(s1, m, 64);
    }
    a0 += __shfl_xor(a0, 32, 64);
    a1 += __shfl_xor(a1, 32, 64);
    a2 += __shfl_xor(a2, 32, 64);
    a3 += __shfl_xor(a3, 32, 64);
    if (lane < 32) {
        float ssel = lane < 16 ? s0 : s1;
        float inv = ssel > 0.f ? 1.f / ssel : 0.f;
        uint2 o;
        o.x = (unsigned int)f2bf(a0 * inv) | ((unsigned int)f2bf(a1 * inv) << 16);
        o.y = (unsigned int)f2bf(a2 * inv) | ((unsigned int)f2bf(a3 * inv) << 16);
        *(uint2*)(Out + (long)node * CDIM + lane * 4) = o;
    }
}

__global__ void attn_finalize_kernel(const float* __restrict__ sacc, float* __restrict__ attn) {
    float s0 = sacc[0] / (float)NNODES;
    float s1 = sacc[1] / (float)NNODES;
    float m = fmaxf(s0, s1);
    float e0 = expf(s0 - m), e1 = expf(s1 - m);
    float inv = 1.f / (e0 + e1);
    attn[0] = e0 * inv;
    attn[1] = e1 * inv;
}

// ---- final classifier with fused semantic combine (layer 2) ----
__global__ __launch_bounds__(256)
void final_linear_kernel(const unsigned short* __restrict__ O0,
                         const unsigned short* __restrict__ O1,
                         const float* __restrict__ attnp,
                         const float* __restrict__ lw, const float* __restrict__ lb,
                         float* __restrict__ out) {
    __shared__ float lws[CDIM * FOUT];
    int tid = threadIdx.x;
    for (int i = tid; i < CDIM * FOUT; i += 256) lws[i] = lw[i];
    __syncthreads();
    float fa0 = attnp[0], fa1 = attnp[1];
    int idx = blockIdx.x * 256 + tid;
    if (idx >= NNODES * FOUT) return;
    int n = idx >> 3, o = idx & 7;
    const ushort8* r0 = (const ushort8*)(O0 + (long)n * CDIM);
    const ushort8* r1 = (const ushort8*)(O1 + (long)n * CDIM);
    float acc = lb[o];
#pragma unroll
    for (int k8 = 0; k8 < 16; ++k8) {
        ushort8 v0 = r0[k8];
        ushort8 v1 = r1[k8];
#pragma unroll
        for (int e = 0; e < 8; ++e) {
            float hv = fa0 * bfrelu2f(v0[e]) + fa1 * bfrelu2f(v1[e]);
            acc = fmaf(hv, lws[(k8 * 8 + e) * FOUT + o], acc);
        }
    }
    out[idx] = acc;
}

extern "C" void kernel_launch(void* const* d_in, const int* in_sizes, int n_in,
                              void* d_out, int out_size, void* d_ws, size_t ws_size,
                              hipStream_t stream) {
    const float* x          = (const float*)d_in[0];
    const int*   ei_spatial = (const int*)d_in[1];
    const int*   ei_similar = (const int*)d_in[2];
    const float* p1_proj_w  = (const float*)d_in[3];
    const float* p1_proj_b  = (const float*)d_in[4];
    const float* p1_att_src = (const float*)d_in[5];
    const float* p1_att_dst = (const float*)d_in[6];
    const float* p1_q       = (const float*)d_in[7];
    const float* p1_kw      = (const float*)d_in[8];
    const float* p1_kb      = (const float*)d_in[9];
    const float* p2_proj_w  = (const float*)d_in[10];
    const float* p2_proj_b  = (const float*)d_in[11];
    const float* p2_att_src = (const float*)d_in[12];
    const float* p2_att_dst = (const float*)d_in[13];
    const float* p2_q       = (const float*)d_in[14];
    const float* p2_kw      = (const float*)d_in[15];
    const float* p2_kb      = (const float*)d_in[16];
    const float* lin_w      = (const float*)d_in[17];
    const float* lin_b      = (const float*)d_in[18];

    float* ws = (float*)d_ws;
    const size_t nc = (size_t)NNODES * CDIM;
    const size_t nh2 = (size_t)NNODES * HHEADS;

    float* asrc = ws;                    // 2*N*H
    float* adst = asrc + 2 * nh2;        // 2*N*H
    float* sacc = adst + 2 * nh2;        // 2
    float* attn = sacc + 2;              // 2
    int* rowptr0 = (int*)(attn + 2);     // N+1
    int* rowptr1 = rowptr0 + (NNODES + 1);
    int* cursor0 = rowptr1 + (NNODES + 1);  // N+1 (contiguous with cursor1)
    int* cursor1 = cursor0 + (NNODES + 1);
    int* cs0     = cursor1 + (NNODES + 1);  // E
    int* cs1     = cs0 + EEDGES;            // E
    int* deg0    = cs1 + EEDGES;            // N (deg0/deg1 contiguous for one memset)
    int* deg1    = deg0 + NNODES;           // N
    int* bsum0   = deg1 + NNODES;           // SB
    int* bsum1   = bsum0 + SB;              // SB
    uintptr_t kp = (uintptr_t)(bsum1 + SB);
    kp = (kp + 15) & ~(uintptr_t)15;
    unsigned short* pwT_b = (unsigned short*)kp;    // 128*128 bf16
    unsigned short* kwT_b = pwT_b + CDIM * CDIM;
    unsigned short* Hb    = kwT_b + CDIM * CDIM;    // N*C bf16
    unsigned short* O0b   = Hb + nc;
    unsigned short* O1b   = O0b + nc;

    const int gE = (EEDGES + 255) / 256;
    const int gm = (NNODES + 63) / 64;      // 1563
    const int gseg = (NNODES + 3) / 4;
    const int nh = NNODES * HHEADS;

    // ---- build CSR for both edge types (structure reused across layers) ----
    hipMemsetAsync(deg0, 0, 2 * NNODES * sizeof(int), stream);
    hist_dual<<<2 * gE, 256, 0, stream>>>(ei_spatial + EEDGES, deg0,
                                          ei_similar + EEDGES, deg1, gE);
    scan_partial_dual<<<2 * SB, 256, 0, stream>>>(deg0, bsum0, deg1, bsum1);
    scan_bsum_dual<<<1, 64, 0, stream>>>(bsum0, bsum1);
    scan_final_dual<<<2 * SB, 256, 0, stream>>>(deg0, bsum0, rowptr0, deg1, bsum1, rowptr1);
    hipMemcpyAsync(cursor0, rowptr0, 2 * (NNODES + 1) * sizeof(int),
                   hipMemcpyDeviceToDevice, stream);
    fill_dual<<<2 * gE, 256, 0, stream>>>(ei_spatial, ei_spatial + EEDGES, cursor0, cs0,
                                          ei_similar, ei_similar + EEDGES, cursor1, cs1, gE);

    // ================= Layer 1 =================
    cvt_wT2<FIN><<<((FIN + CDIM) * CDIM + 255) / 256, 256, 0, stream>>>(
        p1_proj_w, p1_kw, pwT_b, kwT_b);
    proj_mfma<FIN, 0><<<gm, 256, 0, stream>>>(x, nullptr, nullptr, pwT_b, p1_proj_b,
                                              p1_att_src, p1_att_dst, Hb, asrc, adst);
    seg_aggregate_dual<<<2 * gseg, 256, 0, stream>>>(
        rowptr0, cs0, asrc, adst, O0b,
        rowptr1, cs1, asrc + nh, adst + nh, O1b, Hb, gseg);
    hipMemsetAsync(sacc, 0, 2 * sizeof(float), stream);
    score_mfma_dual<<<2 * SNB, 256, 0, stream>>>(O0b, O1b, kwT_b, p1_kb, p1_q, sacc);
    attn_finalize_kernel<<<1, 1, 0, stream>>>(sacc, attn);

    // ================= Layer 2 (combine fused into proj staging) =================
    cvt_wT2<CDIM><<<((CDIM + CDIM) * CDIM + 255) / 256, 256, 0, stream>>>(
        p2_proj_w, p2_kw, pwT_b, kwT_b);
    proj_mfma<CDIM, 2><<<gm, 256, 0, stream>>>(O0b, O1b, attn, pwT_b, p2_proj_b,
                                               p2_att_src, p2_att_dst, Hb, asrc, adst);
    seg_aggregate_dual<<<2 * gseg, 256, 0, stream>>>(
        rowptr0, cs0, asrc, adst, O0b,
        rowptr1, cs1, asrc + nh, adst + nh, O1b, Hb, gseg);
    hipMemsetAsync(sacc, 0, 2 * sizeof(float), stream);
    score_mfma_dual<<<2 * SNB, 256, 0, stream>>>(O0b, O1b, kwT_b, p2_kb, p2_q, sacc);
    attn_finalize_kernel<<<1, 1, 0, stream>>>(sacc, attn);

    // ================= Final classifier (combine fused) =================
    const int gfin = (NNODES * FOUT + 255) / 256;
    final_linear_kernel<<<gfin, 256, 0, stream>>>(O0b, O1b, attn, lin_w, lin_b,
                                                  (float*)d_out);
}

// Round 14
// 513.963 us; speedup vs baseline: 5.8840x; 1.0114x over previous
//
#include <hip/hip_runtime.h>

#define NNODES 100000
#define EEDGES 600000
#define CDIM 128
#define HHEADS 2
#define DDIM 64
#define FIN 64
#define FOUT 8
#define NEG 0.2f

#define SB 200    // scan blocks
#define SCH 500   // nodes per scan block (200*500 = 100000 exactly)
#define SNB 384   // persistent score blocks per edge type

typedef short bf16x8 __attribute__((ext_vector_type(8)));
typedef unsigned short ushort8 __attribute__((ext_vector_type(8)));
typedef float f32x4 __attribute__((ext_vector_type(4)));

__device__ __forceinline__ float tanh_fast(float x) {
    float e = __expf(2.f * x);
    return 1.f - 2.f / (e + 1.f);
}

__device__ __forceinline__ unsigned short f2bf(float x) {
    unsigned int u = __float_as_uint(x);
    unsigned int r = (u + 0x7FFFu + ((u >> 16) & 1u)) >> 16;  // RNE
    return (unsigned short)r;
}
__device__ __forceinline__ float bf2f(unsigned short u) {
    return __uint_as_float(((unsigned int)u) << 16);
}
__device__ __forceinline__ float bfrelu2f(unsigned short u) {
    return (u & 0x8000) ? 0.f : __uint_as_float(((unsigned int)u) << 16);
}

// 2-way semantic softmax from raw score sums (recomputed inline by consumers)
__device__ __forceinline__ void attn_from_sacc(const float* saccp, float& fa0, float& fa1) {
    float s0 = saccp[0] / (float)NNODES;
    float s1 = saccp[1] / (float)NNODES;
    float m = fmaxf(s0, s1);
    float e0 = expf(s0 - m), e1 = expf(s1 - m);
    float inv = 1.f / (e0 + e1);
    fa0 = e0 * inv; fa1 = e1 * inv;
}

// ---- ALL weight transposes (both layers) in one launch; also zeroes sacc[0..4) ----
__global__ __launch_bounds__(256)
void cvt_all(const float* __restrict__ p1w, const float* __restrict__ k1w,
             const float* __restrict__ p2w, const float* __restrict__ k2w,
             unsigned short* __restrict__ p1T, unsigned short* __restrict__ k1T,
             unsigned short* __restrict__ p2T, unsigned short* __restrict__ k2T,
             float* __restrict__ sacc) {
    int idx = blockIdx.x * 256 + threadIdx.x;
    if (blockIdx.x == 0 && threadIdx.x < 4) sacc[threadIdx.x] = 0.f;
    if (idx < FIN * CDIM) {                    // p1: [k][c] -> [c*FIN+k]
        int c = idx / FIN, k = idx % FIN;
        p1T[idx] = f2bf(p1w[k * CDIM + c]);
    } else if (idx < (FIN + CDIM) * CDIM) {    // k1
        int j = idx - FIN * CDIM;
        int c = j >> 7, k = j & 127;
        k1T[j] = f2bf(k1w[k * CDIM + c]);
    } else if (idx < (FIN + 2 * CDIM) * CDIM) { // p2
        int j = idx - (FIN + CDIM) * CDIM;
        int c = j >> 7, k = j & 127;
        p2T[j] = f2bf(p2w[k * CDIM + c]);
    } else if (idx < (FIN + 3 * CDIM) * CDIM) { // k2
        int j = idx - (FIN + 2 * CDIM) * CDIM;
        int c = j >> 7, k = j & 127;
        k2T[j] = f2bf(k2w[k * CDIM + c]);
    }
}

// ============ projection via MFMA: H = bf16(X@W + b), fused attention dots ============
// MODE 0: X f32 (layer 1). MODE 2: X = a0*relu(O0)+a1*relu(O1), attn from sacc (layer 2).
template<int K, int MODE>
__global__ __launch_bounds__(256)
void proj_mfma(const void* __restrict__ Xv, const void* __restrict__ Xv2,
               const float* __restrict__ saccp,
               const unsigned short* __restrict__ pwT_b,
               const float* __restrict__ bias,
               const float* __restrict__ att_src, const float* __restrict__ att_dst,
               unsigned short* __restrict__ Hout,
               float* __restrict__ a_src, float* __restrict__ a_dst) {
    const int U = K / 8;
    __shared__ ushort8 smem[192 * (K / 8)];   // As8 [64][U] + Bs8 [128][U]
    ushort8* As8 = smem;
    ushort8* Bs8 = smem + 64 * U;
    int tid = threadIdx.x;
    int row0 = blockIdx.x * 64;
    float fa0 = 0.f, fa1 = 0.f;
    if (MODE == 2) attn_from_sacc(saccp, fa0, fa1);

#pragma unroll
    for (int i = 0; i < (64 * U) / 256; ++i) {
        int idx = tid + i * 256;
        int row = idx / U, u = idx % U;
        int grow = row0 + row;
        ushort8 v;
        if (grow < NNODES) {
            if (MODE == 2) {
                ushort8 v0 = ((const ushort8*)Xv)[(long)grow * U + u];
                ushort8 v1 = ((const ushort8*)Xv2)[(long)grow * U + u];
#pragma unroll
                for (int e = 0; e < 8; ++e)
                    v[e] = f2bf(fa0 * bfrelu2f(v0[e]) + fa1 * bfrelu2f(v1[e]));
            } else {
                const float* p = (const float*)Xv + (long)grow * K + u * 8;
                float4 a = *(const float4*)p;
                float4 b = *(const float4*)(p + 4);
                v[0] = f2bf(a.x); v[1] = f2bf(a.y); v[2] = f2bf(a.z); v[3] = f2bf(a.w);
                v[4] = f2bf(b.x); v[5] = f2bf(b.y); v[6] = f2bf(b.z); v[7] = f2bf(b.w);
            }
        } else v = (ushort8)0;
        As8[row * U + (u ^ (row & 7))] = v;
    }
#pragma unroll
    for (int i = 0; i < (128 * U) / 256; ++i) {
        int idx = tid + i * 256;
        int c = idx / U, u = idx % U;
        Bs8[c * U + (u ^ (c & 7))] = ((const ushort8*)pwT_b)[idx];
    }
    __syncthreads();

    int l = tid & 63, w = tid >> 6;
    int lrow = w * 16 + (l & 15);
    int ug = l >> 4;
    f32x4 acc[8];
#pragma unroll
    for (int ct = 0; ct < 8; ++ct) acc[ct] = (f32x4)0.f;

#pragma unroll
    for (int kc = 0; kc < K / 32; ++kc) {
        int u = kc * 4 + ug;
        bf16x8 af = *(const bf16x8*)&As8[lrow * U + (u ^ (lrow & 7))];
#pragma unroll
        for (int ct = 0; ct < 8; ++ct) {
            int c = ct * 16 + (l & 15);
            bf16x8 bf = *(const bf16x8*)&Bs8[c * U + (u ^ (c & 7))];
            acc[ct] = __builtin_amdgcn_mfma_f32_16x16x32_bf16(af, bf, acc[ct], 0, 0, 0);
        }
    }

    __syncthreads();
    unsigned short* Cs = (unsigned short*)smem;  // [64][128]
#pragma unroll
    for (int ct = 0; ct < 8; ++ct) {
        int c = ct * 16 + (l & 15);
        float bc = bias[c];
#pragma unroll
        for (int v = 0; v < 4; ++v) {
            int rr = w * 16 + (l >> 4) * 4 + v;
            Cs[rr * 128 + c] = f2bf(acc[ct][v] + bc);
        }
    }
    __syncthreads();

    int r = tid >> 2, q = tid & 3;
    int grow = row0 + r;
    if (grow < NNODES) {
        float h[32];
        ushort8 hv[4];
#pragma unroll
        for (int j = 0; j < 4; ++j) {
            hv[j] = *(ushort8*)&Cs[r * 128 + q * 32 + j * 8];
#pragma unroll
            for (int e = 0; e < 8; ++e) h[j * 8 + e] = bf2f(hv[j][e]);
        }
#pragma unroll
        for (int j = 0; j < 4; ++j)
            *(ushort8*)(Hout + (long)grow * CDIM + q * 32 + j * 8) = hv[j];
#pragma unroll
        for (int i = 0; i < 2; ++i) {
            float s = 0.f, d = 0.f;
#pragma unroll
            for (int j = 0; j < 32; ++j) {
                s = fmaf(h[j], att_src[i * CDIM + q * 32 + j], s);
                d = fmaf(h[j], att_dst[i * CDIM + q * 32 + j], d);
            }
            s += __shfl_xor(s, 1, 64);
            d += __shfl_xor(d, 1, 64);
            if ((q & 1) == 0) {
                int hh = q >> 1;
                long base = (long)i * NNODES * HHEADS + (long)grow * HHEADS + hh;
                a_src[base] = s;
                a_dst[base] = d;
            }
        }
    }
}

// ---- semantic score via MFMA: persistent blocks, kw staged ONCE ----
__global__ __launch_bounds__(256, 3)
void score_mfma_dual(const unsigned short* __restrict__ O0b,
                     const unsigned short* __restrict__ O1b,
                     const unsigned short* __restrict__ kwT_b,
                     const float* __restrict__ kb, const float* __restrict__ q,
                     float* __restrict__ sacc) {
    __shared__ ushort8 As8[64 * 16];    // 16 KB
    __shared__ ushort8 Bs8[128 * 16];   // 32 KB
    __shared__ float red[4];
    const int NT = (NNODES + 63) / 64;  // 1563 row tiles
    int bid = blockIdx.x;
    int type = bid >= SNB;
    const unsigned short* Omb = type ? O1b : O0b;
    int bt = bid - (type ? SNB : 0);
    int tid = threadIdx.x;

#pragma unroll
    for (int i = 0; i < 8; ++i) {
        int idx = tid + i * 256;
        int c = idx >> 4, u = idx & 15;
        Bs8[c * 16 + (u ^ (c & 7))] = ((const ushort8*)kwT_b)[idx];
    }

    int l = tid & 63, w = tid >> 6;
    int lrow = w * 16 + (l & 15);
    int ug = l >> 4;
    float s = 0.f;

    ushort8 pre[4];
    {
        int row0 = bt * 64;
#pragma unroll
        for (int i = 0; i < 4; ++i) {
            int idx = tid + i * 256;
            int row = idx >> 4, u = idx & 15;
            int grow = row0 + row;
            ushort8 v = (ushort8)0;
            if (bt < NT && grow < NNODES) {
                v = ((const ushort8*)Omb)[(long)grow * 16 + u];
#pragma unroll
                for (int e = 0; e < 8; ++e) v[e] = (v[e] & 0x8000) ? 0 : v[e];  // relu
            }
            pre[i] = v;
        }
    }

    for (int t = bt; t < NT; t += SNB) {
        __syncthreads();
#pragma unroll
        for (int i = 0; i < 4; ++i) {
            int idx = tid + i * 256;
            int row = idx >> 4, u = idx & 15;
            As8[row * 16 + (u ^ (row & 7))] = pre[i];
        }
        int tn = t + SNB;
        if (tn < NT) {
            int row0n = tn * 64;
#pragma unroll
            for (int i = 0; i < 4; ++i) {
                int idx = tid + i * 256;
                int row = idx >> 4, u = idx & 15;
                int grow = row0n + row;
                ushort8 v = (ushort8)0;
                if (grow < NNODES) {
                    v = ((const ushort8*)Omb)[(long)grow * 16 + u];
#pragma unroll
                    for (int e = 0; e < 8; ++e) v[e] = (v[e] & 0x8000) ? 0 : v[e];
                }
                pre[i] = v;
            }
        }
        __syncthreads();

        f32x4 acc[8];
#pragma unroll
        for (int ct = 0; ct < 8; ++ct) acc[ct] = (f32x4)0.f;
#pragma unroll
        for (int kc = 0; kc < 4; ++kc) {
            int u = kc * 4 + ug;
            bf16x8 af = *(const bf16x8*)&As8[lrow * 16 + (u ^ (lrow & 7))];
#pragma unroll
            for (int ct = 0; ct < 8; ++ct) {
                int c = ct * 16 + (l & 15);
                bf16x8 bf = *(const bf16x8*)&Bs8[c * 16 + (u ^ (c & 7))];
                acc[ct] = __builtin_amdgcn_mfma_f32_16x16x32_bf16(af, bf, acc[ct], 0, 0, 0);
            }
        }
        int row0 = t * 64;
#pragma unroll
        for (int ct = 0; ct < 8; ++ct) {
            int c = ct * 16 + (l & 15);
            float qc = q[c], kbc = kb[c];
#pragma unroll
            for (int v = 0; v < 4; ++v) {
                int grow = row0 + w * 16 + (l >> 4) * 4 + v;
                if (grow < NNODES) s += qc * tanh_fast(acc[ct][v] + kbc);
            }
        }
    }

#pragma unroll
    for (int m = 32; m >= 1; m >>= 1) s += __shfl_xor(s, m, 64);
    if (l == 0) red[w] = s;
    __syncthreads();
    if (tid == 0) atomicAdd(sacc + type, red[0] + red[1] + red[2] + red[3]);
}

// ============ CSR build (dual-type fused) ============
__global__ void hist_dual(const int* __restrict__ dst0, int* __restrict__ deg0,
                          const int* __restrict__ dst1, int* __restrict__ deg1, int gE) {
    int bid = blockIdx.x;
    int type = bid >= gE;
    const int* dst = type ? dst1 : dst0;
    int* deg = type ? deg1 : deg0;
    int e = (bid - (type ? gE : 0)) * 256 + threadIdx.x;
    if (e < EEDGES) atomicAdd(&deg[dst[e]], 1);
}

__global__ __launch_bounds__(256)
void scan_partial_dual(const int* __restrict__ deg0, int* __restrict__ bsum0,
                       const int* __restrict__ deg1, int* __restrict__ bsum1) {
    __shared__ int red[256];
    int bid = blockIdx.x;
    int type = bid >= SB;
    const int* deg = type ? deg1 : deg0;
    int* bsum = type ? bsum1 : bsum0;
    int b = bid - (type ? SB : 0), t = threadIdx.x;
    int s = 0;
    if (t < 250) {
        int base = b * SCH + t * 2;
        s = deg[base] + deg[base + 1];
    }
    red[t] = s;
    __syncthreads();
#pragma unroll
    for (int off = 128; off >= 1; off >>= 1) {
        if (t < off) red[t] += red[t + off];
        __syncthreads();
    }
    if (t == 0) bsum[b] = red[0];
}

__global__ void scan_bsum_dual(int* __restrict__ bsum0, int* __restrict__ bsum1) {
    int t = threadIdx.x;
    if (t < 2) {
        int* bsum = t ? bsum1 : bsum0;
        int run = 0;
        for (int i = 0; i < SB; ++i) { int v = bsum[i]; bsum[i] = run; run += v; }
    }
}

__global__ __launch_bounds__(256)
void scan_final_dual(const int* __restrict__ deg0, const int* __restrict__ bsum0,
                     int* __restrict__ rowptr0,
                     const int* __restrict__ deg1, const int* __restrict__ bsum1,
                     int* __restrict__ rowptr1) {
    __shared__ int ts[256];
    int bid = blockIdx.x;
    int type = bid >= SB;
    const int* deg = type ? deg1 : deg0;
    const int* bsum = type ? bsum1 : bsum0;
    int* rowptr = type ? rowptr1 : rowptr0;
    int b = bid - (type ? SB : 0), t = threadIdx.x;
    int d0 = 0, d1 = 0;
    int base = b * SCH + t * 2;
    if (t < 250) { d0 = deg[base]; d1 = deg[base + 1]; }
    ts[t] = d0 + d1;
    __syncthreads();
#pragma unroll
    for (int off = 1; off < 256; off <<= 1) {
        int v = (t >= off) ? ts[t - off] : 0;
        __syncthreads();
        ts[t] += v;
        __syncthreads();
    }
    if (t < 250) {
        int excl = bsum[b] + (t > 0 ? ts[t - 1] : 0);
        rowptr[base] = excl;
        rowptr[base + 1] = excl + d0;
    }
    if (b == 0 && t == 0) rowptr[NNODES] = EEDGES;
}

__global__ void fill_dual(const int* __restrict__ src0, const int* __restrict__ dst0,
                          int* __restrict__ cur0, int* __restrict__ cs0,
                          const int* __restrict__ src1, const int* __restrict__ dst1,
                          int* __restrict__ cur1, int* __restrict__ cs1, int gE) {
    int bid = blockIdx.x;
    int type = bid >= gE;
    const int* src = type ? src1 : src0;
    const int* dst = type ? dst1 : dst0;
    int* cursor = type ? cur1 : cur0;
    int* csr_src = type ? cs1 : cs0;
    int e = (bid - (type ? gE : 0)) * 256 + threadIdx.x;
    if (e < EEDGES) {
        int pos = atomicAdd(&cursor[dst[e]], 1);
        csr_src[pos] = src[e];
    }
}

// ============ single-pass aggregation v4: fused edge weights + shfl distribution ============
// Staging (lane-parallel): lane i computes edge base+i's unnormalized softmax weight once.
// Distribution: 3 shfls per 2-edge step (round-12 proven consumer). Lanes 0-31 even edges,
// lanes 32-63 odd edges; lane covers 4 channels (uint2 of bf16).
__global__ __launch_bounds__(256)
void seg_aggregate_dual(const int* __restrict__ rp0, const int* __restrict__ cs0,
                        const float* __restrict__ as0, const float* __restrict__ ad0,
                        unsigned short* __restrict__ O0,
                        const int* __restrict__ rp1, const int* __restrict__ cs1,
                        const float* __restrict__ as1, const float* __restrict__ ad1,
                        unsigned short* __restrict__ O1,
                        const unsigned short* __restrict__ Hfeat, int gseg) {
    int bid = blockIdx.x;
    int type = bid >= gseg;
    const int* rowptr = type ? rp1 : rp0;
    const int* csr_src = type ? cs1 : cs0;
    const float* asv = type ? as1 : as0;
    const float* adv = type ? ad1 : ad0;
    unsigned short* Out = type ? O1 : O0;
    int node = (bid - (type ? gseg : 0)) * 4 + (threadIdx.x >> 6);
    if (node >= NNODES) return;
    int lane = threadIdx.x & 63;
    int cl = lane & 31, eg = lane >> 5;
    int start = rowptr[node], end = rowptr[node + 1];
    int deg = end - start;
    float2 adn = *(const float2*)(adv + node * 2);

    float a0 = 0.f, a1 = 0.f, a2 = 0.f, a3 = 0.f;
    float s0 = 0.f, s1 = 0.f;
    for (int base = 0; base < deg; base += 64) {
        int n = deg - base; if (n > 64) n = 64;
        // stage: lane i computes edge base+i's weight (coalesced csr load + as gather + exp)
        int sA = 0; float wx = 0.f, wy = 0.f;
        if (lane < n) {
            sA = csr_src[start + base + lane];
            float2 av = *(const float2*)(asv + sA * 2);
            float r0 = av.x + adn.x; r0 = r0 >= 0.f ? r0 : NEG * r0;
            float r1 = av.y + adn.y; r1 = r1 >= 0.f ? r1 : NEG * r1;
            wx = __expf(r0); wy = __expf(r1);
        }
        s0 += wx; s1 += wy;
        for (int e0 = 0; e0 < n; e0 += 4) {
            int eA = e0 + eg;
            int siA = __shfl(sA, eA, 64);
            float wxA = __shfl(wx, eA, 64);
            float wyA = __shfl(wy, eA, 64);
            float wA = cl < 16 ? wxA : wyA;   // zero if eA >= n (lane eA holds zeros)
            uint2 hA = *(const uint2*)(Hfeat + (long)siA * CDIM + cl * 4);
            a0 = fmaf(bf2f((unsigned short)hA.x), wA, a0);
            a1 = fmaf(bf2f((unsigned short)(hA.x >> 16)), wA, a1);
            a2 = fmaf(bf2f((unsigned short)hA.y), wA, a2);
            a3 = fmaf(bf2f((unsigned short)(hA.y >> 16)), wA, a3);
            if (e0 + 2 < n) {  // wave-uniform
                int eB = e0 + 2 + eg;
                int siB = __shfl(sA, eB, 64);
                float wxB = __shfl(wx, eB, 64);
                float wyB = __shfl(wy, eB, 64);
                float wB = cl < 16 ? wxB : wyB;
                uint2 hB = *(const uint2*)(Hfeat + (long)siB * CDIM + cl * 4);
                a0 = fmaf(bf2f((unsigned short)hB.x), wB, a0);
                a1 = fmaf(bf2f((unsigned short)(hB.x >> 16)), wB, a1);
                a2 = fmaf(bf2f((unsigned short)hB.y), wB, a2);
                a3 = fmaf(bf2f((unsigned short)(hB.y >> 16)), wB, a3);
            }
        }
    }
#pragma unroll
    for (int m = 32; m >= 1; m >>= 1) {
        s0 += __shfl_xor(s0, m, 64);
        s1 += __shfl_xor(s1, m, 64);
    }
    a0 += __shfl_xor(a0, 32, 64);
    a1 += __shfl_xor(a1, 32, 64);
    a2 += __shfl_xor(a2, 32, 64);
    a3 += __shfl_xor(a3, 32, 64);
    if (lane < 32) {
        float ssel = lane < 16 ? s0 : s1;
        float inv = ssel > 0.f ? 1.f / ssel : 0.f;
        uint2 o;
        o.x = (unsigned int)f2bf(a0 * inv) | ((unsigned int)f2bf(a1 * inv) << 16);
        o.y = (unsigned int)f2bf(a2 * inv) | ((unsigned int)f2bf(a3 * inv) << 16);
        *(uint2*)(Out + (long)node * CDIM + lane * 4) = o;
    }
}

// ---- final classifier with fused semantic combine (attn computed inline) ----
__global__ __launch_bounds__(256)
void final_linear_kernel(const unsigned short* __restrict__ O0,
                         const unsigned short* __restrict__ O1,
                         const float* __restrict__ saccp,
                         const float* __restrict__ lw, const float* __restrict__ lb,
                         float* __restrict__ out) {
    __shared__ float lws[CDIM * FOUT];
    int tid = threadIdx.x;
    for (int i = tid; i < CDIM * FOUT; i += 256) lws[i] = lw[i];
    __syncthreads();
    float fa0, fa1;
    attn_from_sacc(saccp, fa0, fa1);
    int idx = blockIdx.x * 256 + tid;
    if (idx >= NNODES * FOUT) return;
    int n = idx >> 3, o = idx & 7;
    const ushort8* r0 = (const ushort8*)(O0 + (long)n * CDIM);
    const ushort8* r1 = (const ushort8*)(O1 + (long)n * CDIM);
    float acc = lb[o];
#pragma unroll
    for (int k8 = 0; k8 < 16; ++k8) {
        ushort8 v0 = r0[k8];
        ushort8 v1 = r1[k8];
#pragma unroll
        for (int e = 0; e < 8; ++e) {
            float hv = fa0 * bfrelu2f(v0[e]) + fa1 * bfrelu2f(v1[e]);
            acc = fmaf(hv, lws[(k8 * 8 + e) * FOUT + o], acc);
        }
    }
    out[idx] = acc;
}

extern "C" void kernel_launch(void* const* d_in, const int* in_sizes, int n_in,
                              void* d_out, int out_size, void* d_ws, size_t ws_size,
                              hipStream_t stream) {
    const float* x          = (const float*)d_in[0];
    const int*   ei_spatial = (const int*)d_in[1];
    const int*   ei_similar = (const int*)d_in[2];
    const float* p1_proj_w  = (const float*)d_in[3];
    const float* p1_proj_b  = (const float*)d_in[4];
    const float* p1_att_src = (const float*)d_in[5];
    const float* p1_att_dst = (const float*)d_in[6];
    const float* p1_q       = (const float*)d_in[7];
    const float* p1_kw      = (const float*)d_in[8];
    const float* p1_kb      = (const float*)d_in[9];
    const float* p2_proj_w  = (const float*)d_in[10];
    const float* p2_proj_b  = (const float*)d_in[11];
    const float* p2_att_src = (const float*)d_in[12];
    const float* p2_att_dst = (const float*)d_in[13];
    const float* p2_q       = (const float*)d_in[14];
    const float* p2_kw      = (const float*)d_in[15];
    const float* p2_kb      = (const float*)d_in[16];
    const float* lin_w      = (const float*)d_in[17];
    const float* lin_b      = (const float*)d_in[18];

    float* ws = (float*)d_ws;
    const size_t nc = (size_t)NNODES * CDIM;
    const size_t nh2 = (size_t)NNODES * HHEADS;

    float* asrc = ws;                    // 2*N*H
    float* adst = asrc + 2 * nh2;        // 2*N*H
    float* sacc = adst + 2 * nh2;        // 4 (L1: [0..1], L2: [2..3])
    int* rowptr0 = (int*)(sacc + 4);     // N+1
    int* rowptr1 = rowptr0 + (NNODES + 1);
    int* cursor0 = rowptr1 + (NNODES + 1);  // N+1 (contiguous with cursor1)
    int* cursor1 = cursor0 + (NNODES + 1);
    int* cs0     = cursor1 + (NNODES + 1);  // E
    int* cs1     = cs0 + EEDGES;            // E
    int* deg0    = cs1 + EEDGES;            // N (deg0/deg1 contiguous for one memset)
    int* deg1    = deg0 + NNODES;           // N
    int* bsum0   = deg1 + NNODES;           // SB
    int* bsum1   = bsum0 + SB;              // SB
    uintptr_t kp = (uintptr_t)(bsum1 + SB);
    kp = (kp + 15) & ~(uintptr_t)15;
    unsigned short* p1T = (unsigned short*)kp;      // FIN*CDIM bf16
    unsigned short* k1T = p1T + FIN * CDIM;         // CDIM*CDIM
    unsigned short* p2T = k1T + CDIM * CDIM;        // CDIM*CDIM
    unsigned short* k2T = p2T + CDIM * CDIM;        // CDIM*CDIM
    unsigned short* Hb  = k2T + CDIM * CDIM;        // N*C bf16
    unsigned short* O0b = Hb + nc;
    unsigned short* O1b = O0b + nc;

    const int gE = (EEDGES + 255) / 256;
    const int gm = (NNODES + 63) / 64;      // 1563
    const int gseg = (NNODES + 3) / 4;
    const int nh = NNODES * HHEADS;

    // ---- build CSR for both edge types (structure reused across layers) ----
    hipMemsetAsync(deg0, 0, 2 * NNODES * sizeof(int), stream);
    hist_dual<<<2 * gE, 256, 0, stream>>>(ei_spatial + EEDGES, deg0,
                                          ei_similar + EEDGES, deg1, gE);
    scan_partial_dual<<<2 * SB, 256, 0, stream>>>(deg0, bsum0, deg1, bsum1);
    scan_bsum_dual<<<1, 64, 0, stream>>>(bsum0, bsum1);
    scan_final_dual<<<2 * SB, 256, 0, stream>>>(deg0, bsum0, rowptr0, deg1, bsum1, rowptr1);
    hipMemcpyAsync(cursor0, rowptr0, 2 * (NNODES + 1) * sizeof(int),
                   hipMemcpyDeviceToDevice, stream);
    fill_dual<<<2 * gE, 256, 0, stream>>>(ei_spatial, ei_spatial + EEDGES, cursor0, cs0,
                                          ei_similar, ei_similar + EEDGES, cursor1, cs1, gE);

    // ---- all weight transposes (both layers) + sacc zero, one dispatch ----
    const int cvtN = (FIN + 3 * CDIM) * CDIM;
    cvt_all<<<(cvtN + 255) / 256, 256, 0, stream>>>(
        p1_proj_w, p1_kw, p2_proj_w, p2_kw, p1T, k1T, p2T, k2T, sacc);

    // ================= Layer 1 =================
    proj_mfma<FIN, 0><<<gm, 256, 0, stream>>>(x, nullptr, nullptr, p1T, p1_proj_b,
                                              p1_att_src, p1_att_dst, Hb, asrc, adst);
    seg_aggregate_dual<<<2 * gseg, 256, 0, stream>>>(
        rowptr0, cs0, asrc, adst, O0b,
        rowptr1, cs1, asrc + nh, adst + nh, O1b, Hb, gseg);
    score_mfma_dual<<<2 * SNB, 256, 0, stream>>>(O0b, O1b, k1T, p1_kb, p1_q, sacc);

    // ================= Layer 2 (combine + attn-softmax fused into proj) =================
    proj_mfma<CDIM, 2><<<gm, 256, 0, stream>>>(O0b, O1b, sacc, p2T, p2_proj_b,
                                               p2_att_src, p2_att_dst, Hb, asrc, adst);
    seg_aggregate_dual<<<2 * gseg, 256, 0, stream>>>(
        rowptr0, cs0, asrc, adst, O0b,
        rowptr1, cs1, asrc + nh, adst + nh, O1b, Hb, gseg);
    score_mfma_dual<<<2 * SNB, 256, 0, stream>>>(O0b, O1b, k2T, p2_kb, p2_q, sacc + 2);

    // ================= Final classifier (combine + attn-softmax fused) =================
    const int gfin = (NNODES * FOUT + 255) / 256;
    final_linear_kernel<<<gfin, 256, 0, stream>>>(O0b, O1b, sacc + 2, lin_w, lin_b,
                                                  (float*)d_out);
}

// Round 15
// 492.694 us; speedup vs baseline: 6.1380x; 1.0432x over previous
//
#include <hip/hip_runtime.h>

#define NNODES 100000
#define EEDGES 600000
#define CDIM 128
#define HHEADS 2
#define DDIM 64
#define FIN 64
#define FOUT 8
#define NEG 0.2f

#define SB 200    // scan blocks
#define SCH 500   // nodes per scan block (200*500 = 100000 exactly)
#define SNB 384   // persistent score blocks per edge type

typedef short bf16x8 __attribute__((ext_vector_type(8)));
typedef unsigned short ushort8 __attribute__((ext_vector_type(8)));
typedef float f32x4 __attribute__((ext_vector_type(4)));

__device__ __forceinline__ float tanh_fast(float x) {
    float e = __expf(2.f * x);
    return 1.f - 2.f / (e + 1.f);
}

__device__ __forceinline__ unsigned short f2bf(float x) {
    unsigned int u = __float_as_uint(x);
    unsigned int r = (u + 0x7FFFu + ((u >> 16) & 1u)) >> 16;  // RNE
    return (unsigned short)r;
}
__device__ __forceinline__ float bf2f(unsigned short u) {
    return __uint_as_float(((unsigned int)u) << 16);
}
__device__ __forceinline__ float bfrelu2f(unsigned short u) {
    return (u & 0x8000) ? 0.f : __uint_as_float(((unsigned int)u) << 16);
}

// 2-way semantic softmax from raw score sums (recomputed inline by consumers)
__device__ __forceinline__ void attn_from_sacc(const float* saccp, float& fa0, float& fa1) {
    float s0 = saccp[0] / (float)NNODES;
    float s1 = saccp[1] / (float)NNODES;
    float m = fmaxf(s0, s1);
    float e0 = expf(s0 - m), e1 = expf(s1 - m);
    float inv = 1.f / (e0 + e1);
    fa0 = e0 * inv; fa1 = e1 * inv;
}

// ---- ALL weight transposes (both layers) in one launch; also zeroes sacc[0..4) ----
__global__ __launch_bounds__(256)
void cvt_all(const float* __restrict__ p1w, const float* __restrict__ k1w,
             const float* __restrict__ p2w, const float* __restrict__ k2w,
             unsigned short* __restrict__ p1T, unsigned short* __restrict__ k1T,
             unsigned short* __restrict__ p2T, unsigned short* __restrict__ k2T,
             float* __restrict__ sacc) {
    int idx = blockIdx.x * 256 + threadIdx.x;
    if (blockIdx.x == 0 && threadIdx.x < 4) sacc[threadIdx.x] = 0.f;
    if (idx < FIN * CDIM) {                    // p1: [k][c] -> [c*FIN+k]
        int c = idx / FIN, k = idx % FIN;
        p1T[idx] = f2bf(p1w[k * CDIM + c]);
    } else if (idx < (FIN + CDIM) * CDIM) {    // k1
        int j = idx - FIN * CDIM;
        int c = j >> 7, k = j & 127;
        k1T[j] = f2bf(k1w[k * CDIM + c]);
    } else if (idx < (FIN + 2 * CDIM) * CDIM) { // p2
        int j = idx - (FIN + CDIM) * CDIM;
        int c = j >> 7, k = j & 127;
        p2T[j] = f2bf(p2w[k * CDIM + c]);
    } else if (idx < (FIN + 3 * CDIM) * CDIM) { // k2
        int j = idx - (FIN + 2 * CDIM) * CDIM;
        int c = j >> 7, k = j & 127;
        k2T[j] = f2bf(k2w[k * CDIM + c]);
    }
}

// ============ projection via MFMA: H = bf16(X@W + b), fused attention dots ============
// MODE 0: X f32 (layer 1). MODE 2: X = a0*relu(O0)+a1*relu(O1), attn from sacc (layer 2).
template<int K, int MODE>
__global__ __launch_bounds__(256)
void proj_mfma(const void* __restrict__ Xv, const void* __restrict__ Xv2,
               const float* __restrict__ saccp,
               const unsigned short* __restrict__ pwT_b,
               const float* __restrict__ bias,
               const float* __restrict__ att_src, const float* __restrict__ att_dst,
               unsigned short* __restrict__ Hout,
               float* __restrict__ a_src, float* __restrict__ a_dst) {
    const int U = K / 8;
    __shared__ ushort8 smem[192 * (K / 8)];   // As8 [64][U] + Bs8 [128][U]
    ushort8* As8 = smem;
    ushort8* Bs8 = smem + 64 * U;
    int tid = threadIdx.x;
    int row0 = blockIdx.x * 64;
    float fa0 = 0.f, fa1 = 0.f;
    if (MODE == 2) attn_from_sacc(saccp, fa0, fa1);

#pragma unroll
    for (int i = 0; i < (64 * U) / 256; ++i) {
        int idx = tid + i * 256;
        int row = idx / U, u = idx % U;
        int grow = row0 + row;
        ushort8 v;
        if (grow < NNODES) {
            if (MODE == 2) {
                ushort8 v0 = ((const ushort8*)Xv)[(long)grow * U + u];
                ushort8 v1 = ((const ushort8*)Xv2)[(long)grow * U + u];
#pragma unroll
                for (int e = 0; e < 8; ++e)
                    v[e] = f2bf(fa0 * bfrelu2f(v0[e]) + fa1 * bfrelu2f(v1[e]));
            } else {
                const float* p = (const float*)Xv + (long)grow * K + u * 8;
                float4 a = *(const float4*)p;
                float4 b = *(const float4*)(p + 4);
                v[0] = f2bf(a.x); v[1] = f2bf(a.y); v[2] = f2bf(a.z); v[3] = f2bf(a.w);
                v[4] = f2bf(b.x); v[5] = f2bf(b.y); v[6] = f2bf(b.z); v[7] = f2bf(b.w);
            }
        } else v = (ushort8)0;
        As8[row * U + (u ^ (row & 7))] = v;
    }
#pragma unroll
    for (int i = 0; i < (128 * U) / 256; ++i) {
        int idx = tid + i * 256;
        int c = idx / U, u = idx % U;
        Bs8[c * U + (u ^ (c & 7))] = ((const ushort8*)pwT_b)[idx];
    }
    __syncthreads();

    int l = tid & 63, w = tid >> 6;
    int lrow = w * 16 + (l & 15);
    int ug = l >> 4;
    f32x4 acc[8];
#pragma unroll
    for (int ct = 0; ct < 8; ++ct) acc[ct] = (f32x4)0.f;

#pragma unroll
    for (int kc = 0; kc < K / 32; ++kc) {
        int u = kc * 4 + ug;
        bf16x8 af = *(const bf16x8*)&As8[lrow * U + (u ^ (lrow & 7))];
#pragma unroll
        for (int ct = 0; ct < 8; ++ct) {
            int c = ct * 16 + (l & 15);
            bf16x8 bf = *(const bf16x8*)&Bs8[c * U + (u ^ (c & 7))];
            acc[ct] = __builtin_amdgcn_mfma_f32_16x16x32_bf16(af, bf, acc[ct], 0, 0, 0);
        }
    }

    __syncthreads();
    unsigned short* Cs = (unsigned short*)smem;  // [64][128]
#pragma unroll
    for (int ct = 0; ct < 8; ++ct) {
        int c = ct * 16 + (l & 15);
        float bc = bias[c];
#pragma unroll
        for (int v = 0; v < 4; ++v) {
            int rr = w * 16 + (l >> 4) * 4 + v;
            Cs[rr * 128 + c] = f2bf(acc[ct][v] + bc);
        }
    }
    __syncthreads();

    int r = tid >> 2, q = tid & 3;
    int grow = row0 + r;
    if (grow < NNODES) {
        float h[32];
        ushort8 hv[4];
#pragma unroll
        for (int j = 0; j < 4; ++j) {
            hv[j] = *(ushort8*)&Cs[r * 128 + q * 32 + j * 8];
#pragma unroll
            for (int e = 0; e < 8; ++e) h[j * 8 + e] = bf2f(hv[j][e]);
        }
#pragma unroll
        for (int j = 0; j < 4; ++j)
            *(ushort8*)(Hout + (long)grow * CDIM + q * 32 + j * 8) = hv[j];
#pragma unroll
        for (int i = 0; i < 2; ++i) {
            float s = 0.f, d = 0.f;
#pragma unroll
            for (int j = 0; j < 32; ++j) {
                s = fmaf(h[j], att_src[i * CDIM + q * 32 + j], s);
                d = fmaf(h[j], att_dst[i * CDIM + q * 32 + j], d);
            }
            s += __shfl_xor(s, 1, 64);
            d += __shfl_xor(d, 1, 64);
            if ((q & 1) == 0) {
                int hh = q >> 1;
                long base = (long)i * NNODES * HHEADS + (long)grow * HHEADS + hh;
                a_src[base] = s;
                a_dst[base] = d;
            }
        }
    }
}

// ---- semantic score via MFMA: persistent blocks, kw staged ONCE ----
__global__ __launch_bounds__(256, 3)
void score_mfma_dual(const unsigned short* __restrict__ O0b,
                     const unsigned short* __restrict__ O1b,
                     const unsigned short* __restrict__ kwT_b,
                     const float* __restrict__ kb, const float* __restrict__ q,
                     float* __restrict__ sacc) {
    __shared__ ushort8 As8[64 * 16];    // 16 KB
    __shared__ ushort8 Bs8[128 * 16];   // 32 KB
    __shared__ float red[4];
    const int NT = (NNODES + 63) / 64;  // 1563 row tiles
    int bid = blockIdx.x;
    int type = bid >= SNB;
    const unsigned short* Omb = type ? O1b : O0b;
    int bt = bid - (type ? SNB : 0);
    int tid = threadIdx.x;

#pragma unroll
    for (int i = 0; i < 8; ++i) {
        int idx = tid + i * 256;
        int c = idx >> 4, u = idx & 15;
        Bs8[c * 16 + (u ^ (c & 7))] = ((const ushort8*)kwT_b)[idx];
    }

    int l = tid & 63, w = tid >> 6;
    int lrow = w * 16 + (l & 15);
    int ug = l >> 4;
    float s = 0.f;

    ushort8 pre[4];
    {
        int row0 = bt * 64;
#pragma unroll
        for (int i = 0; i < 4; ++i) {
            int idx = tid + i * 256;
            int row = idx >> 4, u = idx & 15;
            int grow = row0 + row;
            ushort8 v = (ushort8)0;
            if (bt < NT && grow < NNODES) {
                v = ((const ushort8*)Omb)[(long)grow * 16 + u];
#pragma unroll
                for (int e = 0; e < 8; ++e) v[e] = (v[e] & 0x8000) ? 0 : v[e];  // relu
            }
            pre[i] = v;
        }
    }

    for (int t = bt; t < NT; t += SNB) {
        __syncthreads();
#pragma unroll
        for (int i = 0; i < 4; ++i) {
            int idx = tid + i * 256;
            int row = idx >> 4, u = idx & 15;
            As8[row * 16 + (u ^ (row & 7))] = pre[i];
        }
        int tn = t + SNB;
        if (tn < NT) {
            int row0n = tn * 64;
#pragma unroll
            for (int i = 0; i < 4; ++i) {
                int idx = tid + i * 256;
                int row = idx >> 4, u = idx & 15;
                int grow = row0n + row;
                ushort8 v = (ushort8)0;
                if (grow < NNODES) {
                    v = ((const ushort8*)Omb)[(long)grow * 16 + u];
#pragma unroll
                    for (int e = 0; e < 8; ++e) v[e] = (v[e] & 0x8000) ? 0 : v[e];
                }
                pre[i] = v;
            }
        }
        __syncthreads();

        f32x4 acc[8];
#pragma unroll
        for (int ct = 0; ct < 8; ++ct) acc[ct] = (f32x4)0.f;
#pragma unroll
        for (int kc = 0; kc < 4; ++kc) {
            int u = kc * 4 + ug;
            bf16x8 af = *(const bf16x8*)&As8[lrow * 16 + (u ^ (lrow & 7))];
#pragma unroll
            for (int ct = 0; ct < 8; ++ct) {
                int c = ct * 16 + (l & 15);
                bf16x8 bf = *(const bf16x8*)&Bs8[c * 16 + (u ^ (c & 7))];
                acc[ct] = __builtin_amdgcn_mfma_f32_16x16x32_bf16(af, bf, acc[ct], 0, 0, 0);
            }
        }
        int row0 = t * 64;
#pragma unroll
        for (int ct = 0; ct < 8; ++ct) {
            int c = ct * 16 + (l & 15);
            float qc = q[c], kbc = kb[c];
#pragma unroll
            for (int v = 0; v < 4; ++v) {
                int grow = row0 + w * 16 + (l >> 4) * 4 + v;
                if (grow < NNODES) s += qc * tanh_fast(acc[ct][v] + kbc);
            }
        }
    }

#pragma unroll
    for (int m = 32; m >= 1; m >>= 1) s += __shfl_xor(s, m, 64);
    if (l == 0) red[w] = s;
    __syncthreads();
    if (tid == 0) atomicAdd(sacc + type, red[0] + red[1] + red[2] + red[3]);
}

// ============ CSR build (dual-type fused) ============
__global__ void hist_dual(const int* __restrict__ dst0, int* __restrict__ deg0,
                          const int* __restrict__ dst1, int* __restrict__ deg1, int gE) {
    int bid = blockIdx.x;
    int type = bid >= gE;
    const int* dst = type ? dst1 : dst0;
    int* deg = type ? deg1 : deg0;
    int e = (bid - (type ? gE : 0)) * 256 + threadIdx.x;
    if (e < EEDGES) atomicAdd(&deg[dst[e]], 1);
}

__global__ __launch_bounds__(256)
void scan_partial_dual(const int* __restrict__ deg0, int* __restrict__ bsum0,
                       const int* __restrict__ deg1, int* __restrict__ bsum1) {
    __shared__ int red[256];
    int bid = blockIdx.x;
    int type = bid >= SB;
    const int* deg = type ? deg1 : deg0;
    int* bsum = type ? bsum1 : bsum0;
    int b = bid - (type ? SB : 0), t = threadIdx.x;
    int s = 0;
    if (t < 250) {
        int base = b * SCH + t * 2;
        s = deg[base] + deg[base + 1];
    }
    red[t] = s;
    __syncthreads();
#pragma unroll
    for (int off = 128; off >= 1; off >>= 1) {
        if (t < off) red[t] += red[t + off];
        __syncthreads();
    }
    if (t == 0) bsum[b] = red[0];
}

__global__ void scan_bsum_dual(int* __restrict__ bsum0, int* __restrict__ bsum1) {
    int t = threadIdx.x;
    if (t < 2) {
        int* bsum = t ? bsum1 : bsum0;
        int run = 0;
        for (int i = 0; i < SB; ++i) { int v = bsum[i]; bsum[i] = run; run += v; }
    }
}

// writes rowptr AND cursor (removes the cursor memcpy dispatch)
__global__ __launch_bounds__(256)
void scan_final_dual(const int* __restrict__ deg0, const int* __restrict__ bsum0,
                     int* __restrict__ rowptr0, int* __restrict__ cursor0,
                     const int* __restrict__ deg1, const int* __restrict__ bsum1,
                     int* __restrict__ rowptr1, int* __restrict__ cursor1) {
    __shared__ int ts[256];
    int bid = blockIdx.x;
    int type = bid >= SB;
    const int* deg = type ? deg1 : deg0;
    const int* bsum = type ? bsum1 : bsum0;
    int* rowptr = type ? rowptr1 : rowptr0;
    int* cursor = type ? cursor1 : cursor0;
    int b = bid - (type ? SB : 0), t = threadIdx.x;
    int d0 = 0, d1 = 0;
    int base = b * SCH + t * 2;
    if (t < 250) { d0 = deg[base]; d1 = deg[base + 1]; }
    ts[t] = d0 + d1;
    __syncthreads();
#pragma unroll
    for (int off = 1; off < 256; off <<= 1) {
        int v = (t >= off) ? ts[t - off] : 0;
        __syncthreads();
        ts[t] += v;
        __syncthreads();
    }
    if (t < 250) {
        int excl = bsum[b] + (t > 0 ? ts[t - 1] : 0);
        rowptr[base] = excl;      cursor[base] = excl;
        rowptr[base + 1] = excl + d0;  cursor[base + 1] = excl + d0;
    }
    if (b == 0 && t == 0) rowptr[NNODES] = EEDGES;
}

__global__ void fill_dual(const int* __restrict__ src0, const int* __restrict__ dst0,
                          int* __restrict__ cur0, int* __restrict__ cs0,
                          const int* __restrict__ src1, const int* __restrict__ dst1,
                          int* __restrict__ cur1, int* __restrict__ cs1, int gE) {
    int bid = blockIdx.x;
    int type = bid >= gE;
    const int* src = type ? src1 : src0;
    const int* dst = type ? dst1 : dst0;
    int* cursor = type ? cur1 : cur0;
    int* csr_src = type ? cs1 : cs0;
    int e = (bid - (type ? gE : 0)) * 256 + threadIdx.x;
    if (e < EEDGES) {
        int pos = atomicAdd(&cursor[dst[e]], 1);
        csr_src[pos] = src[e];
    }
}

// ============ single-pass aggregation v5: quad-gather (4 edges / wave instruction) ======
// Staging: lane i computes edge base+i's unnormalized weight once (fused, no edge_w pass).
// Consume: lane = (edge-of-quad = lane>>4, channel-block cpos = lane&15); each lane loads
// uint4 (8 bf16 channels) of its quad-edge's H row -> 1 gather instr covers 4 edges (1 KB).
__global__ __launch_bounds__(256)
void seg_aggregate_dual(const int* __restrict__ rp0, const int* __restrict__ cs0,
                        const float* __restrict__ as0, const float* __restrict__ ad0,
                        unsigned short* __restrict__ O0,
                        const int* __restrict__ rp1, const int* __restrict__ cs1,
                        const float* __restrict__ as1, const float* __restrict__ ad1,
                        unsigned short* __restrict__ O1,
                        const unsigned short* __restrict__ Hfeat, int gseg) {
    int bid = blockIdx.x;
    int type = bid >= gseg;
    const int* rowptr = type ? rp1 : rp0;
    const int* csr_src = type ? cs1 : cs0;
    const float* asv = type ? as1 : as0;
    const float* adv = type ? ad1 : ad0;
    unsigned short* Out = type ? O1 : O0;
    int node = (bid - (type ? gseg : 0)) * 4 + (threadIdx.x >> 6);
    if (node >= NNODES) return;
    int lane = threadIdx.x & 63;
    int rowgrp = lane >> 4;      // which edge of the quad this lane serves
    int cpos = lane & 15;        // channel block: channels cpos*8 .. cpos*8+7
    int start = rowptr[node], end = rowptr[node + 1];
    int deg = end - start;
    float2 adn = *(const float2*)(adv + node * 2);

    float a[8] = {0.f, 0.f, 0.f, 0.f, 0.f, 0.f, 0.f, 0.f};
    float s0 = 0.f, s1 = 0.f;
    for (int base = 0; base < deg; base += 64) {
        int n = deg - base; if (n > 64) n = 64;
        // stage: lane i computes edge base+i's weight (coalesced csr load + as gather + exp)
        int sA = 0; float wx = 0.f, wy = 0.f;
        if (lane < n) {
            sA = csr_src[start + base + lane];
            float2 av = *(const float2*)(asv + sA * 2);
            float r0 = av.x + adn.x; r0 = r0 >= 0.f ? r0 : NEG * r0;
            float r1 = av.y + adn.y; r1 = r1 >= 0.f ? r1 : NEG * r1;
            wx = __expf(r0); wy = __expf(r1);
        }
        s0 += wx; s1 += wy;
        for (int e0 = 0; e0 < n; e0 += 8) {
            // quad A: edges e0..e0+3 (padding lanes hold w=0, si=0)
            int eA = e0 + rowgrp;
            int siA = __shfl(sA, eA, 64);
            float wxA = __shfl(wx, eA, 64);
            float wyA = __shfl(wy, eA, 64);
            float wA = cpos < 8 ? wxA : wyA;
            uint4 hA = *(const uint4*)(Hfeat + (long)siA * CDIM + cpos * 8);
            a[0] = fmaf(bf2f((unsigned short)hA.x), wA, a[0]);
            a[1] = fmaf(bf2f((unsigned short)(hA.x >> 16)), wA, a[1]);
            a[2] = fmaf(bf2f((unsigned short)hA.y), wA, a[2]);
            a[3] = fmaf(bf2f((unsigned short)(hA.y >> 16)), wA, a[3]);
            a[4] = fmaf(bf2f((unsigned short)hA.z), wA, a[4]);
            a[5] = fmaf(bf2f((unsigned short)(hA.z >> 16)), wA, a[5]);
            a[6] = fmaf(bf2f((unsigned short)hA.w), wA, a[6]);
            a[7] = fmaf(bf2f((unsigned short)(hA.w >> 16)), wA, a[7]);
            if (e0 + 4 < n) {  // wave-uniform: quad B edges e0+4..e0+7
                int eB = e0 + 4 + rowgrp;
                int siB = __shfl(sA, eB, 64);
                float wxB = __shfl(wx, eB, 64);
                float wyB = __shfl(wy, eB, 64);
                float wB = cpos < 8 ? wxB : wyB;
                uint4 hB = *(const uint4*)(Hfeat + (long)siB * CDIM + cpos * 8);
                a[0] = fmaf(bf2f((unsigned short)hB.x), wB, a[0]);
                a[1] = fmaf(bf2f((unsigned short)(hB.x >> 16)), wB, a[1]);
                a[2] = fmaf(bf2f((unsigned short)hB.y), wB, a[2]);
                a[3] = fmaf(bf2f((unsigned short)(hB.y >> 16)), wB, a[3]);
                a[4] = fmaf(bf2f((unsigned short)hB.z), wB, a[4]);
                a[5] = fmaf(bf2f((unsigned short)(hB.z >> 16)), wB, a[5]);
                a[6] = fmaf(bf2f((unsigned short)hB.w), wB, a[6]);
                a[7] = fmaf(bf2f((unsigned short)(hB.w >> 16)), wB, a[7]);
            }
        }
    }
    // softmax denominators over all lanes
#pragma unroll
    for (int m = 32; m >= 1; m >>= 1) {
        s0 += __shfl_xor(s0, m, 64);
        s1 += __shfl_xor(s1, m, 64);
    }
    // merge the 4 edge-groups (rowgrp dimension = lane bits 4,5)
#pragma unroll
    for (int i = 0; i < 8; ++i) {
        a[i] += __shfl_xor(a[i], 16, 64);
        a[i] += __shfl_xor(a[i], 32, 64);
    }
    if (lane < 16) {
        float ssel = cpos < 8 ? s0 : s1;
        float inv = ssel > 0.f ? 1.f / ssel : 0.f;
        uint4 o;
        o.x = (unsigned int)f2bf(a[0] * inv) | ((unsigned int)f2bf(a[1] * inv) << 16);
        o.y = (unsigned int)f2bf(a[2] * inv) | ((unsigned int)f2bf(a[3] * inv) << 16);
        o.z = (unsigned int)f2bf(a[4] * inv) | ((unsigned int)f2bf(a[5] * inv) << 16);
        o.w = (unsigned int)f2bf(a[6] * inv) | ((unsigned int)f2bf(a[7] * inv) << 16);
        *(uint4*)(Out + (long)node * CDIM + cpos * 8) = o;
    }
}

// ---- final classifier with fused semantic combine (attn computed inline) ----
__global__ __launch_bounds__(256)
void final_linear_kernel(const unsigned short* __restrict__ O0,
                         const unsigned short* __restrict__ O1,
                         const float* __restrict__ saccp,
                         const float* __restrict__ lw, const float* __restrict__ lb,
                         float* __restrict__ out) {
    __shared__ float lws[CDIM * FOUT];
    int tid = threadIdx.x;
    for (int i = tid; i < CDIM * FOUT; i += 256) lws[i] = lw[i];
    __syncthreads();
    float fa0, fa1;
    attn_from_sacc(saccp, fa0, fa1);
    int idx = blockIdx.x * 256 + tid;
    if (idx >= NNODES * FOUT) return;
    int n = idx >> 3, o = idx & 7;
    const ushort8* r0 = (const ushort8*)(O0 + (long)n * CDIM);
    const ushort8* r1 = (const ushort8*)(O1 + (long)n * CDIM);
    float acc = lb[o];
#pragma unroll
    for (int k8 = 0; k8 < 16; ++k8) {
        ushort8 v0 = r0[k8];
        ushort8 v1 = r1[k8];
#pragma unroll
        for (int e = 0; e < 8; ++e) {
            float hv = fa0 * bfrelu2f(v0[e]) + fa1 * bfrelu2f(v1[e]);
            acc = fmaf(hv, lws[(k8 * 8 + e) * FOUT + o], acc);
        }
    }
    out[idx] = acc;
}

extern "C" void kernel_launch(void* const* d_in, const int* in_sizes, int n_in,
                              void* d_out, int out_size, void* d_ws, size_t ws_size,
                              hipStream_t stream) {
    const float* x          = (const float*)d_in[0];
    const int*   ei_spatial = (const int*)d_in[1];
    const int*   ei_similar = (const int*)d_in[2];
    const float* p1_proj_w  = (const float*)d_in[3];
    const float* p1_proj_b  = (const float*)d_in[4];
    const float* p1_att_src = (const float*)d_in[5];
    const float* p1_att_dst = (const float*)d_in[6];
    const float* p1_q       = (const float*)d_in[7];
    const float* p1_kw      = (const float*)d_in[8];
    const float* p1_kb      = (const float*)d_in[9];
    const float* p2_proj_w  = (const float*)d_in[10];
    const float* p2_proj_b  = (const float*)d_in[11];
    const float* p2_att_src = (const float*)d_in[12];
    const float* p2_att_dst = (const float*)d_in[13];
    const float* p2_q       = (const float*)d_in[14];
    const float* p2_kw      = (const float*)d_in[15];
    const float* p2_kb      = (const float*)d_in[16];
    const float* lin_w      = (const float*)d_in[17];
    const float* lin_b      = (const float*)d_in[18];

    float* ws = (float*)d_ws;
    const size_t nc = (size_t)NNODES * CDIM;
    const size_t nh2 = (size_t)NNODES * HHEADS;

    float* asrc = ws;                    // 2*N*H
    float* adst = asrc + 2 * nh2;        // 2*N*H
    float* sacc = adst + 2 * nh2;        // 4 (L1: [0..1], L2: [2..3])
    int* rowptr0 = (int*)(sacc + 4);     // N+1
    int* rowptr1 = rowptr0 + (NNODES + 1);
    int* cursor0 = rowptr1 + (NNODES + 1);  // N+1
    int* cursor1 = cursor0 + (NNODES + 1);
    int* cs0     = cursor1 + (NNODES + 1);  // E
    int* cs1     = cs0 + EEDGES;            // E
    int* deg0    = cs1 + EEDGES;            // N (deg0/deg1 contiguous for one memset)
    int* deg1    = deg0 + NNODES;           // N
    int* bsum0   = deg1 + NNODES;           // SB
    int* bsum1   = bsum0 + SB;              // SB
    uintptr_t kp = (uintptr_t)(bsum1 + SB);
    kp = (kp + 15) & ~(uintptr_t)15;
    unsigned short* p1T = (unsigned short*)kp;      // FIN*CDIM bf16
    unsigned short* k1T = p1T + FIN * CDIM;         // CDIM*CDIM
    unsigned short* p2T = k1T + CDIM * CDIM;        // CDIM*CDIM
    unsigned short* k2T = p2T + CDIM * CDIM;        // CDIM*CDIM
    unsigned short* Hb  = k2T + CDIM * CDIM;        // N*C bf16
    unsigned short* O0b = Hb + nc;
    unsigned short* O1b = O0b + nc;

    const int gE = (EEDGES + 255) / 256;
    const int gm = (NNODES + 63) / 64;      // 1563
    const int gseg = (NNODES + 3) / 4;
    const int nh = NNODES * HHEADS;

    // ---- build CSR for both edge types (structure reused across layers) ----
    hipMemsetAsync(deg0, 0, 2 * NNODES * sizeof(int), stream);
    hist_dual<<<2 * gE, 256, 0, stream>>>(ei_spatial + EEDGES, deg0,
                                          ei_similar + EEDGES, deg1, gE);
    scan_partial_dual<<<2 * SB, 256, 0, stream>>>(deg0, bsum0, deg1, bsum1);
    scan_bsum_dual<<<1, 64, 0, stream>>>(bsum0, bsum1);
    scan_final_dual<<<2 * SB, 256, 0, stream>>>(deg0, bsum0, rowptr0, cursor0,
                                                deg1, bsum1, rowptr1, cursor1);
    fill_dual<<<2 * gE, 256, 0, stream>>>(ei_spatial, ei_spatial + EEDGES, cursor0, cs0,
                                          ei_similar, ei_similar + EEDGES, cursor1, cs1, gE);

    // ---- all weight transposes (both layers) + sacc zero, one dispatch ----
    const int cvtN = (FIN + 3 * CDIM) * CDIM;
    cvt_all<<<(cvtN + 255) / 256, 256, 0, stream>>>(
        p1_proj_w, p1_kw, p2_proj_w, p2_kw, p1T, k1T, p2T, k2T, sacc);

    // ================= Layer 1 =================
    proj_mfma<FIN, 0><<<gm, 256, 0, stream>>>(x, nullptr, nullptr, p1T, p1_proj_b,
                                              p1_att_src, p1_att_dst, Hb, asrc, adst);
    seg_aggregate_dual<<<2 * gseg, 256, 0, stream>>>(
        rowptr0, cs0, asrc, adst, O0b,
        rowptr1, cs1, asrc + nh, adst + nh, O1b, Hb, gseg);
    score_mfma_dual<<<2 * SNB, 256, 0, stream>>>(O0b, O1b, k1T, p1_kb, p1_q, sacc);

    // ================= Layer 2 (combine + attn-softmax fused into proj) =================
    proj_mfma<CDIM, 2><<<gm, 256, 0, stream>>>(O0b, O1b, sacc, p2T, p2_proj_b,
                                               p2_att_src, p2_att_dst, Hb, asrc, adst);
    seg_aggregate_dual<<<2 * gseg, 256, 0, stream>>>(
        rowptr0, cs0, asrc, adst, O0b,
        rowptr1, cs1, asrc + nh, adst + nh, O1b, Hb, gseg);
    score_mfma_dual<<<2 * SNB, 256, 0, stream>>>(O0b, O1b, k2T, p2_kb, p2_q, sacc + 2);

    // ================= Final classifier (combine + attn-softmax fused) =================
    const int gfin = (NNODES * FOUT + 255) / 256;
    final_linear_kernel<<<gfin, 256, 0, stream>>>(O0b, O1b, sacc + 2, lin_w, lin_b,
                                                  (float*)d_out);
}